// Round 9
// baseline (820.629 us; speedup 1.0000x reference)
//
#include <hip/hip_runtime.h>
#include <hip/hip_bf16.h>
#include <hip/hip_fp16.h>

#define BT 16384
#define F 32
#define H 256
#define FH 8192
#define SPLITK 4

typedef _Float16 half8 __attribute__((ext_vector_type(8)));
typedef float float4v __attribute__((ext_vector_type(4)));

#define GLD_LDS(gsrc, ldst) \
    __builtin_amdgcn_global_load_lds( \
        (const __attribute__((address_space(1))) void*)(gsrc), \
        (__attribute__((address_space(3))) void*)(ldst), 16, 0, 0)

// Pipelined-barrier macros (T3/T4): counted vmcnt keeps the prefetch in
// flight ACROSS the barrier; sched_barrier(0) pins ordering (rule #18).
#define WAITVM2_BAR() do { \
    __builtin_amdgcn_sched_barrier(0); \
    asm volatile("s_waitcnt vmcnt(2)" ::: "memory"); \
    __builtin_amdgcn_s_barrier(); \
    __builtin_amdgcn_sched_barrier(0); } while (0)
#define WAITVM0_BAR() do { \
    __builtin_amdgcn_sched_barrier(0); \
    asm volatile("s_waitcnt vmcnt(0)" ::: "memory"); \
    __builtin_amdgcn_s_barrier(); \
    __builtin_amdgcn_sched_barrier(0); } while (0)
#define END_BAR() do { \
    __builtin_amdgcn_sched_barrier(0); \
    __builtin_amdgcn_s_barrier(); \
    __builtin_amdgcn_sched_barrier(0); } while (0)
#define LGKM_BAR() do { \
    __builtin_amdgcn_sched_barrier(0); \
    asm volatile("s_waitcnt lgkmcnt(0)" ::: "memory"); \
    __builtin_amdgcn_s_barrier(); \
    __builtin_amdgcn_sched_barrier(0); } while (0)

// ---------------------------------------------------------------------------
// Prep: transpose w2/wg/wf (F,H_contr,H_out) fp32 -> [f][n_out][h_contr] fp16
// ---------------------------------------------------------------------------
__global__ __launch_bounds__(256) void transpose_w_kernel(
    const float* __restrict__ w2, const float* __restrict__ wg,
    const float* __restrict__ wf, _Float16* __restrict__ wt)
{
    __shared__ float tile[64][65];
    int bid = blockIdx.x;
    int tens = bid >> 9, rem = bid & 511;
    int f = rem >> 4, tl = rem & 15;
    int hb = (tl >> 2) * 64, nb = (tl & 3) * 64;
    const float* src = (tens == 0 ? w2 : (tens == 1 ? wg : wf)) + f * 65536;
    _Float16* dst = wt + (size_t)tens * 2097152 + f * 65536;
    int lane = threadIdx.x & 63, w = threadIdx.x >> 6;
    for (int i = 0; i < 16; ++i) {
        int r = i * 4 + w;
        tile[r][lane] = src[(hb + r) * 256 + nb + lane];
    }
    __syncthreads();
    for (int i = 0; i < 16; ++i) {
        int c = i * 4 + w;
        dst[(nb + c) * 256 + hb + lane] = (_Float16)tile[lane][c];
    }
}

// ---------------------------------------------------------------------------
// Prep: Wcat[n][k] fp16, n<256 from sw1 (8192,256), n in [256,288) from ssw
// ---------------------------------------------------------------------------
__global__ __launch_bounds__(256) void transpose_s_kernel(
    const float* __restrict__ sw1, const float* __restrict__ ssw,
    _Float16* __restrict__ wcat)
{
    __shared__ float tile[64][65];
    int bid = blockIdx.x;
    int lane = threadIdx.x & 63, w = threadIdx.x >> 6;
    if (bid < 512) {
        int k0 = (bid >> 2) * 64, n0 = (bid & 3) * 64;
        for (int i = 0; i < 16; ++i) {
            int r = i * 4 + w;
            tile[r][lane] = sw1[(size_t)(k0 + r) * 256 + n0 + lane];
        }
        __syncthreads();
        for (int i = 0; i < 16; ++i) {
            int c = i * 4 + w;
            wcat[(size_t)(n0 + c) * FH + k0 + lane] = (_Float16)tile[lane][c];
        }
    } else {
        int k0 = (bid - 512) * 64;
        int t = threadIdx.x;
        for (int i = 0; i < 8; ++i) {
            int idx = t + i * 256;
            int r = idx >> 5, cc = idx & 31;
            tile[r][cc] = ssw[(size_t)(k0 + r) * 32 + cc];
        }
        __syncthreads();
        for (int i = 0; i < 8; ++i) {
            int idx = t + i * 256;
            int c = idx >> 6, rr = idx & 63;
            wcat[(size_t)(256 + c) * FH + k0 + rr] = (_Float16)tile[rr][c];
        }
    }
}

// ---------------------------------------------------------------------------
// Fused per-feature GRN v3b: BM=64 tokens x 1 feature, 512 threads (8 waves =
// 2m x 4n). Proven round-5 ping-pong structure (Bs 2 x 16KB tiles, 2 barriers
// per K-step, counted vmcnt(2)) with ONE change: the Bs bank swizzle.
// Bank math (16-lane phase, fixed q): Bs rows are 64B, bank-start =
// 16*(ln&1) + 4*cp mod 32. Old cp = q^(row&3) gives lanes {0,4,8,12} the same
// 4-bank group -> 4-way conflict on every B ds_read_b128; 24 steps x 4 reads
// x 8 waves x 4096 blocks x ~6 extra cyc ~= 1.9e7 = the measured counter.
// New cp = q ^ ((row>>1)&3): same-phase aliasing only at lane distance 8
// -> 2-way = free. Stage-side source chunk matches (rule #21).
// ---------------------------------------------------------------------------
__global__ __launch_bounds__(512, 4) void grn_kernel(
    const float* __restrict__ x, const float* __restrict__ w1, const float* __restrict__ b1,
    const float* __restrict__ b2, const float* __restrict__ bg, const float* __restrict__ bfv_,
    const float* __restrict__ gamma, const float* __restrict__ beta,
    const float* __restrict__ wsk, const float* __restrict__ bsk,
    const _Float16* __restrict__ w2t, const _Float16* __restrict__ wgt,
    const _Float16* __restrict__ wft, _Float16* __restrict__ stacked, int tok_base)
{
    __shared__ __align__(16) char smem[65536];
    _Float16* As = (_Float16*)smem;                  // 64 x 256 fp16 swizzled (32KB)
    _Float16* Bs = (_Float16*)(smem + 32768);        // 2 x (256x32) fp16 (32KB)
    float* red = (float*)smem;                       // alias As (post-MFMA): 512 f32
    float* mv  = (float*)(smem + 2048);              // alias As: 128 f32

    const int f = blockIdx.y;
    const int tok0 = blockIdx.x * 64;                // chunk-local
    const int t = threadIdx.x;
    const int wv = t >> 6;
    const int ln = t & 15;
    const int q  = (t >> 4) & 3;
    const int wm = wv >> 2;                          // m-half 0/1
    const int wn = wv & 3;                           // n-quarter 0..3
    const int r0 = wm * 32 + ln;                     // A-frag row, mt=0
    const int r1 = r0 + 16;                          // A-frag row, mt=1

    const _Float16* w2f = w2t + (size_t)f * 65536;
    const _Float16* wgf = wgt + (size_t)f * 65536;
    const _Float16* wff = wft + (size_t)f * 65536;

#define GRN_STAGE(buf, Bsrc, kc) do {                                          \
        const _Float16* _bp = (Bsrc);                                          \
        _Pragma("unroll")                                                      \
        for (int _i = 0; _i < 2; ++_i) {                                       \
            int _s = t + _i * 512;                                             \
            int _row = _s >> 2;                                                \
            int _c = (_s & 3) ^ ((_row >> 1) & 3);                             \
            GLD_LDS(_bp + _row * 256 + (kc) * 32 + _c * 8,                     \
                    Bs + (buf) * 8192 + _s * 8);                               \
        } } while (0)

#define GRN_MFMA(ACC, kc) do {                                                 \
        const _Float16* _B = Bs + ((kc) & 1) * 8192;                           \
        half8 _a0 = *(const half8*)&As[r0 * 256 + ((((kc) * 4 + q) ^ (r0 & 7)) << 3)]; \
        half8 _a1 = *(const half8*)&As[r1 * 256 + ((((kc) * 4 + q) ^ (r1 & 7)) << 3)]; \
        _Pragma("unroll")                                                      \
        for (int _nt = 0; _nt < 4; ++_nt) {                                    \
            int _rb = wn * 64 + _nt * 16 + ln;                                 \
            int _cp = q ^ ((_rb >> 1) & 3);                                    \
            half8 _b8 = *(const half8*)&_B[_rb * 32 + _cp * 8];                \
            ACC[0][_nt] = __builtin_amdgcn_mfma_f32_16x16x32_f16(              \
                _a0, _b8, ACC[0][_nt], 0, 0, 0);                               \
            ACC[1][_nt] = __builtin_amdgcn_mfma_f32_16x16x32_f16(              \
                _a1, _b8, ACC[1][_nt], 0, 0, 0);                               \
        } } while (0)

    // b2 preloaded (oldest in vm FIFO; retired by the first counted wait)
    float b2v[4];
#pragma unroll
    for (int nt = 0; nt < 4; ++nt) b2v[nt] = b2[f * H + wn * 64 + nt * 16 + ln];

    GRN_STAGE(0, w2f, 0);                            // first weight tile

    // A = elu(x * w1 + b1) -> As (swizzled). x reads are wave-uniform s_loads.
    {
        const int colE = t & 255;
        const int rgE = __builtin_amdgcn_readfirstlane(t >> 8) * 32;
        const float w1v = w1[f * H + colE];
        const float b1v = b1[f * H + colE];
        const int chE = colE >> 3, elE = colE & 7;
#pragma unroll 8
        for (int i = 0; i < 32; ++i) {
            int row = rgE + i;
            float xv = x[(size_t)(tok_base + tok0 + row) * F + f];
            float z = fmaf(xv, w1v, b1v);
            float e = z > 0.f ? z : (__expf(z) - 1.f);
            As[row * 256 + ((chE ^ (row & 7)) << 3) + elE] = (_Float16)e;
        }
    }
    LGKM_BAR();                                      // As visible; stage in flight

    float4v acc1[2][4];
#pragma unroll
    for (int mt = 0; mt < 2; ++mt)
#pragma unroll
        for (int nt = 0; nt < 4; ++nt)
#pragma unroll
            for (int r = 0; r < 4; ++r) acc1[mt][nt][r] = 0.f;

    // ---- stage 1: h2 = A @ w2 ----
#pragma unroll
    for (int kc = 0; kc < 8; ++kc) {
        if (kc < 7) GRN_STAGE((kc + 1) & 1, w2f, kc + 1);
        else        GRN_STAGE(0, wgf, 0);            // chain into stage 2
        WAITVM2_BAR();
        GRN_MFMA(acc1, kc);
        END_BAR();
    }

    // h2 + b2 -> As (swizzled fp16). No vm-ops here (b2 preloaded) so the
    // wg-kc0 prefetch stays in flight; lgkm-only barrier.
    {
#pragma unroll
        for (int mt = 0; mt < 2; ++mt)
#pragma unroll
            for (int nt = 0; nt < 4; ++nt) {
                int n = wn * 64 + nt * 16 + ln;
#pragma unroll
                for (int r = 0; r < 4; ++r) {
                    int row = wm * 32 + mt * 16 + q * 4 + r;
                    As[row * 256 + (((n >> 3) ^ (row & 7)) << 3) + (n & 7)] =
                        (_Float16)(acc1[mt][nt][r] + b2v[nt]);
                }
            }
    }
    LGKM_BAR();

    float4v accG[2][4], accF[2][4];
#pragma unroll
    for (int mt = 0; mt < 2; ++mt)
#pragma unroll
        for (int nt = 0; nt < 4; ++nt)
#pragma unroll
            for (int r = 0; r < 4; ++r) { accG[mt][nt][r] = 0.f; accF[mt][nt][r] = 0.f; }

    // ---- stage 2a: Cg = h2 @ wg ----
#pragma unroll
    for (int kc = 0; kc < 8; ++kc) {
        if (kc < 7) GRN_STAGE((kc + 1) & 1, wgf, kc + 1);
        else        GRN_STAGE(0, wff, 0);            // chain into wf
        WAITVM2_BAR();
        GRN_MFMA(accG, kc);
        END_BAR();
    }
    // ---- stage 2b: Cf = h2 @ wf ----
#pragma unroll
    for (int kc = 0; kc < 8; ++kc) {
        if (kc < 7) {
            GRN_STAGE((kc + 1) & 1, wff, kc + 1);
            WAITVM2_BAR();
        } else {
            WAITVM0_BAR();                           // final drain
        }
        GRN_MFMA(accF, kc);
        END_BAR();
    }
#undef GRN_STAGE
#undef GRN_MFMA

    // ---- GLU + residual, in registers (y overwrites accG) ----
    float xr[2][4];
#pragma unroll
    for (int mt = 0; mt < 2; ++mt)
#pragma unroll
        for (int r = 0; r < 4; ++r)
            xr[mt][r] = x[(size_t)(tok_base + tok0 + wm * 32 + mt * 16 + q * 4 + r) * F + f];
#pragma unroll
    for (int nt = 0; nt < 4; ++nt) {
        int nn = f * H + wn * 64 + nt * 16 + ln;
        float bgv = bg[nn], bfv = bfv_[nn], wsv = wsk[nn], bsv = bsk[nn];
#pragma unroll
        for (int mt = 0; mt < 2; ++mt)
#pragma unroll
            for (int r = 0; r < 4; ++r) {
                float cg = accG[mt][nt][r] + bgv;
                float cf = accF[mt][nt][r] + bfv;
                float sig = 1.f / (1.f + __expf(-cg));
                accG[mt][nt][r] = sig * cf + xr[mt][r] * wsv + bsv;
            }
    }

    // ---- LN sums fused from registers ----
    // per row: in-thread sum over 4 cols, shfl_xor over the 16 ln-lanes
    // (lane bits 0..3; q/row bits untouched), then red[row][wn] cross-wave.
#pragma unroll
    for (int mt = 0; mt < 2; ++mt)
#pragma unroll
        for (int r = 0; r < 4; ++r) {
            float v0 = accG[mt][0][r], v1 = accG[mt][1][r];
            float v2 = accG[mt][2][r], v3 = accG[mt][3][r];
            float s1 = (v0 + v1) + (v2 + v3);
            float s2 = (v0 * v0 + v1 * v1) + (v2 * v2 + v3 * v3);
#pragma unroll
            for (int m = 1; m <= 8; m <<= 1) {
                s1 += __shfl_xor(s1, m, 64);
                s2 += __shfl_xor(s2, m, 64);
            }
            if (ln == 0) {
                int row = wm * 32 + mt * 16 + q * 4 + r;
                red[row * 4 + wn] = s1;
                red[256 + row * 4 + wn] = s2;
            }
        }
    __syncthreads();
    if (t < 64) {
        float a = (red[t * 4] + red[t * 4 + 1]) + (red[t * 4 + 2] + red[t * 4 + 3]);
        float b = (red[256 + t * 4] + red[256 + t * 4 + 1])
                + (red[256 + t * 4 + 2] + red[256 + t * 4 + 3]);
        float mean = a * (1.f / 256.f);
        float var = b * (1.f / 256.f) - mean * mean;
        mv[t] = mean;
        mv[64 + t] = rsqrtf(var + 1e-5f);
    }
    __syncthreads();

    // ---- normalize + scale from registers, store fp16 ----
    float mr[2][4], rr[2][4];
#pragma unroll
    for (int mt = 0; mt < 2; ++mt)
#pragma unroll
        for (int r = 0; r < 4; ++r) {
            int row = wm * 32 + mt * 16 + q * 4 + r;
            mr[mt][r] = mv[row];
            rr[mt][r] = mv[64 + row];
        }
#pragma unroll
    for (int nt = 0; nt < 4; ++nt) {
        int n = wn * 64 + nt * 16 + ln;
        float gv = gamma[f * H + n], bvv = beta[f * H + n];
#pragma unroll
        for (int mt = 0; mt < 2; ++mt)
#pragma unroll
            for (int r = 0; r < 4; ++r) {
                int row = wm * 32 + mt * 16 + q * 4 + r;
                float vv = (accG[mt][nt][r] - mr[mt][r]) * rr[mt][r] * gv + bvv;
                stacked[(size_t)(tok0 + row) * FH + f * H + n] = (_Float16)vv;
            }
    }
}

// ---------------------------------------------------------------------------
// Selection GEMM v3: BM=64, BK=64, 256 threads (4 waves, one n-column each).
// A (stacked) double-buffered in LDS via global_load_lds with XOR swizzle.
// B (wcat, L2-resident) loaded straight to registers each K-step. All
// accumulator indexing compile-time static (rule #20).
// ---------------------------------------------------------------------------
__global__ __launch_bounds__(256, 3) void sel_gemm_kernel(
    const _Float16* __restrict__ stacked, const _Float16* __restrict__ wcat,
    float* __restrict__ sh_part, float* __restrict__ sres_part, int C)
{
    __shared__ __align__(16) _Float16 As2[2][64 * 64];   // 2 x 8 KB
    const int t = threadIdx.x;
    const int wv = t >> 6;
    const int ln = t & 15, q = (t & 63) >> 4;
    const int tok0 = blockIdx.x * 64;                    // chunk-local
    const int kb = blockIdx.y;                           // k-slice 0..3

    const int s1 = t + 256;
    const int row0 = t >> 3,  c0 = ((t & 7) ^ (row0 & 7)) * 8;
    const int row1 = s1 >> 3, c1 = ((s1 & 7) ^ (row1 & 7)) * 8;
    const _Float16* a0src = stacked + (size_t)(tok0 + row0) * FH + kb * 2048 + c0;
    const _Float16* a1src = stacked + (size_t)(tok0 + row1) * FH + kb * 2048 + c1;

    float4v acc[4][5];
#pragma unroll
    for (int mt = 0; mt < 4; ++mt)
#pragma unroll
        for (int i = 0; i < 5; ++i)
#pragma unroll
            for (int r = 0; r < 4; ++r) acc[mt][i][r] = 0.f;

    GLD_LDS(a0src, &As2[0][t * 8]);
    GLD_LDS(a1src, &As2[0][s1 * 8]);
    __syncthreads();

    for (int kc = 0; kc < 32; ++kc) {
        const int cur = kc & 1;
        // ---- B fragments for this K-step: global->reg, issued FIRST ----
        half8 bb0[5], bb1[5];
#define SEL_LOAD(i)                                                            \
        {                                                                      \
            const _Float16* bp = wcat                                          \
                + (size_t)((wv + 4 * (i)) * 16 + ln) * FH                      \
                + kb * 2048 + kc * 64 + q * 8;                                 \
            bb0[i] = *(const half8*)bp;                                        \
            bb1[i] = *(const half8*)(bp + 32);                                 \
        }
        SEL_LOAD(0) SEL_LOAD(1) SEL_LOAD(2) SEL_LOAD(3)
        if (wv < 2) SEL_LOAD(4)
#undef SEL_LOAD
        // ---- prefetch next A tile into the other buffer ----
        if (kc < 31) {
            GLD_LDS(a0src + (kc + 1) * 64, &As2[cur ^ 1][t * 8]);
            GLD_LDS(a1src + (kc + 1) * 64, &As2[cur ^ 1][s1 * 8]);
        }
        // ---- A fragments from LDS (swizzled, conflict-free) ----
        const _Float16* As = As2[cur];
        half8 af0[4], af1[4];
#pragma unroll
        for (int mt = 0; mt < 4; ++mt) {
            int row = mt * 16 + ln;
            af0[mt] = *(const half8*)&As[row * 64 + ((q ^ (row & 7)) * 8)];
            af1[mt] = *(const half8*)&As[row * 64 + (((4 + q) ^ (row & 7)) * 8)];
        }
        // ---- MFMA, fully static indexing ----
#define SEL_FMA(i)                                                             \
        {                                                                      \
            _Pragma("unroll")                                                  \
            for (int mt = 0; mt < 4; ++mt)                                     \
                acc[mt][i] = __builtin_amdgcn_mfma_f32_16x16x32_f16(           \
                    af0[mt], bb0[i], acc[mt][i], 0, 0, 0);                     \
            _Pragma("unroll")                                                  \
            for (int mt = 0; mt < 4; ++mt)                                     \
                acc[mt][i] = __builtin_amdgcn_mfma_f32_16x16x32_f16(           \
                    af1[mt], bb1[i], acc[mt][i], 0, 0, 0);                     \
        }
        SEL_FMA(0) SEL_FMA(1) SEL_FMA(2) SEL_FMA(3)
        if (wv < 2) SEL_FMA(4)
#undef SEL_FMA
        __syncthreads();   // drains prefetch; all waves done reading buf[cur]
    }

    // ---- epilogue: plain stores, static branches ----
    float* shp = sh_part + (size_t)kb * ((size_t)C * 256);
    float* srp = sres_part + (size_t)kb * ((size_t)C * 32);
#pragma unroll
    for (int i = 0; i < 4; ++i) {
        int n = (wv + 4 * i) * 16 + ln;                  // always < 256
#pragma unroll
        for (int mt = 0; mt < 4; ++mt)
#pragma unroll
            for (int r = 0; r < 4; ++r) {
                int m = tok0 + mt * 16 + q * 4 + r;
                shp[(size_t)m * 256 + n] = acc[mt][i][r];
            }
    }
    if (wv < 2) {                                        // tile 4 = sres cols
        int n = wv * 16 + ln;                            // 0..31
#pragma unroll
        for (int mt = 0; mt < 4; ++mt)
#pragma unroll
            for (int r = 0; r < 4; ++r) {
                int m = tok0 + mt * 16 + q * 4 + r;
                srp[(size_t)m * 32 + n] = acc[mt][4][r];
            }
    }
}

// ---------------------------------------------------------------------------
// Fused selection tail + weighted sum. Block = 8 tokens (32 lanes each).
// Reduces the 4 split-K partials (+bias) -> elu -> fc2(256->32) -> GLU -> LN
// -> softmax -> out = sum_f stacked*w
// ---------------------------------------------------------------------------
__global__ __launch_bounds__(256) void tail_kernel(
    const float* __restrict__ sh_part, const float* __restrict__ sres_part,
    const _Float16* __restrict__ stacked,
    const float* __restrict__ sb1, const float* __restrict__ ssb,
    const float* __restrict__ sw2, const float* __restrict__ sb2,
    const float* __restrict__ swg, const float* __restrict__ sbg,
    const float* __restrict__ swf, const float* __restrict__ sbf,
    const float* __restrict__ sgam, const float* __restrict__ sbet,
    float* __restrict__ out, int tok_base, int C)
{
    __shared__ float sw2s[256 * 32];                    // 32 KB
    __shared__ float swgs[1024], swfs[1024];            // 8 KB
    __shared__ float shv[8][257];                       // 8 tokens x 256 (+pad)
    __shared__ float wls[8][33];
    const int t = threadIdx.x;
    const size_t shS = (size_t)C * 256;
    const size_t srS = (size_t)C * 32;
    for (int i = 0; i < 32; ++i) sw2s[t + i * 256] = sw2[t + i * 256];
    for (int i = 0; i < 4; ++i) {
        swgs[t + i * 256] = swg[t + i * 256];
        swfs[t + i * 256] = swf[t + i * 256];
    }
    // reduce split-K partials + bias, elu, stage for 8 tokens
    for (int i = 0; i < 8; ++i) {
        int idx = t + i * 256;
        int gg = idx >> 8, col = idx & 255;
        size_t o = (size_t)(blockIdx.x * 8 + gg) * 256 + col;
        float z = sb1[col] + sh_part[o] + sh_part[shS + o]
                + sh_part[2 * shS + o] + sh_part[3 * shS + o];
        shv[gg][col] = z > 0.f ? z : (__expf(z) - 1.f);
    }
    __syncthreads();
    const int g = t >> 5;                               // token group 0..7
    const int j = t & 31;                               // feature index
    const int token = blockIdx.x * 8 + g;               // chunk-local
    // fc2: 256 -> 32
    float p = sb2[j];
    for (int k = 0; k < 256; ++k) p += shv[g][k] * sw2s[k * 32 + j];
    // GLU via width-32 shuffles
    float gacc = sbg[j], uacc = sbf[j];
#pragma unroll 8
    for (int i = 0; i < 32; ++i) {
        float tv = __shfl(p, i, 32);
        gacc += tv * swgs[i * 32 + j];
        uacc += tv * swfs[i * 32 + j];
    }
    float sig = 1.f / (1.f + __expf(-gacc));
    size_t o2 = (size_t)token * 32 + j;
    float sresv = ssb[j] + sres_part[o2] + sres_part[srS + o2]
                + sres_part[2 * srS + o2] + sres_part[3 * srS + o2];
    float sv = sresv + sig * uacc;
    // LayerNorm over 32 lanes
    float s1 = sv, s2 = sv * sv;
    for (int off = 16; off; off >>= 1) {
        s1 += __shfl_xor(s1, off, 32);
        s2 += __shfl_xor(s2, off, 32);
    }
    float mean = s1 * (1.f / 32.f);
    float var = s2 * (1.f / 32.f) - mean * mean;
    float v = (sv - mean) * rsqrtf(var + 1e-5f) * sgam[j] + sbet[j];
    // softmax over 32 lanes
    float mx = v;
    for (int off = 16; off; off >>= 1) mx = fmaxf(mx, __shfl_xor(mx, off, 32));
    float e = __expf(v - mx);
    float ssum = e;
    for (int off = 16; off; off >>= 1) ssum += __shfl_xor(ssum, off, 32);
    wls[g][j] = e / ssum;
    __syncthreads();
    // weighted sum over features for the block's 8 tokens
    for (int tk = 0; tk < 8; ++tk) {
        const _Float16* sp = stacked + (size_t)(blockIdx.x * 8 + tk) * FH;
        float a = 0.f;
#pragma unroll
        for (int f = 0; f < 32; ++f) a += (float)sp[f * 256 + t] * wls[tk][f];
        out[(size_t)(tok_base + blockIdx.x * 8 + tk) * 256 + t] = a;
    }
}

// ---------------------------------------------------------------------------
extern "C" void kernel_launch(void* const* d_in, const int* in_sizes, int n_in,
                              void* d_out, int out_size, void* d_ws, size_t ws_size,
                              hipStream_t stream)
{
    (void)in_sizes; (void)n_in; (void)out_size;
    const float* x    = (const float*)d_in[0];
    const float* w1   = (const float*)d_in[1];
    const float* b1   = (const float*)d_in[2];
    const float* w2   = (const float*)d_in[3];
    const float* b2   = (const float*)d_in[4];
    const float* wg   = (const float*)d_in[5];
    const float* bg   = (const float*)d_in[6];
    const float* wf   = (const float*)d_in[7];
    const float* bfp  = (const float*)d_in[8];
    const float* gamma= (const float*)d_in[9];
    const float* beta = (const float*)d_in[10];
    const float* wsk  = (const float*)d_in[11];
    const float* bsk  = (const float*)d_in[12];
    const float* sw1  = (const float*)d_in[13];
    const float* sb1  = (const float*)d_in[14];
    const float* sw2  = (const float*)d_in[15];
    const float* sb2  = (const float*)d_in[16];
    const float* swg  = (const float*)d_in[17];
    const float* sbg  = (const float*)d_in[18];
    const float* swf  = (const float*)d_in[19];
    const float* sbf  = (const float*)d_in[20];
    const float* sgam = (const float*)d_in[21];
    const float* sbet = (const float*)d_in[22];
    const float* ssw  = (const float*)d_in[23];
    const float* ssb  = (const float*)d_in[24];

    // ---- workspace layout, chunk size adaptive to ws_size ----
    // per-token: stacked 16384B + sh_part 4*1024B + sres_part 4*128B = 20992B
    const size_t fixedB = 12582912 + 4718592;            // wt (12 MiB) + wcat (4.5 MiB)
    int C = BT;                                          // tokens per chunk
    while (C > 512) {
        size_t need = fixedB + (size_t)C * 20992;
        if (need <= ws_size) break;
        C >>= 1;
    }
    const int nChunks = BT / C;

    char* ws = (char*)d_ws;
    _Float16* wt      = (_Float16*)ws;                                   // 3 x 2M fp16
    _Float16* wcat    = (_Float16*)(ws + 12582912);                      // 288 x 8192 fp16
    char* p = ws + fixedB;
    _Float16* stacked = (_Float16*)p;            p += (size_t)C * FH * 2;
    float* sh_part    = (float*)p;               p += (size_t)C * 256 * 4 * SPLITK;
    float* sres_part  = (float*)p;
    float* out        = (float*)d_out;

    hipLaunchKernelGGL(transpose_w_kernel, dim3(1536), dim3(256), 0, stream, w2, wg, wf, wt);
    hipLaunchKernelGGL(transpose_s_kernel, dim3(640), dim3(256), 0, stream, sw1, ssw, wcat);
    for (int c = 0; c < nChunks; ++c) {
        int tb = c * C;
        hipLaunchKernelGGL(grn_kernel, dim3(C / 64, 32), dim3(512), 0, stream,
                           x, w1, b1, b2, bg, bfp, gamma, beta, wsk, bsk,
                           wt, wt + 2097152, wt + 2 * 2097152, stacked, tb);
        hipLaunchKernelGGL(sel_gemm_kernel, dim3(C / 64, SPLITK), dim3(256), 0, stream,
                           stacked, wcat, sh_part, sres_part, C);
        hipLaunchKernelGGL(tail_kernel, dim3(C / 8), dim3(256), 0, stream,
                           sh_part, sres_part, stacked, sb1, ssb, sw2, sb2, swg, sbg, swf, sbf,
                           sgam, sbet, out, tb, C);
    }
}

// Round 10
// 805.341 us; speedup vs baseline: 1.0190x; 1.0190x over previous
//
#include <hip/hip_runtime.h>
#include <hip/hip_bf16.h>
#include <hip/hip_fp16.h>

#define BT 16384
#define F 32
#define H 256
#define FH 8192
#define SPLITK 4

typedef _Float16 half8 __attribute__((ext_vector_type(8)));
typedef float float4v __attribute__((ext_vector_type(4)));

#define GLD_LDS(gsrc, ldst) \
    __builtin_amdgcn_global_load_lds( \
        (const __attribute__((address_space(1))) void*)(gsrc), \
        (__attribute__((address_space(3))) void*)(ldst), 16, 0, 0)

// Pipelined-barrier macros (T3/T4): counted vmcnt keeps the prefetch in
// flight ACROSS the barrier; sched_barrier(0) pins ordering (rule #18).
#define WAITVM2_BAR() do { \
    __builtin_amdgcn_sched_barrier(0); \
    asm volatile("s_waitcnt vmcnt(2)" ::: "memory"); \
    __builtin_amdgcn_s_barrier(); \
    __builtin_amdgcn_sched_barrier(0); } while (0)
#define WAITVM0_BAR() do { \
    __builtin_amdgcn_sched_barrier(0); \
    asm volatile("s_waitcnt vmcnt(0)" ::: "memory"); \
    __builtin_amdgcn_s_barrier(); \
    __builtin_amdgcn_sched_barrier(0); } while (0)
#define END_BAR() do { \
    __builtin_amdgcn_sched_barrier(0); \
    __builtin_amdgcn_s_barrier(); \
    __builtin_amdgcn_sched_barrier(0); } while (0)
#define LGKM_BAR() do { \
    __builtin_amdgcn_sched_barrier(0); \
    asm volatile("s_waitcnt lgkmcnt(0)" ::: "memory"); \
    __builtin_amdgcn_s_barrier(); \
    __builtin_amdgcn_sched_barrier(0); } while (0)

// ---------------------------------------------------------------------------
// Prep: transpose w2/wg/wf (F,H_contr,H_out) fp32 -> [f][n_out][h_contr] fp16
// ---------------------------------------------------------------------------
__global__ __launch_bounds__(256) void transpose_w_kernel(
    const float* __restrict__ w2, const float* __restrict__ wg,
    const float* __restrict__ wf, _Float16* __restrict__ wt)
{
    __shared__ float tile[64][65];
    int bid = blockIdx.x;
    int tens = bid >> 9, rem = bid & 511;
    int f = rem >> 4, tl = rem & 15;
    int hb = (tl >> 2) * 64, nb = (tl & 3) * 64;
    const float* src = (tens == 0 ? w2 : (tens == 1 ? wg : wf)) + f * 65536;
    _Float16* dst = wt + (size_t)tens * 2097152 + f * 65536;
    int lane = threadIdx.x & 63, w = threadIdx.x >> 6;
    for (int i = 0; i < 16; ++i) {
        int r = i * 4 + w;
        tile[r][lane] = src[(hb + r) * 256 + nb + lane];
    }
    __syncthreads();
    for (int i = 0; i < 16; ++i) {
        int c = i * 4 + w;
        dst[(nb + c) * 256 + hb + lane] = (_Float16)tile[lane][c];
    }
}

// ---------------------------------------------------------------------------
// Prep: Wcat[n][k] fp16, n<256 from sw1 (8192,256), n in [256,288) from ssw
// ---------------------------------------------------------------------------
__global__ __launch_bounds__(256) void transpose_s_kernel(
    const float* __restrict__ sw1, const float* __restrict__ ssw,
    _Float16* __restrict__ wcat)
{
    __shared__ float tile[64][65];
    int bid = blockIdx.x;
    int lane = threadIdx.x & 63, w = threadIdx.x >> 6;
    if (bid < 512) {
        int k0 = (bid >> 2) * 64, n0 = (bid & 3) * 64;
        for (int i = 0; i < 16; ++i) {
            int r = i * 4 + w;
            tile[r][lane] = sw1[(size_t)(k0 + r) * 256 + n0 + lane];
        }
        __syncthreads();
        for (int i = 0; i < 16; ++i) {
            int c = i * 4 + w;
            wcat[(size_t)(n0 + c) * FH + k0 + lane] = (_Float16)tile[lane][c];
        }
    } else {
        int k0 = (bid - 512) * 64;
        int t = threadIdx.x;
        for (int i = 0; i < 8; ++i) {
            int idx = t + i * 256;
            int r = idx >> 5, cc = idx & 31;
            tile[r][cc] = ssw[(size_t)(k0 + r) * 32 + cc];
        }
        __syncthreads();
        for (int i = 0; i < 8; ++i) {
            int idx = t + i * 256;
            int c = idx >> 6, rr = idx & 63;
            wcat[(size_t)(256 + c) * FH + k0 + rr] = (_Float16)tile[rr][c];
        }
    }
}

// ---------------------------------------------------------------------------
// Fused per-feature GRN v5: identical compute/sync structure to v3b (proven),
// ONE change: XCD-clustered block decode (T1). Old grid (m,f) linearizes so
// consecutive bids share f and round-robin over the 8 XCDs -> every XCD
// touches all 32 features' weights (12 MB) vs 4 MB per-XCD L2 -> thrash;
// FETCH_SIZE showed 52 MB (4x the 13 MB compulsory). New decode gives each
// XCD 4 features (1.5 MB, L2-resident): xcd=bid&7, f=xcd*4+(slot&3),
// mtile=slot>>2. Bijective for any M=C/64 (blocks = M*32, M*4 slots/XCD).
// ---------------------------------------------------------------------------
__global__ __launch_bounds__(512, 4) void grn_kernel(
    const float* __restrict__ x, const float* __restrict__ w1, const float* __restrict__ b1,
    const float* __restrict__ b2, const float* __restrict__ bg, const float* __restrict__ bfv_,
    const float* __restrict__ gamma, const float* __restrict__ beta,
    const float* __restrict__ wsk, const float* __restrict__ bsk,
    const _Float16* __restrict__ w2t, const _Float16* __restrict__ wgt,
    const _Float16* __restrict__ wft, _Float16* __restrict__ stacked, int tok_base)
{
    __shared__ __align__(16) char smem[65536];
    _Float16* As = (_Float16*)smem;                  // 64 x 256 fp16 swizzled (32KB)
    _Float16* Bs = (_Float16*)(smem + 32768);        // 2 x (256x32) fp16 (32KB)
    float* red = (float*)smem;                       // alias As (post-MFMA): 512 f32
    float* mv  = (float*)(smem + 2048);              // alias As: 128 f32

    // XCD-clustered decode (T1): each XCD owns features [4*xcd, 4*xcd+4)
    const int bid = blockIdx.x;
    const int xcd = bid & 7;
    const int slot = bid >> 3;
    const int f = xcd * 4 + (slot & 3);
    const int tok0 = (slot >> 2) * 64;               // chunk-local
    const int t = threadIdx.x;
    const int wv = t >> 6;
    const int ln = t & 15;
    const int q  = (t >> 4) & 3;
    const int wm = wv >> 2;                          // m-half 0/1
    const int wn = wv & 3;                           // n-quarter 0..3
    const int r0 = wm * 32 + ln;                     // A-frag row, mt=0
    const int r1 = r0 + 16;                          // A-frag row, mt=1

    const _Float16* w2f = w2t + (size_t)f * 65536;
    const _Float16* wgf = wgt + (size_t)f * 65536;
    const _Float16* wff = wft + (size_t)f * 65536;

#define GRN_STAGE(buf, Bsrc, kc) do {                                          \
        const _Float16* _bp = (Bsrc);                                          \
        _Pragma("unroll")                                                      \
        for (int _i = 0; _i < 2; ++_i) {                                       \
            int _s = t + _i * 512;                                             \
            int _row = _s >> 2;                                                \
            int _c = (_s & 3) ^ ((_row >> 1) & 3);                             \
            GLD_LDS(_bp + _row * 256 + (kc) * 32 + _c * 8,                     \
                    Bs + (buf) * 8192 + _s * 8);                               \
        } } while (0)

#define GRN_MFMA(ACC, kc) do {                                                 \
        const _Float16* _B = Bs + ((kc) & 1) * 8192;                           \
        half8 _a0 = *(const half8*)&As[r0 * 256 + ((((kc) * 4 + q) ^ (r0 & 7)) << 3)]; \
        half8 _a1 = *(const half8*)&As[r1 * 256 + ((((kc) * 4 + q) ^ (r1 & 7)) << 3)]; \
        _Pragma("unroll")                                                      \
        for (int _nt = 0; _nt < 4; ++_nt) {                                    \
            int _rb = wn * 64 + _nt * 16 + ln;                                 \
            int _cp = q ^ ((_rb >> 1) & 3);                                    \
            half8 _b8 = *(const half8*)&_B[_rb * 32 + _cp * 8];                \
            ACC[0][_nt] = __builtin_amdgcn_mfma_f32_16x16x32_f16(              \
                _a0, _b8, ACC[0][_nt], 0, 0, 0);                               \
            ACC[1][_nt] = __builtin_amdgcn_mfma_f32_16x16x32_f16(              \
                _a1, _b8, ACC[1][_nt], 0, 0, 0);                               \
        } } while (0)

    // b2 preloaded (oldest in vm FIFO; retired by the first counted wait)
    float b2v[4];
#pragma unroll
    for (int nt = 0; nt < 4; ++nt) b2v[nt] = b2[f * H + wn * 64 + nt * 16 + ln];

    GRN_STAGE(0, w2f, 0);                            // first weight tile

    // A = elu(x * w1 + b1) -> As (swizzled). x reads are wave-uniform s_loads.
    {
        const int colE = t & 255;
        const int rgE = __builtin_amdgcn_readfirstlane(t >> 8) * 32;
        const float w1v = w1[f * H + colE];
        const float b1v = b1[f * H + colE];
        const int chE = colE >> 3, elE = colE & 7;
#pragma unroll 8
        for (int i = 0; i < 32; ++i) {
            int row = rgE + i;
            float xv = x[(size_t)(tok_base + tok0 + row) * F + f];
            float z = fmaf(xv, w1v, b1v);
            float e = z > 0.f ? z : (__expf(z) - 1.f);
            As[row * 256 + ((chE ^ (row & 7)) << 3) + elE] = (_Float16)e;
        }
    }
    LGKM_BAR();                                      // As visible; stage in flight

    float4v acc1[2][4];
#pragma unroll
    for (int mt = 0; mt < 2; ++mt)
#pragma unroll
        for (int nt = 0; nt < 4; ++nt)
#pragma unroll
            for (int r = 0; r < 4; ++r) acc1[mt][nt][r] = 0.f;

    // ---- stage 1: h2 = A @ w2 ----
#pragma unroll
    for (int kc = 0; kc < 8; ++kc) {
        if (kc < 7) GRN_STAGE((kc + 1) & 1, w2f, kc + 1);
        else        GRN_STAGE(0, wgf, 0);            // chain into stage 2
        WAITVM2_BAR();
        GRN_MFMA(acc1, kc);
        END_BAR();
    }

    // h2 + b2 -> As (swizzled fp16). No vm-ops here (b2 preloaded) so the
    // wg-kc0 prefetch stays in flight; lgkm-only barrier.
    {
#pragma unroll
        for (int mt = 0; mt < 2; ++mt)
#pragma unroll
            for (int nt = 0; nt < 4; ++nt) {
                int n = wn * 64 + nt * 16 + ln;
#pragma unroll
                for (int r = 0; r < 4; ++r) {
                    int row = wm * 32 + mt * 16 + q * 4 + r;
                    As[row * 256 + (((n >> 3) ^ (row & 7)) << 3) + (n & 7)] =
                        (_Float16)(acc1[mt][nt][r] + b2v[nt]);
                }
            }
    }
    LGKM_BAR();

    float4v accG[2][4], accF[2][4];
#pragma unroll
    for (int mt = 0; mt < 2; ++mt)
#pragma unroll
        for (int nt = 0; nt < 4; ++nt)
#pragma unroll
            for (int r = 0; r < 4; ++r) { accG[mt][nt][r] = 0.f; accF[mt][nt][r] = 0.f; }

    // ---- stage 2a: Cg = h2 @ wg ----
#pragma unroll
    for (int kc = 0; kc < 8; ++kc) {
        if (kc < 7) GRN_STAGE((kc + 1) & 1, wgf, kc + 1);
        else        GRN_STAGE(0, wff, 0);            // chain into wf
        WAITVM2_BAR();
        GRN_MFMA(accG, kc);
        END_BAR();
    }
    // ---- stage 2b: Cf = h2 @ wf ----
#pragma unroll
    for (int kc = 0; kc < 8; ++kc) {
        if (kc < 7) {
            GRN_STAGE((kc + 1) & 1, wff, kc + 1);
            WAITVM2_BAR();
        } else {
            WAITVM0_BAR();                           // final drain
        }
        GRN_MFMA(accF, kc);
        END_BAR();
    }
#undef GRN_STAGE
#undef GRN_MFMA

    // ---- GLU + residual, in registers (y overwrites accG) ----
    float xr[2][4];
#pragma unroll
    for (int mt = 0; mt < 2; ++mt)
#pragma unroll
        for (int r = 0; r < 4; ++r)
            xr[mt][r] = x[(size_t)(tok_base + tok0 + wm * 32 + mt * 16 + q * 4 + r) * F + f];
#pragma unroll
    for (int nt = 0; nt < 4; ++nt) {
        int nn = f * H + wn * 64 + nt * 16 + ln;
        float bgv = bg[nn], bfv = bfv_[nn], wsv = wsk[nn], bsv = bsk[nn];
#pragma unroll
        for (int mt = 0; mt < 2; ++mt)
#pragma unroll
            for (int r = 0; r < 4; ++r) {
                float cg = accG[mt][nt][r] + bgv;
                float cf = accF[mt][nt][r] + bfv;
                float sig = 1.f / (1.f + __expf(-cg));
                accG[mt][nt][r] = sig * cf + xr[mt][r] * wsv + bsv;
            }
    }

    // ---- LN sums fused from registers ----
#pragma unroll
    for (int mt = 0; mt < 2; ++mt)
#pragma unroll
        for (int r = 0; r < 4; ++r) {
            float v0 = accG[mt][0][r], v1 = accG[mt][1][r];
            float v2 = accG[mt][2][r], v3 = accG[mt][3][r];
            float s1 = (v0 + v1) + (v2 + v3);
            float s2 = (v0 * v0 + v1 * v1) + (v2 * v2 + v3 * v3);
#pragma unroll
            for (int m = 1; m <= 8; m <<= 1) {
                s1 += __shfl_xor(s1, m, 64);
                s2 += __shfl_xor(s2, m, 64);
            }
            if (ln == 0) {
                int row = wm * 32 + mt * 16 + q * 4 + r;
                red[row * 4 + wn] = s1;
                red[256 + row * 4 + wn] = s2;
            }
        }
    __syncthreads();
    if (t < 64) {
        float a = (red[t * 4] + red[t * 4 + 1]) + (red[t * 4 + 2] + red[t * 4 + 3]);
        float b = (red[256 + t * 4] + red[256 + t * 4 + 1])
                + (red[256 + t * 4 + 2] + red[256 + t * 4 + 3]);
        float mean = a * (1.f / 256.f);
        float var = b * (1.f / 256.f) - mean * mean;
        mv[t] = mean;
        mv[64 + t] = rsqrtf(var + 1e-5f);
    }
    __syncthreads();

    // ---- normalize + scale from registers, store fp16 ----
    float mr[2][4], rr[2][4];
#pragma unroll
    for (int mt = 0; mt < 2; ++mt)
#pragma unroll
        for (int r = 0; r < 4; ++r) {
            int row = wm * 32 + mt * 16 + q * 4 + r;
            mr[mt][r] = mv[row];
            rr[mt][r] = mv[64 + row];
        }
#pragma unroll
    for (int nt = 0; nt < 4; ++nt) {
        int n = wn * 64 + nt * 16 + ln;
        float gv = gamma[f * H + n], bvv = beta[f * H + n];
#pragma unroll
        for (int mt = 0; mt < 2; ++mt)
#pragma unroll
            for (int r = 0; r < 4; ++r) {
                int row = wm * 32 + mt * 16 + q * 4 + r;
                float vv = (accG[mt][nt][r] - mr[mt][r]) * rr[mt][r] * gv + bvv;
                stacked[(size_t)(tok0 + row) * FH + f * H + n] = (_Float16)vv;
            }
    }
}

// ---------------------------------------------------------------------------
// Selection GEMM v4: structure identical to v3 (proven), ONE change:
// XCD-clustered decode. Old grid (m,kb) round-robins m over XCDs -> every
// XCD touches all 4 wcat k-slices (4.7 MB > 4 MB L2). New: xcd=bid&7,
// kb=xcd>>1 (2 XCDs per slice, 1.18 MB each), mtile=slot*2+(xcd&1).
// Bijective for any even M.
// ---------------------------------------------------------------------------
__global__ __launch_bounds__(256, 3) void sel_gemm_kernel(
    const _Float16* __restrict__ stacked, const _Float16* __restrict__ wcat,
    float* __restrict__ sh_part, float* __restrict__ sres_part, int C)
{
    __shared__ __align__(16) _Float16 As2[2][64 * 64];   // 2 x 8 KB
    const int t = threadIdx.x;
    const int wv = t >> 6;
    const int ln = t & 15, q = (t & 63) >> 4;
    const int bid = blockIdx.x;
    const int xcd = bid & 7;
    const int slot = bid >> 3;
    const int kb = xcd >> 1;                             // k-slice 0..3
    const int tok0 = (slot * 2 + (xcd & 1)) * 64;        // chunk-local

    const int s1 = t + 256;
    const int row0 = t >> 3,  c0 = ((t & 7) ^ (row0 & 7)) * 8;
    const int row1 = s1 >> 3, c1 = ((s1 & 7) ^ (row1 & 7)) * 8;
    const _Float16* a0src = stacked + (size_t)(tok0 + row0) * FH + kb * 2048 + c0;
    const _Float16* a1src = stacked + (size_t)(tok0 + row1) * FH + kb * 2048 + c1;

    float4v acc[4][5];
#pragma unroll
    for (int mt = 0; mt < 4; ++mt)
#pragma unroll
        for (int i = 0; i < 5; ++i)
#pragma unroll
            for (int r = 0; r < 4; ++r) acc[mt][i][r] = 0.f;

    GLD_LDS(a0src, &As2[0][t * 8]);
    GLD_LDS(a1src, &As2[0][s1 * 8]);
    __syncthreads();

    for (int kc = 0; kc < 32; ++kc) {
        const int cur = kc & 1;
        // ---- B fragments for this K-step: global->reg, issued FIRST ----
        half8 bb0[5], bb1[5];
#define SEL_LOAD(i)                                                            \
        {                                                                      \
            const _Float16* bp = wcat                                          \
                + (size_t)((wv + 4 * (i)) * 16 + ln) * FH                      \
                + kb * 2048 + kc * 64 + q * 8;                                 \
            bb0[i] = *(const half8*)bp;                                        \
            bb1[i] = *(const half8*)(bp + 32);                                 \
        }
        SEL_LOAD(0) SEL_LOAD(1) SEL_LOAD(2) SEL_LOAD(3)
        if (wv < 2) SEL_LOAD(4)
#undef SEL_LOAD
        // ---- prefetch next A tile into the other buffer ----
        if (kc < 31) {
            GLD_LDS(a0src + (kc + 1) * 64, &As2[cur ^ 1][t * 8]);
            GLD_LDS(a1src + (kc + 1) * 64, &As2[cur ^ 1][s1 * 8]);
        }
        // ---- A fragments from LDS (swizzled, conflict-free) ----
        const _Float16* As = As2[cur];
        half8 af0[4], af1[4];
#pragma unroll
        for (int mt = 0; mt < 4; ++mt) {
            int row = mt * 16 + ln;
            af0[mt] = *(const half8*)&As[row * 64 + ((q ^ (row & 7)) * 8)];
            af1[mt] = *(const half8*)&As[row * 64 + (((4 + q) ^ (row & 7)) * 8)];
        }
        // ---- MFMA, fully static indexing ----
#define SEL_FMA(i)                                                             \
        {                                                                      \
            _Pragma("unroll")                                                  \
            for (int mt = 0; mt < 4; ++mt)                                     \
                acc[mt][i] = __builtin_amdgcn_mfma_f32_16x16x32_f16(           \
                    af0[mt], bb0[i], acc[mt][i], 0, 0, 0);                     \
            _Pragma("unroll")                                                  \
            for (int mt = 0; mt < 4; ++mt)                                     \
                acc[mt][i] = __builtin_amdgcn_mfma_f32_16x16x32_f16(           \
                    af1[mt], bb1[i], acc[mt][i], 0, 0, 0);                     \
        }
        SEL_FMA(0) SEL_FMA(1) SEL_FMA(2) SEL_FMA(3)
        if (wv < 2) SEL_FMA(4)
#undef SEL_FMA
        __syncthreads();   // drains prefetch; all waves done reading buf[cur]
    }

    // ---- epilogue: plain stores, static branches ----
    float* shp = sh_part + (size_t)kb * ((size_t)C * 256);
    float* srp = sres_part + (size_t)kb * ((size_t)C * 32);
#pragma unroll
    for (int i = 0; i < 4; ++i) {
        int n = (wv + 4 * i) * 16 + ln;                  // always < 256
#pragma unroll
        for (int mt = 0; mt < 4; ++mt)
#pragma unroll
            for (int r = 0; r < 4; ++r) {
                int m = tok0 + mt * 16 + q * 4 + r;
                shp[(size_t)m * 256 + n] = acc[mt][i][r];
            }
    }
    if (wv < 2) {                                        // tile 4 = sres cols
        int n = wv * 16 + ln;                            // 0..31
#pragma unroll
        for (int mt = 0; mt < 4; ++mt)
#pragma unroll
            for (int r = 0; r < 4; ++r) {
                int m = tok0 + mt * 16 + q * 4 + r;
                srp[(size_t)m * 32 + n] = acc[mt][4][r];
            }
    }
}

// ---------------------------------------------------------------------------
// Fused selection tail + weighted sum. Block = 8 tokens (32 lanes each).
// Reduces the 4 split-K partials (+bias) -> elu -> fc2(256->32) -> GLU -> LN
// -> softmax -> out = sum_f stacked*w
// ---------------------------------------------------------------------------
__global__ __launch_bounds__(256) void tail_kernel(
    const float* __restrict__ sh_part, const float* __restrict__ sres_part,
    const _Float16* __restrict__ stacked,
    const float* __restrict__ sb1, const float* __restrict__ ssb,
    const float* __restrict__ sw2, const float* __restrict__ sb2,
    const float* __restrict__ swg, const float* __restrict__ sbg,
    const float* __restrict__ swf, const float* __restrict__ sbf,
    const float* __restrict__ sgam, const float* __restrict__ sbet,
    float* __restrict__ out, int tok_base, int C)
{
    __shared__ float sw2s[256 * 32];                    // 32 KB
    __shared__ float swgs[1024], swfs[1024];            // 8 KB
    __shared__ float shv[8][257];                       // 8 tokens x 256 (+pad)
    __shared__ float wls[8][33];
    const int t = threadIdx.x;
    const size_t shS = (size_t)C * 256;
    const size_t srS = (size_t)C * 32;
    for (int i = 0; i < 32; ++i) sw2s[t + i * 256] = sw2[t + i * 256];
    for (int i = 0; i < 4; ++i) {
        swgs[t + i * 256] = swg[t + i * 256];
        swfs[t + i * 256] = swf[t + i * 256];
    }
    // reduce split-K partials + bias, elu, stage for 8 tokens
    for (int i = 0; i < 8; ++i) {
        int idx = t + i * 256;
        int gg = idx >> 8, col = idx & 255;
        size_t o = (size_t)(blockIdx.x * 8 + gg) * 256 + col;
        float z = sb1[col] + sh_part[o] + sh_part[shS + o]
                + sh_part[2 * shS + o] + sh_part[3 * shS + o];
        shv[gg][col] = z > 0.f ? z : (__expf(z) - 1.f);
    }
    __syncthreads();
    const int g = t >> 5;                               // token group 0..7
    const int j = t & 31;                               // feature index
    const int token = blockIdx.x * 8 + g;               // chunk-local
    // fc2: 256 -> 32
    float p = sb2[j];
    for (int k = 0; k < 256; ++k) p += shv[g][k] * sw2s[k * 32 + j];
    // GLU via width-32 shuffles
    float gacc = sbg[j], uacc = sbf[j];
#pragma unroll 8
    for (int i = 0; i < 32; ++i) {
        float tv = __shfl(p, i, 32);
        gacc += tv * swgs[i * 32 + j];
        uacc += tv * swfs[i * 32 + j];
    }
    float sig = 1.f / (1.f + __expf(-gacc));
    size_t o2 = (size_t)token * 32 + j;
    float sresv = ssb[j] + sres_part[o2] + sres_part[srS + o2]
                + sres_part[2 * srS + o2] + sres_part[3 * srS + o2];
    float sv = sresv + sig * uacc;
    // LayerNorm over 32 lanes
    float s1 = sv, s2 = sv * sv;
    for (int off = 16; off; off >>= 1) {
        s1 += __shfl_xor(s1, off, 32);
        s2 += __shfl_xor(s2, off, 32);
    }
    float mean = s1 * (1.f / 32.f);
    float var = s2 * (1.f / 32.f) - mean * mean;
    float v = (sv - mean) * rsqrtf(var + 1e-5f) * sgam[j] + sbet[j];
    // softmax over 32 lanes
    float mx = v;
    for (int off = 16; off; off >>= 1) mx = fmaxf(mx, __shfl_xor(mx, off, 32));
    float e = __expf(v - mx);
    float ssum = e;
    for (int off = 16; off; off >>= 1) ssum += __shfl_xor(ssum, off, 32);
    wls[g][j] = e / ssum;
    __syncthreads();
    // weighted sum over features for the block's 8 tokens
    for (int tk = 0; tk < 8; ++tk) {
        const _Float16* sp = stacked + (size_t)(blockIdx.x * 8 + tk) * FH;
        float a = 0.f;
#pragma unroll
        for (int f = 0; f < 32; ++f) a += (float)sp[f * 256 + t] * wls[tk][f];
        out[(size_t)(tok_base + blockIdx.x * 8 + tk) * 256 + t] = a;
    }
}

// ---------------------------------------------------------------------------
extern "C" void kernel_launch(void* const* d_in, const int* in_sizes, int n_in,
                              void* d_out, int out_size, void* d_ws, size_t ws_size,
                              hipStream_t stream)
{
    (void)in_sizes; (void)n_in; (void)out_size;
    const float* x    = (const float*)d_in[0];
    const float* w1   = (const float*)d_in[1];
    const float* b1   = (const float*)d_in[2];
    const float* w2   = (const float*)d_in[3];
    const float* b2   = (const float*)d_in[4];
    const float* wg   = (const float*)d_in[5];
    const float* bg   = (const float*)d_in[6];
    const float* wf   = (const float*)d_in[7];
    const float* bfp  = (const float*)d_in[8];
    const float* gamma= (const float*)d_in[9];
    const float* beta = (const float*)d_in[10];
    const float* wsk  = (const float*)d_in[11];
    const float* bsk  = (const float*)d_in[12];
    const float* sw1  = (const float*)d_in[13];
    const float* sb1  = (const float*)d_in[14];
    const float* sw2  = (const float*)d_in[15];
    const float* sb2  = (const float*)d_in[16];
    const float* swg  = (const float*)d_in[17];
    const float* sbg  = (const float*)d_in[18];
    const float* swf  = (const float*)d_in[19];
    const float* sbf  = (const float*)d_in[20];
    const float* sgam = (const float*)d_in[21];
    const float* sbet = (const float*)d_in[22];
    const float* ssw  = (const float*)d_in[23];
    const float* ssb  = (const float*)d_in[24];

    // ---- workspace layout, chunk size adaptive to ws_size ----
    // per-token: stacked 16384B + sh_part 4*1024B + sres_part 4*128B = 20992B
    const size_t fixedB = 12582912 + 4718592;            // wt (12 MiB) + wcat (4.5 MiB)
    int C = BT;                                          // tokens per chunk
    while (C > 512) {
        size_t need = fixedB + (size_t)C * 20992;
        if (need <= ws_size) break;
        C >>= 1;
    }
    const int nChunks = BT / C;

    char* ws = (char*)d_ws;
    _Float16* wt      = (_Float16*)ws;                                   // 3 x 2M fp16
    _Float16* wcat    = (_Float16*)(ws + 12582912);                      // 288 x 8192 fp16
    char* p = ws + fixedB;
    _Float16* stacked = (_Float16*)p;            p += (size_t)C * FH * 2;
    float* sh_part    = (float*)p;               p += (size_t)C * 256 * 4 * SPLITK;
    float* sres_part  = (float*)p;
    float* out        = (float*)d_out;

    hipLaunchKernelGGL(transpose_w_kernel, dim3(1536), dim3(256), 0, stream, w2, wg, wf, wt);
    hipLaunchKernelGGL(transpose_s_kernel, dim3(640), dim3(256), 0, stream, sw1, ssw, wcat);
    for (int c = 0; c < nChunks; ++c) {
        int tb = c * C;
        hipLaunchKernelGGL(grn_kernel, dim3((C / 64) * 32), dim3(512), 0, stream,
                           x, w1, b1, b2, bg, bfp, gamma, beta, wsk, bsk,
                           wt, wt + 2097152, wt + 2 * 2097152, stacked, tb);
        hipLaunchKernelGGL(sel_gemm_kernel, dim3((C / 64) * SPLITK), dim3(256), 0, stream,
                           stacked, wcat, sh_part, sres_part, C);
        hipLaunchKernelGGL(tail_kernel, dim3(C / 8), dim3(256), 0, stream,
                           sh_part, sres_part, stacked, sb1, ssb, sw2, sb2, swg, sbg, swf, sbf,
                           sgam, sbet, out, tb, C);
    }
}

// Round 11
// 728.047 us; speedup vs baseline: 1.1272x; 1.1062x over previous
//
#include <hip/hip_runtime.h>
#include <hip/hip_bf16.h>
#include <hip/hip_fp16.h>

#define BT 16384
#define F 32
#define H 256
#define FH 8192
#define SPLITK 4

typedef _Float16 half8 __attribute__((ext_vector_type(8)));
typedef _Float16 half4v __attribute__((ext_vector_type(4)));
typedef float float4v __attribute__((ext_vector_type(4)));

#define GLD_LDS(gsrc, ldst) \
    __builtin_amdgcn_global_load_lds( \
        (const __attribute__((address_space(1))) void*)(gsrc), \
        (__attribute__((address_space(3))) void*)(ldst), 16, 0, 0)

// Pipelined-barrier macros (T3/T4): counted vmcnt keeps the prefetch in
// flight ACROSS the barrier; sched_barrier(0) pins ordering (rule #18).
#define WAITVM2_BAR() do { \
    __builtin_amdgcn_sched_barrier(0); \
    asm volatile("s_waitcnt vmcnt(2)" ::: "memory"); \
    __builtin_amdgcn_s_barrier(); \
    __builtin_amdgcn_sched_barrier(0); } while (0)
#define WAITVM0_BAR() do { \
    __builtin_amdgcn_sched_barrier(0); \
    asm volatile("s_waitcnt vmcnt(0)" ::: "memory"); \
    __builtin_amdgcn_s_barrier(); \
    __builtin_amdgcn_sched_barrier(0); } while (0)
#define END_BAR() do { \
    __builtin_amdgcn_sched_barrier(0); \
    __builtin_amdgcn_s_barrier(); \
    __builtin_amdgcn_sched_barrier(0); } while (0)
#define LGKM_BAR() do { \
    __builtin_amdgcn_sched_barrier(0); \
    asm volatile("s_waitcnt lgkmcnt(0)" ::: "memory"); \
    __builtin_amdgcn_s_barrier(); \
    __builtin_amdgcn_sched_barrier(0); } while (0)

// ---------------------------------------------------------------------------
// Prep: transpose w2/wg/wf (F,H_contr,H_out) fp32 -> [f][n_out][h_contr] fp16
// ---------------------------------------------------------------------------
__global__ __launch_bounds__(256) void transpose_w_kernel(
    const float* __restrict__ w2, const float* __restrict__ wg,
    const float* __restrict__ wf, _Float16* __restrict__ wt)
{
    __shared__ float tile[64][65];
    int bid = blockIdx.x;
    int tens = bid >> 9, rem = bid & 511;
    int f = rem >> 4, tl = rem & 15;
    int hb = (tl >> 2) * 64, nb = (tl & 3) * 64;
    const float* src = (tens == 0 ? w2 : (tens == 1 ? wg : wf)) + f * 65536;
    _Float16* dst = wt + (size_t)tens * 2097152 + f * 65536;
    int lane = threadIdx.x & 63, w = threadIdx.x >> 6;
    for (int i = 0; i < 16; ++i) {
        int r = i * 4 + w;
        tile[r][lane] = src[(hb + r) * 256 + nb + lane];
    }
    __syncthreads();
    for (int i = 0; i < 16; ++i) {
        int c = i * 4 + w;
        dst[(nb + c) * 256 + hb + lane] = (_Float16)tile[lane][c];
    }
}

// ---------------------------------------------------------------------------
// Prep: Wcat[n][k] fp16, n<256 from sw1 (8192,256), n in [256,288) from ssw
// ---------------------------------------------------------------------------
__global__ __launch_bounds__(256) void transpose_s_kernel(
    const float* __restrict__ sw1, const float* __restrict__ ssw,
    _Float16* __restrict__ wcat)
{
    __shared__ float tile[64][65];
    int bid = blockIdx.x;
    int lane = threadIdx.x & 63, w = threadIdx.x >> 6;
    if (bid < 512) {
        int k0 = (bid >> 2) * 64, n0 = (bid & 3) * 64;
        for (int i = 0; i < 16; ++i) {
            int r = i * 4 + w;
            tile[r][lane] = sw1[(size_t)(k0 + r) * 256 + n0 + lane];
        }
        __syncthreads();
        for (int i = 0; i < 16; ++i) {
            int c = i * 4 + w;
            wcat[(size_t)(n0 + c) * FH + k0 + lane] = (_Float16)tile[lane][c];
        }
    } else {
        int k0 = (bid - 512) * 64;
        int t = threadIdx.x;
        for (int i = 0; i < 8; ++i) {
            int idx = t + i * 256;
            int r = idx >> 5, cc = idx & 31;
            tile[r][cc] = ssw[(size_t)(k0 + r) * 32 + cc];
        }
        __syncthreads();
        for (int i = 0; i < 8; ++i) {
            int idx = t + i * 256;
            int c = idx >> 6, rr = idx & 63;
            wcat[(size_t)(256 + c) * FH + k0 + rr] = (_Float16)tile[rr][c];
        }
    }
}

// ---------------------------------------------------------------------------
// Fused per-feature GRN v6: v5 structure (proven: XCD-clustered decode,
// ping-pong Bs, counted vmcnt(2)) + epilogue-param PRELOAD: all GLU/LN
// params (bg,bf,ws,bs,gamma,beta) and the x residuals are loaded BEFORE the
// first GRN_STAGE, so they sit OLDEST in the vm FIFO -- every counted
// vmcnt(2) retires them (counting stays exact), and the epilogue issues
// zero global loads. VGPR ~60->~96, still under the 128 4-waves/SIMD cliff.
// ---------------------------------------------------------------------------
__global__ __launch_bounds__(512, 4) void grn_kernel(
    const float* __restrict__ x, const float* __restrict__ w1, const float* __restrict__ b1,
    const float* __restrict__ b2, const float* __restrict__ bg, const float* __restrict__ bfv_,
    const float* __restrict__ gamma, const float* __restrict__ beta,
    const float* __restrict__ wsk, const float* __restrict__ bsk,
    const _Float16* __restrict__ w2t, const _Float16* __restrict__ wgt,
    const _Float16* __restrict__ wft, _Float16* __restrict__ stacked, int tok_base)
{
    __shared__ __align__(16) char smem[65536];
    _Float16* As = (_Float16*)smem;                  // 64 x 256 fp16 swizzled (32KB)
    _Float16* Bs = (_Float16*)(smem + 32768);        // 2 x (256x32) fp16 (32KB)
    float* red = (float*)smem;                       // alias As (post-MFMA): 512 f32
    float* mv  = (float*)(smem + 2048);              // alias As: 128 f32

    // XCD-clustered decode (T1): each XCD owns features [4*xcd, 4*xcd+4)
    const int bid = blockIdx.x;
    const int xcd = bid & 7;
    const int slot = bid >> 3;
    const int f = xcd * 4 + (slot & 3);
    const int tok0 = (slot >> 2) * 64;               // chunk-local
    const int t = threadIdx.x;
    const int wv = t >> 6;
    const int ln = t & 15;
    const int q  = (t >> 4) & 3;
    const int wm = wv >> 2;                          // m-half 0/1
    const int wn = wv & 3;                           // n-quarter 0..3
    const int r0 = wm * 32 + ln;                     // A-frag row, mt=0
    const int r1 = r0 + 16;                          // A-frag row, mt=1

    const _Float16* w2f = w2t + (size_t)f * 65536;
    const _Float16* wgf = wgt + (size_t)f * 65536;
    const _Float16* wff = wft + (size_t)f * 65536;

#define GRN_STAGE(buf, Bsrc, kc) do {                                          \
        const _Float16* _bp = (Bsrc);                                          \
        _Pragma("unroll")                                                      \
        for (int _i = 0; _i < 2; ++_i) {                                       \
            int _s = t + _i * 512;                                             \
            int _row = _s >> 2;                                                \
            int _c = (_s & 3) ^ ((_row >> 1) & 3);                             \
            GLD_LDS(_bp + _row * 256 + (kc) * 32 + _c * 8,                     \
                    Bs + (buf) * 8192 + _s * 8);                               \
        } } while (0)

#define GRN_MFMA(ACC, kc) do {                                                 \
        const _Float16* _B = Bs + ((kc) & 1) * 8192;                           \
        half8 _a0 = *(const half8*)&As[r0 * 256 + ((((kc) * 4 + q) ^ (r0 & 7)) << 3)]; \
        half8 _a1 = *(const half8*)&As[r1 * 256 + ((((kc) * 4 + q) ^ (r1 & 7)) << 3)]; \
        _Pragma("unroll")                                                      \
        for (int _nt = 0; _nt < 4; ++_nt) {                                    \
            int _rb = wn * 64 + _nt * 16 + ln;                                 \
            int _cp = q ^ ((_rb >> 1) & 3);                                    \
            half8 _b8 = *(const half8*)&_B[_rb * 32 + _cp * 8];                \
            ACC[0][_nt] = __builtin_amdgcn_mfma_f32_16x16x32_f16(              \
                _a0, _b8, ACC[0][_nt], 0, 0, 0);                               \
            ACC[1][_nt] = __builtin_amdgcn_mfma_f32_16x16x32_f16(              \
                _a1, _b8, ACC[1][_nt], 0, 0, 0);                               \
        } } while (0)

    // ---- PRELOAD: epilogue params + residual x, oldest in the vm FIFO ----
    float b2v[4], bgp[4], bfp4[4], wsp[4], bsp[4], gap[4], bep[4];
#pragma unroll
    for (int nt = 0; nt < 4; ++nt) {
        int nn = f * H + wn * 64 + nt * 16 + ln;
        b2v[nt] = b2[nn];
        bgp[nt] = bg[nn];   bfp4[nt] = bfv_[nn];
        wsp[nt] = wsk[nn];  bsp[nt]  = bsk[nn];
        gap[nt] = gamma[nn]; bep[nt] = beta[nn];
    }
    float xr[2][4];
#pragma unroll
    for (int mt = 0; mt < 2; ++mt)
#pragma unroll
        for (int r = 0; r < 4; ++r)
            xr[mt][r] = x[(size_t)(tok_base + tok0 + wm * 32 + mt * 16 + q * 4 + r) * F + f];

    GRN_STAGE(0, w2f, 0);                            // first weight tile

    // A = elu(x * w1 + b1) -> As (swizzled). x reads are wave-uniform s_loads.
    {
        const int colE = t & 255;
        const int rgE = __builtin_amdgcn_readfirstlane(t >> 8) * 32;
        const float w1v = w1[f * H + colE];
        const float b1v = b1[f * H + colE];
        const int chE = colE >> 3, elE = colE & 7;
#pragma unroll 8
        for (int i = 0; i < 32; ++i) {
            int row = rgE + i;
            float xv = x[(size_t)(tok_base + tok0 + row) * F + f];
            float z = fmaf(xv, w1v, b1v);
            float e = z > 0.f ? z : (__expf(z) - 1.f);
            As[row * 256 + ((chE ^ (row & 7)) << 3) + elE] = (_Float16)e;
        }
    }
    LGKM_BAR();                                      // As visible; stage in flight

    float4v acc1[2][4];
#pragma unroll
    for (int mt = 0; mt < 2; ++mt)
#pragma unroll
        for (int nt = 0; nt < 4; ++nt)
#pragma unroll
            for (int r = 0; r < 4; ++r) acc1[mt][nt][r] = 0.f;

    // ---- stage 1: h2 = A @ w2 ----
#pragma unroll
    for (int kc = 0; kc < 8; ++kc) {
        if (kc < 7) GRN_STAGE((kc + 1) & 1, w2f, kc + 1);
        else        GRN_STAGE(0, wgf, 0);            // chain into stage 2
        WAITVM2_BAR();
        GRN_MFMA(acc1, kc);
        END_BAR();
    }

    // h2 + b2 -> As (swizzled fp16). No vm-ops here (params preloaded) so
    // the wg-kc0 prefetch stays in flight; lgkm-only barrier.
    {
#pragma unroll
        for (int mt = 0; mt < 2; ++mt)
#pragma unroll
            for (int nt = 0; nt < 4; ++nt) {
                int n = wn * 64 + nt * 16 + ln;
#pragma unroll
                for (int r = 0; r < 4; ++r) {
                    int row = wm * 32 + mt * 16 + q * 4 + r;
                    As[row * 256 + (((n >> 3) ^ (row & 7)) << 3) + (n & 7)] =
                        (_Float16)(acc1[mt][nt][r] + b2v[nt]);
                }
            }
    }
    LGKM_BAR();

    float4v accG[2][4], accF[2][4];
#pragma unroll
    for (int mt = 0; mt < 2; ++mt)
#pragma unroll
        for (int nt = 0; nt < 4; ++nt)
#pragma unroll
            for (int r = 0; r < 4; ++r) { accG[mt][nt][r] = 0.f; accF[mt][nt][r] = 0.f; }

    // ---- stage 2a: Cg = h2 @ wg ----
#pragma unroll
    for (int kc = 0; kc < 8; ++kc) {
        if (kc < 7) GRN_STAGE((kc + 1) & 1, wgf, kc + 1);
        else        GRN_STAGE(0, wff, 0);            // chain into wf
        WAITVM2_BAR();
        GRN_MFMA(accG, kc);
        END_BAR();
    }
    // ---- stage 2b: Cf = h2 @ wf ----
#pragma unroll
    for (int kc = 0; kc < 8; ++kc) {
        if (kc < 7) {
            GRN_STAGE((kc + 1) & 1, wff, kc + 1);
            WAITVM2_BAR();
        } else {
            WAITVM0_BAR();                           // final drain
        }
        GRN_MFMA(accF, kc);
        END_BAR();
    }
#undef GRN_STAGE
#undef GRN_MFMA

    // ---- GLU + residual, in registers (y overwrites accG); zero vm-ops ----
#pragma unroll
    for (int nt = 0; nt < 4; ++nt) {
#pragma unroll
        for (int mt = 0; mt < 2; ++mt)
#pragma unroll
            for (int r = 0; r < 4; ++r) {
                float cg = accG[mt][nt][r] + bgp[nt];
                float cf = accF[mt][nt][r] + bfp4[nt];
                float sig = 1.f / (1.f + __expf(-cg));
                accG[mt][nt][r] = sig * cf + xr[mt][r] * wsp[nt] + bsp[nt];
            }
    }

    // ---- LN sums fused from registers ----
#pragma unroll
    for (int mt = 0; mt < 2; ++mt)
#pragma unroll
        for (int r = 0; r < 4; ++r) {
            float v0 = accG[mt][0][r], v1 = accG[mt][1][r];
            float v2 = accG[mt][2][r], v3 = accG[mt][3][r];
            float s1 = (v0 + v1) + (v2 + v3);
            float s2 = (v0 * v0 + v1 * v1) + (v2 * v2 + v3 * v3);
#pragma unroll
            for (int m = 1; m <= 8; m <<= 1) {
                s1 += __shfl_xor(s1, m, 64);
                s2 += __shfl_xor(s2, m, 64);
            }
            if (ln == 0) {
                int row = wm * 32 + mt * 16 + q * 4 + r;
                red[row * 4 + wn] = s1;
                red[256 + row * 4 + wn] = s2;
            }
        }
    __syncthreads();
    if (t < 64) {
        float a = (red[t * 4] + red[t * 4 + 1]) + (red[t * 4 + 2] + red[t * 4 + 3]);
        float b = (red[256 + t * 4] + red[256 + t * 4 + 1])
                + (red[256 + t * 4 + 2] + red[256 + t * 4 + 3]);
        float mean = a * (1.f / 256.f);
        float var = b * (1.f / 256.f) - mean * mean;
        mv[t] = mean;
        mv[64 + t] = rsqrtf(var + 1e-5f);
    }
    __syncthreads();

    // ---- normalize + scale from registers, store fp16 ----
    float mr[2][4], rr[2][4];
#pragma unroll
    for (int mt = 0; mt < 2; ++mt)
#pragma unroll
        for (int r = 0; r < 4; ++r) {
            int row = wm * 32 + mt * 16 + q * 4 + r;
            mr[mt][r] = mv[row];
            rr[mt][r] = mv[64 + row];
        }
#pragma unroll
    for (int nt = 0; nt < 4; ++nt) {
        int n = wn * 64 + nt * 16 + ln;
#pragma unroll
        for (int mt = 0; mt < 2; ++mt)
#pragma unroll
            for (int r = 0; r < 4; ++r) {
                int row = wm * 32 + mt * 16 + q * 4 + r;
                float vv = (accG[mt][nt][r] - mr[mt][r]) * rr[mt][r] * gap[nt] + bep[nt];
                stacked[(size_t)(tok0 + row) * FH + f * H + n] = (_Float16)vv;
            }
    }
}

// ---------------------------------------------------------------------------
// Selection GEMM v4 (unchanged): XCD-clustered decode, A double-buffered via
// global_load_lds + XOR swizzle, B straight to registers, static indexing.
// ---------------------------------------------------------------------------
__global__ __launch_bounds__(256, 3) void sel_gemm_kernel(
    const _Float16* __restrict__ stacked, const _Float16* __restrict__ wcat,
    float* __restrict__ sh_part, float* __restrict__ sres_part, int C)
{
    __shared__ __align__(16) _Float16 As2[2][64 * 64];   // 2 x 8 KB
    const int t = threadIdx.x;
    const int wv = t >> 6;
    const int ln = t & 15, q = (t & 63) >> 4;
    const int bid = blockIdx.x;
    const int xcd = bid & 7;
    const int slot = bid >> 3;
    const int kb = xcd >> 1;                             // k-slice 0..3
    const int tok0 = (slot * 2 + (xcd & 1)) * 64;        // chunk-local

    const int s1 = t + 256;
    const int row0 = t >> 3,  c0 = ((t & 7) ^ (row0 & 7)) * 8;
    const int row1 = s1 >> 3, c1 = ((s1 & 7) ^ (row1 & 7)) * 8;
    const _Float16* a0src = stacked + (size_t)(tok0 + row0) * FH + kb * 2048 + c0;
    const _Float16* a1src = stacked + (size_t)(tok0 + row1) * FH + kb * 2048 + c1;

    float4v acc[4][5];
#pragma unroll
    for (int mt = 0; mt < 4; ++mt)
#pragma unroll
        for (int i = 0; i < 5; ++i)
#pragma unroll
            for (int r = 0; r < 4; ++r) acc[mt][i][r] = 0.f;

    GLD_LDS(a0src, &As2[0][t * 8]);
    GLD_LDS(a1src, &As2[0][s1 * 8]);
    __syncthreads();

    for (int kc = 0; kc < 32; ++kc) {
        const int cur = kc & 1;
        // ---- B fragments for this K-step: global->reg, issued FIRST ----
        half8 bb0[5], bb1[5];
#define SEL_LOAD(i)                                                            \
        {                                                                      \
            const _Float16* bp = wcat                                          \
                + (size_t)((wv + 4 * (i)) * 16 + ln) * FH                      \
                + kb * 2048 + kc * 64 + q * 8;                                 \
            bb0[i] = *(const half8*)bp;                                        \
            bb1[i] = *(const half8*)(bp + 32);                                 \
        }
        SEL_LOAD(0) SEL_LOAD(1) SEL_LOAD(2) SEL_LOAD(3)
        if (wv < 2) SEL_LOAD(4)
#undef SEL_LOAD
        // ---- prefetch next A tile into the other buffer ----
        if (kc < 31) {
            GLD_LDS(a0src + (kc + 1) * 64, &As2[cur ^ 1][t * 8]);
            GLD_LDS(a1src + (kc + 1) * 64, &As2[cur ^ 1][s1 * 8]);
        }
        // ---- A fragments from LDS (swizzled, conflict-free) ----
        const _Float16* As = As2[cur];
        half8 af0[4], af1[4];
#pragma unroll
        for (int mt = 0; mt < 4; ++mt) {
            int row = mt * 16 + ln;
            af0[mt] = *(const half8*)&As[row * 64 + ((q ^ (row & 7)) * 8)];
            af1[mt] = *(const half8*)&As[row * 64 + (((4 + q) ^ (row & 7)) * 8)];
        }
        // ---- MFMA, fully static indexing ----
#define SEL_FMA(i)                                                            \
        {                                                                      \
            _Pragma("unroll")                                                  \
            for (int mt = 0; mt < 4; ++mt)                                     \
                acc[mt][i] = __builtin_amdgcn_mfma_f32_16x16x32_f16(           \
                    af0[mt], bb0[i], acc[mt][i], 0, 0, 0);                     \
            _Pragma("unroll")                                                  \
            for (int mt = 0; mt < 4; ++mt)                                     \
                acc[mt][i] = __builtin_amdgcn_mfma_f32_16x16x32_f16(           \
                    af1[mt], bb1[i], acc[mt][i], 0, 0, 0);                     \
        }
        SEL_FMA(0) SEL_FMA(1) SEL_FMA(2) SEL_FMA(3)
        if (wv < 2) SEL_FMA(4)
#undef SEL_FMA
        __syncthreads();   // drains prefetch; all waves done reading buf[cur]
    }

    // ---- epilogue: plain stores, static branches ----
    float* shp = sh_part + (size_t)kb * ((size_t)C * 256);
    float* srp = sres_part + (size_t)kb * ((size_t)C * 32);
#pragma unroll
    for (int i = 0; i < 4; ++i) {
        int n = (wv + 4 * i) * 16 + ln;                  // always < 256
#pragma unroll
        for (int mt = 0; mt < 4; ++mt)
#pragma unroll
            for (int r = 0; r < 4; ++r) {
                int m = tok0 + mt * 16 + q * 4 + r;
                shp[(size_t)m * 256 + n] = acc[mt][i][r];
            }
    }
    if (wv < 2) {                                        // tile 4 = sres cols
        int n = wv * 16 + ln;                            // 0..31
#pragma unroll
        for (int mt = 0; mt < 4; ++mt)
#pragma unroll
            for (int r = 0; r < 4; ++r) {
                int m = tok0 + mt * 16 + q * 4 + r;
                srp[(size_t)m * 32 + n] = acc[mt][4][r];
            }
    }
}

// ---------------------------------------------------------------------------
// Fused selection tail v2 + weighted sum. Block = 8 tokens.
// This round: vectorized memory phases (G13).
//  - split-K reduce + elu: float4 over all 4 slices (2 iters vs 8 scalar);
//    shv pad 257->260 keeps rows 16B-aligned for float4 stores.
//  - weighted sum: each thread owns 4 consecutive out columns of 2 tokens;
//    half4 stacked reads (8B/lane) + float4 out stores (16B/lane) --
//    64 vector loads/thread vs 256 scalar fp16 loads. Same summation order.
// ---------------------------------------------------------------------------
__global__ __launch_bounds__(256) void tail_kernel(
    const float* __restrict__ sh_part, const float* __restrict__ sres_part,
    const _Float16* __restrict__ stacked,
    const float* __restrict__ sb1, const float* __restrict__ ssb,
    const float* __restrict__ sw2, const float* __restrict__ sb2,
    const float* __restrict__ swg, const float* __restrict__ sbg,
    const float* __restrict__ swf, const float* __restrict__ sbf,
    const float* __restrict__ sgam, const float* __restrict__ sbet,
    float* __restrict__ out, int tok_base, int C)
{
    __shared__ float sw2s[256 * 32];                    // 32 KB
    __shared__ float swgs[1024], swfs[1024];            // 8 KB
    __shared__ float shv[8][260];                       // 8 tokens x 256 (16B-aligned rows)
    __shared__ float wls[8][33];
    const int t = threadIdx.x;
    const size_t shS = (size_t)C * 256;
    const size_t srS = (size_t)C * 32;
    for (int i = 0; i < 32; ++i) sw2s[t + i * 256] = sw2[t + i * 256];
    for (int i = 0; i < 4; ++i) {
        swgs[t + i * 256] = swg[t + i * 256];
        swfs[t + i * 256] = swf[t + i * 256];
    }
    // reduce split-K partials + bias, elu (float4-vectorized; same add order)
#pragma unroll
    for (int i = 0; i < 2; ++i) {
        int slot = t + i * 256;                         // 0..511
        int gg = slot >> 6;                             // token 0..7
        int c4 = (slot & 63) * 4;                       // col 0..252
        size_t o = (size_t)(blockIdx.x * 8 + gg) * 256 + c4;
        float4v z = *(const float4v*)&sb1[c4];
        z += *(const float4v*)&sh_part[o];
        z += *(const float4v*)&sh_part[shS + o];
        z += *(const float4v*)&sh_part[2 * shS + o];
        z += *(const float4v*)&sh_part[3 * shS + o];
        float4v e;
#pragma unroll
        for (int j = 0; j < 4; ++j)
            e[j] = z[j] > 0.f ? z[j] : (__expf(z[j]) - 1.f);
        *(float4v*)&shv[gg][c4] = e;
    }
    __syncthreads();
    const int g = t >> 5;                               // token group 0..7
    const int j = t & 31;                               // feature index
    const int token = blockIdx.x * 8 + g;               // chunk-local
    // fc2: 256 -> 32
    float p = sb2[j];
    for (int k = 0; k < 256; ++k) p += shv[g][k] * sw2s[k * 32 + j];
    // GLU via width-32 shuffles
    float gacc = sbg[j], uacc = sbf[j];
#pragma unroll 8
    for (int i = 0; i < 32; ++i) {
        float tv = __shfl(p, i, 32);
        gacc += tv * swgs[i * 32 + j];
        uacc += tv * swfs[i * 32 + j];
    }
    float sig = 1.f / (1.f + __expf(-gacc));
    size_t o2 = (size_t)token * 32 + j;
    float sresv = ssb[j] + sres_part[o2] + sres_part[srS + o2]
                + sres_part[2 * srS + o2] + sres_part[3 * srS + o2];
    float sv = sresv + sig * uacc;
    // LayerNorm over 32 lanes
    float s1 = sv, s2 = sv * sv;
    for (int off = 16; off; off >>= 1) {
        s1 += __shfl_xor(s1, off, 32);
        s2 += __shfl_xor(s2, off, 32);
    }
    float mean = s1 * (1.f / 32.f);
    float var = s2 * (1.f / 32.f) - mean * mean;
    float v = (sv - mean) * rsqrtf(var + 1e-5f) * sgam[j] + sbet[j];
    // softmax over 32 lanes
    float mx = v;
    for (int off = 16; off; off >>= 1) mx = fmaxf(mx, __shfl_xor(mx, off, 32));
    float e = __expf(v - mx);
    float ssum = e;
    for (int off = 16; off; off >>= 1) ssum += __shfl_xor(ssum, off, 32);
    wls[g][j] = e / ssum;
    __syncthreads();
    // weighted sum: thread -> 4 consecutive cols of 2 tokens (vectorized)
    {
        const int tg = t >> 6;                          // 0..3
        const int c4 = (t & 63) * 4;                    // col 0..252
#pragma unroll
        for (int tt = 0; tt < 2; ++tt) {
            int tk = tg * 2 + tt;
            const _Float16* sp = stacked + (size_t)(blockIdx.x * 8 + tk) * FH;
            float a0 = 0.f, a1 = 0.f, a2 = 0.f, a3 = 0.f;
#pragma unroll
            for (int f = 0; f < 32; ++f) {
                half4v vv = *(const half4v*)&sp[f * 256 + c4];
                float w = wls[tk][f];
                a0 += (float)vv[0] * w;
                a1 += (float)vv[1] * w;
                a2 += (float)vv[2] * w;
                a3 += (float)vv[3] * w;
            }
            float4v ov; ov[0] = a0; ov[1] = a1; ov[2] = a2; ov[3] = a3;
            *(float4v*)&out[(size_t)(tok_base + blockIdx.x * 8 + tk) * 256 + c4] = ov;
        }
    }
}

// ---------------------------------------------------------------------------
extern "C" void kernel_launch(void* const* d_in, const int* in_sizes, int n_in,
                              void* d_out, int out_size, void* d_ws, size_t ws_size,
                              hipStream_t stream)
{
    (void)in_sizes; (void)n_in; (void)out_size;
    const float* x    = (const float*)d_in[0];
    const float* w1   = (const float*)d_in[1];
    const float* b1   = (const float*)d_in[2];
    const float* w2   = (const float*)d_in[3];
    const float* b2   = (const float*)d_in[4];
    const float* wg   = (const float*)d_in[5];
    const float* bg   = (const float*)d_in[6];
    const float* wf   = (const float*)d_in[7];
    const float* bfp  = (const float*)d_in[8];
    const float* gamma= (const float*)d_in[9];
    const float* beta = (const float*)d_in[10];
    const float* wsk  = (const float*)d_in[11];
    const float* bsk  = (const float*)d_in[12];
    const float* sw1  = (const float*)d_in[13];
    const float* sb1  = (const float*)d_in[14];
    const float* sw2  = (const float*)d_in[15];
    const float* sb2  = (const float*)d_in[16];
    const float* swg  = (const float*)d_in[17];
    const float* sbg  = (const float*)d_in[18];
    const float* swf  = (const float*)d_in[19];
    const float* sbf  = (const float*)d_in[20];
    const float* sgam = (const float*)d_in[21];
    const float* sbet = (const float*)d_in[22];
    const float* ssw  = (const float*)d_in[23];
    const float* ssb  = (const float*)d_in[24];

    // ---- workspace layout, chunk size adaptive to ws_size ----
    // per-token: stacked 16384B + sh_part 4*1024B + sres_part 4*128B = 20992B
    const size_t fixedB = 12582912 + 4718592;            // wt (12 MiB) + wcat (4.5 MiB)
    int C = BT;                                          // tokens per chunk
    while (C > 512) {
        size_t need = fixedB + (size_t)C * 20992;
        if (need <= ws_size) break;
        C >>= 1;
    }
    const int nChunks = BT / C;

    char* ws = (char*)d_ws;
    _Float16* wt      = (_Float16*)ws;                                   // 3 x 2M fp16
    _Float16* wcat    = (_Float16*)(ws + 12582912);                      // 288 x 8192 fp16
    char* p = ws + fixedB;
    _Float16* stacked = (_Float16*)p;            p += (size_t)C * FH * 2;
    float* sh_part    = (float*)p;               p += (size_t)C * 256 * 4 * SPLITK;
    float* sres_part  = (float*)p;
    float* out        = (float*)d_out;

    hipLaunchKernelGGL(transpose_w_kernel, dim3(1536), dim3(256), 0, stream, w2, wg, wf, wt);
    hipLaunchKernelGGL(transpose_s_kernel, dim3(640), dim3(256), 0, stream, sw1, ssw, wcat);
    for (int c = 0; c < nChunks; ++c) {
        int tb = c * C;
        hipLaunchKernelGGL(grn_kernel, dim3((C / 64) * 32), dim3(512), 0, stream,
                           x, w1, b1, b2, bg, bfp, gamma, beta, wsk, bsk,
                           wt, wt + 2097152, wt + 2 * 2097152, stacked, tb);
        hipLaunchKernelGGL(sel_gemm_kernel, dim3((C / 64) * SPLITK), dim3(256), 0, stream,
                           stacked, wcat, sh_part, sres_part, C);
        hipLaunchKernelGGL(tail_kernel, dim3(C / 8), dim3(256), 0, stream,
                           sh_part, sres_part, stacked, sb1, ssb, sw2, sb2, swg, sbg, swf, sbf,
                           sgam, sbet, out, tb, C);
    }
}

// Round 12
// 716.577 us; speedup vs baseline: 1.1452x; 1.0160x over previous
//
#include <hip/hip_runtime.h>
#include <hip/hip_bf16.h>
#include <hip/hip_fp16.h>

#define BT 16384
#define F 32
#define H 256
#define FH 8192
#define SPLITK 4

typedef _Float16 half8 __attribute__((ext_vector_type(8)));
typedef _Float16 half4v __attribute__((ext_vector_type(4)));
typedef float float4v __attribute__((ext_vector_type(4)));

#define GLD_LDS(gsrc, ldst) \
    __builtin_amdgcn_global_load_lds( \
        (const __attribute__((address_space(1))) void*)(gsrc), \
        (__attribute__((address_space(3))) void*)(ldst), 16, 0, 0)

// Pipelined-barrier macros (T3/T4): counted vmcnt keeps the prefetch in
// flight ACROSS the barrier; sched_barrier(0) pins ordering (rule #18).
#define WAITVM2_BAR() do { \
    __builtin_amdgcn_sched_barrier(0); \
    asm volatile("s_waitcnt vmcnt(2)" ::: "memory"); \
    __builtin_amdgcn_s_barrier(); \
    __builtin_amdgcn_sched_barrier(0); } while (0)
#define WAITVM0_BAR() do { \
    __builtin_amdgcn_sched_barrier(0); \
    asm volatile("s_waitcnt vmcnt(0)" ::: "memory"); \
    __builtin_amdgcn_s_barrier(); \
    __builtin_amdgcn_sched_barrier(0); } while (0)
#define END_BAR() do { \
    __builtin_amdgcn_sched_barrier(0); \
    __builtin_amdgcn_s_barrier(); \
    __builtin_amdgcn_sched_barrier(0); } while (0)
#define LGKM_BAR() do { \
    __builtin_amdgcn_sched_barrier(0); \
    asm volatile("s_waitcnt lgkmcnt(0)" ::: "memory"); \
    __builtin_amdgcn_s_barrier(); \
    __builtin_amdgcn_sched_barrier(0); } while (0)

// ---------------------------------------------------------------------------
// Prep: transpose w2/wg/wf (F,H_contr,H_out) fp32 -> [f][n_out][h_contr] fp16
// ---------------------------------------------------------------------------
__global__ __launch_bounds__(256) void transpose_w_kernel(
    const float* __restrict__ w2, const float* __restrict__ wg,
    const float* __restrict__ wf, _Float16* __restrict__ wt)
{
    __shared__ float tile[64][65];
    int bid = blockIdx.x;
    int tens = bid >> 9, rem = bid & 511;
    int f = rem >> 4, tl = rem & 15;
    int hb = (tl >> 2) * 64, nb = (tl & 3) * 64;
    const float* src = (tens == 0 ? w2 : (tens == 1 ? wg : wf)) + f * 65536;
    _Float16* dst = wt + (size_t)tens * 2097152 + f * 65536;
    int lane = threadIdx.x & 63, w = threadIdx.x >> 6;
    for (int i = 0; i < 16; ++i) {
        int r = i * 4 + w;
        tile[r][lane] = src[(hb + r) * 256 + nb + lane];
    }
    __syncthreads();
    for (int i = 0; i < 16; ++i) {
        int c = i * 4 + w;
        dst[(nb + c) * 256 + hb + lane] = (_Float16)tile[lane][c];
    }
}

// ---------------------------------------------------------------------------
// Prep: Wcat[n][k] fp16, n<256 from sw1 (8192,256), n in [256,288) from ssw
// ---------------------------------------------------------------------------
__global__ __launch_bounds__(256) void transpose_s_kernel(
    const float* __restrict__ sw1, const float* __restrict__ ssw,
    _Float16* __restrict__ wcat)
{
    __shared__ float tile[64][65];
    int bid = blockIdx.x;
    int lane = threadIdx.x & 63, w = threadIdx.x >> 6;
    if (bid < 512) {
        int k0 = (bid >> 2) * 64, n0 = (bid & 3) * 64;
        for (int i = 0; i < 16; ++i) {
            int r = i * 4 + w;
            tile[r][lane] = sw1[(size_t)(k0 + r) * 256 + n0 + lane];
        }
        __syncthreads();
        for (int i = 0; i < 16; ++i) {
            int c = i * 4 + w;
            wcat[(size_t)(n0 + c) * FH + k0 + lane] = (_Float16)tile[lane][c];
        }
    } else {
        int k0 = (bid - 512) * 64;
        int t = threadIdx.x;
        for (int i = 0; i < 8; ++i) {
            int idx = t + i * 256;
            int r = idx >> 5, cc = idx & 31;
            tile[r][cc] = ssw[(size_t)(k0 + r) * 32 + cc];
        }
        __syncthreads();
        for (int i = 0; i < 8; ++i) {
            int idx = t + i * 256;
            int c = idx >> 6, rr = idx & 63;
            wcat[(size_t)(256 + c) * FH + k0 + rr] = (_Float16)tile[rr][c];
        }
    }
}

// ---------------------------------------------------------------------------
// Fused per-feature GRN v5 (REVERTED from v6): XCD-clustered decode, ping-pong
// Bs, counted vmcnt(2). v6's whole-kernel preload of 36 epilogue params
// spilled to scratch (WRITE_SIZE 131->213 MB, FETCH 15->55 MB, +16 us) --
// the allocator kept VGPR at 64 and spilled the long live ranges. v5 loads
// epilogue params at use time (L2-hot: 32 blocks/XCD share them). Only the
// 4-reg b2v preload survives (short-ish live range, measured clean in r10).
// ---------------------------------------------------------------------------
__global__ __launch_bounds__(512, 4) void grn_kernel(
    const float* __restrict__ x, const float* __restrict__ w1, const float* __restrict__ b1,
    const float* __restrict__ b2, const float* __restrict__ bg, const float* __restrict__ bfv_,
    const float* __restrict__ gamma, const float* __restrict__ beta,
    const float* __restrict__ wsk, const float* __restrict__ bsk,
    const _Float16* __restrict__ w2t, const _Float16* __restrict__ wgt,
    const _Float16* __restrict__ wft, _Float16* __restrict__ stacked, int tok_base)
{
    __shared__ __align__(16) char smem[65536];
    _Float16* As = (_Float16*)smem;                  // 64 x 256 fp16 swizzled (32KB)
    _Float16* Bs = (_Float16*)(smem + 32768);        // 2 x (256x32) fp16 (32KB)
    float* red = (float*)smem;                       // alias As (post-MFMA): 512 f32
    float* mv  = (float*)(smem + 2048);              // alias As: 128 f32

    // XCD-clustered decode (T1): each XCD owns features [4*xcd, 4*xcd+4)
    const int bid = blockIdx.x;
    const int xcd = bid & 7;
    const int slot = bid >> 3;
    const int f = xcd * 4 + (slot & 3);
    const int tok0 = (slot >> 2) * 64;               // chunk-local
    const int t = threadIdx.x;
    const int wv = t >> 6;
    const int ln = t & 15;
    const int q  = (t >> 4) & 3;
    const int wm = wv >> 2;                          // m-half 0/1
    const int wn = wv & 3;                           // n-quarter 0..3
    const int r0 = wm * 32 + ln;                     // A-frag row, mt=0
    const int r1 = r0 + 16;                          // A-frag row, mt=1

    const _Float16* w2f = w2t + (size_t)f * 65536;
    const _Float16* wgf = wgt + (size_t)f * 65536;
    const _Float16* wff = wft + (size_t)f * 65536;

#define GRN_STAGE(buf, Bsrc, kc) do {                                          \
        const _Float16* _bp = (Bsrc);                                          \
        _Pragma("unroll")                                                      \
        for (int _i = 0; _i < 2; ++_i) {                                       \
            int _s = t + _i * 512;                                             \
            int _row = _s >> 2;                                                \
            int _c = (_s & 3) ^ ((_row >> 1) & 3);                             \
            GLD_LDS(_bp + _row * 256 + (kc) * 32 + _c * 8,                     \
                    Bs + (buf) * 8192 + _s * 8);                               \
        } } while (0)

#define GRN_MFMA(ACC, kc) do {                                                 \
        const _Float16* _B = Bs + ((kc) & 1) * 8192;                           \
        half8 _a0 = *(const half8*)&As[r0 * 256 + ((((kc) * 4 + q) ^ (r0 & 7)) << 3)]; \
        half8 _a1 = *(const half8*)&As[r1 * 256 + ((((kc) * 4 + q) ^ (r1 & 7)) << 3)]; \
        _Pragma("unroll")                                                      \
        for (int _nt = 0; _nt < 4; ++_nt) {                                    \
            int _rb = wn * 64 + _nt * 16 + ln;                                 \
            int _cp = q ^ ((_rb >> 1) & 3);                                    \
            half8 _b8 = *(const half8*)&_B[_rb * 32 + _cp * 8];                \
            ACC[0][_nt] = __builtin_amdgcn_mfma_f32_16x16x32_f16(              \
                _a0, _b8, ACC[0][_nt], 0, 0, 0);                               \
            ACC[1][_nt] = __builtin_amdgcn_mfma_f32_16x16x32_f16(              \
                _a1, _b8, ACC[1][_nt], 0, 0, 0);                               \
        } } while (0)

    // b2 preloaded (oldest in vm FIFO; retired by the first counted wait)
    float b2v[4];
#pragma unroll
    for (int nt = 0; nt < 4; ++nt) b2v[nt] = b2[f * H + wn * 64 + nt * 16 + ln];

    GRN_STAGE(0, w2f, 0);                            // first weight tile

    // A = elu(x * w1 + b1) -> As (swizzled). x reads are wave-uniform s_loads.
    {
        const int colE = t & 255;
        const int rgE = __builtin_amdgcn_readfirstlane(t >> 8) * 32;
        const float w1v = w1[f * H + colE];
        const float b1v = b1[f * H + colE];
        const int chE = colE >> 3, elE = colE & 7;
#pragma unroll 8
        for (int i = 0; i < 32; ++i) {
            int row = rgE + i;
            float xv = x[(size_t)(tok_base + tok0 + row) * F + f];
            float z = fmaf(xv, w1v, b1v);
            float e = z > 0.f ? z : (__expf(z) - 1.f);
            As[row * 256 + ((chE ^ (row & 7)) << 3) + elE] = (_Float16)e;
        }
    }
    LGKM_BAR();                                      // As visible; stage in flight

    float4v acc1[2][4];
#pragma unroll
    for (int mt = 0; mt < 2; ++mt)
#pragma unroll
        for (int nt = 0; nt < 4; ++nt)
#pragma unroll
            for (int r = 0; r < 4; ++r) acc1[mt][nt][r] = 0.f;

    // ---- stage 1: h2 = A @ w2 ----
#pragma unroll
    for (int kc = 0; kc < 8; ++kc) {
        if (kc < 7) GRN_STAGE((kc + 1) & 1, w2f, kc + 1);
        else        GRN_STAGE(0, wgf, 0);            // chain into stage 2
        WAITVM2_BAR();
        GRN_MFMA(acc1, kc);
        END_BAR();
    }

    // h2 + b2 -> As (swizzled fp16). No vm-ops here (b2 preloaded) so the
    // wg-kc0 prefetch stays in flight; lgkm-only barrier.
    {
#pragma unroll
        for (int mt = 0; mt < 2; ++mt)
#pragma unroll
            for (int nt = 0; nt < 4; ++nt) {
                int n = wn * 64 + nt * 16 + ln;
#pragma unroll
                for (int r = 0; r < 4; ++r) {
                    int row = wm * 32 + mt * 16 + q * 4 + r;
                    As[row * 256 + (((n >> 3) ^ (row & 7)) << 3) + (n & 7)] =
                        (_Float16)(acc1[mt][nt][r] + b2v[nt]);
                }
            }
    }
    LGKM_BAR();

    float4v accG[2][4], accF[2][4];
#pragma unroll
    for (int mt = 0; mt < 2; ++mt)
#pragma unroll
        for (int nt = 0; nt < 4; ++nt)
#pragma unroll
            for (int r = 0; r < 4; ++r) { accG[mt][nt][r] = 0.f; accF[mt][nt][r] = 0.f; }

    // ---- stage 2a: Cg = h2 @ wg ----
#pragma unroll
    for (int kc = 0; kc < 8; ++kc) {
        if (kc < 7) GRN_STAGE((kc + 1) & 1, wgf, kc + 1);
        else        GRN_STAGE(0, wff, 0);            // chain into wf
        WAITVM2_BAR();
        GRN_MFMA(accG, kc);
        END_BAR();
    }
    // ---- stage 2b: Cf = h2 @ wf ----
#pragma unroll
    for (int kc = 0; kc < 8; ++kc) {
        if (kc < 7) {
            GRN_STAGE((kc + 1) & 1, wff, kc + 1);
            WAITVM2_BAR();
        } else {
            WAITVM0_BAR();                           // final drain
        }
        GRN_MFMA(accF, kc);
        END_BAR();
    }
#undef GRN_STAGE
#undef GRN_MFMA

    // ---- GLU + residual, in registers (y overwrites accG) ----
    float xr[2][4];
#pragma unroll
    for (int mt = 0; mt < 2; ++mt)
#pragma unroll
        for (int r = 0; r < 4; ++r)
            xr[mt][r] = x[(size_t)(tok_base + tok0 + wm * 32 + mt * 16 + q * 4 + r) * F + f];
#pragma unroll
    for (int nt = 0; nt < 4; ++nt) {
        int nn = f * H + wn * 64 + nt * 16 + ln;
        float bgv = bg[nn], bfv = bfv_[nn], wsv = wsk[nn], bsv = bsk[nn];
#pragma unroll
        for (int mt = 0; mt < 2; ++mt)
#pragma unroll
            for (int r = 0; r < 4; ++r) {
                float cg = accG[mt][nt][r] + bgv;
                float cf = accF[mt][nt][r] + bfv;
                float sig = 1.f / (1.f + __expf(-cg));
                accG[mt][nt][r] = sig * cf + xr[mt][r] * wsv + bsv;
            }
    }

    // ---- LN sums fused from registers ----
#pragma unroll
    for (int mt = 0; mt < 2; ++mt)
#pragma unroll
        for (int r = 0; r < 4; ++r) {
            float v0 = accG[mt][0][r], v1 = accG[mt][1][r];
            float v2 = accG[mt][2][r], v3 = accG[mt][3][r];
            float s1 = (v0 + v1) + (v2 + v3);
            float s2 = (v0 * v0 + v1 * v1) + (v2 * v2 + v3 * v3);
#pragma unroll
            for (int m = 1; m <= 8; m <<= 1) {
                s1 += __shfl_xor(s1, m, 64);
                s2 += __shfl_xor(s2, m, 64);
            }
            if (ln == 0) {
                int row = wm * 32 + mt * 16 + q * 4 + r;
                red[row * 4 + wn] = s1;
                red[256 + row * 4 + wn] = s2;
            }
        }
    __syncthreads();
    if (t < 64) {
        float a = (red[t * 4] + red[t * 4 + 1]) + (red[t * 4 + 2] + red[t * 4 + 3]);
        float b = (red[256 + t * 4] + red[256 + t * 4 + 1])
                + (red[256 + t * 4 + 2] + red[256 + t * 4 + 3]);
        float mean = a * (1.f / 256.f);
        float var = b * (1.f / 256.f) - mean * mean;
        mv[t] = mean;
        mv[64 + t] = rsqrtf(var + 1e-5f);
    }
    __syncthreads();

    // ---- normalize + scale from registers, store fp16 ----
    float mr[2][4], rr[2][4];
#pragma unroll
    for (int mt = 0; mt < 2; ++mt)
#pragma unroll
        for (int r = 0; r < 4; ++r) {
            int row = wm * 32 + mt * 16 + q * 4 + r;
            mr[mt][r] = mv[row];
            rr[mt][r] = mv[64 + row];
        }
#pragma unroll
    for (int nt = 0; nt < 4; ++nt) {
        int n = wn * 64 + nt * 16 + ln;
        float gv = gamma[f * H + n], bvv = beta[f * H + n];
#pragma unroll
        for (int mt = 0; mt < 2; ++mt)
#pragma unroll
            for (int r = 0; r < 4; ++r) {
                int row = wm * 32 + mt * 16 + q * 4 + r;
                float vv = (accG[mt][nt][r] - mr[mt][r]) * rr[mt][r] * gv + bvv;
                stacked[(size_t)(tok0 + row) * FH + f * H + n] = (_Float16)vv;
            }
    }
}

// ---------------------------------------------------------------------------
// Selection GEMM v4 (unchanged): XCD-clustered decode, A double-buffered via
// global_load_lds + XOR swizzle, B straight to registers, static indexing.
// ---------------------------------------------------------------------------
__global__ __launch_bounds__(256, 3) void sel_gemm_kernel(
    const _Float16* __restrict__ stacked, const _Float16* __restrict__ wcat,
    float* __restrict__ sh_part, float* __restrict__ sres_part, int C)
{
    __shared__ __align__(16) _Float16 As2[2][64 * 64];   // 2 x 8 KB
    const int t = threadIdx.x;
    const int wv = t >> 6;
    const int ln = t & 15, q = (t & 63) >> 4;
    const int bid = blockIdx.x;
    const int xcd = bid & 7;
    const int slot = bid >> 3;
    const int kb = xcd >> 1;                             // k-slice 0..3
    const int tok0 = (slot * 2 + (xcd & 1)) * 64;        // chunk-local

    const int s1 = t + 256;
    const int row0 = t >> 3,  c0 = ((t & 7) ^ (row0 & 7)) * 8;
    const int row1 = s1 >> 3, c1 = ((s1 & 7) ^ (row1 & 7)) * 8;
    const _Float16* a0src = stacked + (size_t)(tok0 + row0) * FH + kb * 2048 + c0;
    const _Float16* a1src = stacked + (size_t)(tok0 + row1) * FH + kb * 2048 + c1;

    float4v acc[4][5];
#pragma unroll
    for (int mt = 0; mt < 4; ++mt)
#pragma unroll
        for (int i = 0; i < 5; ++i)
#pragma unroll
            for (int r = 0; r < 4; ++r) acc[mt][i][r] = 0.f;

    GLD_LDS(a0src, &As2[0][t * 8]);
    GLD_LDS(a1src, &As2[0][s1 * 8]);
    __syncthreads();

    for (int kc = 0; kc < 32; ++kc) {
        const int cur = kc & 1;
        // ---- B fragments for this K-step: global->reg, issued FIRST ----
        half8 bb0[5], bb1[5];
#define SEL_LOAD(i)                                                            \
        {                                                                      \
            const _Float16* bp = wcat                                          \
                + (size_t)((wv + 4 * (i)) * 16 + ln) * FH                      \
                + kb * 2048 + kc * 64 + q * 8;                                 \
            bb0[i] = *(const half8*)bp;                                        \
            bb1[i] = *(const half8*)(bp + 32);                                 \
        }
        SEL_LOAD(0) SEL_LOAD(1) SEL_LOAD(2) SEL_LOAD(3)
        if (wv < 2) SEL_LOAD(4)
#undef SEL_LOAD
        // ---- prefetch next A tile into the other buffer ----
        if (kc < 31) {
            GLD_LDS(a0src + (kc + 1) * 64, &As2[cur ^ 1][t * 8]);
            GLD_LDS(a1src + (kc + 1) * 64, &As2[cur ^ 1][s1 * 8]);
        }
        // ---- A fragments from LDS (swizzled, conflict-free) ----
        const _Float16* As = As2[cur];
        half8 af0[4], af1[4];
#pragma unroll
        for (int mt = 0; mt < 4; ++mt) {
            int row = mt * 16 + ln;
            af0[mt] = *(const half8*)&As[row * 64 + ((q ^ (row & 7)) * 8)];
            af1[mt] = *(const half8*)&As[row * 64 + (((4 + q) ^ (row & 7)) * 8)];
        }
        // ---- MFMA, fully static indexing ----
#define SEL_FMA(i)                                                            \
        {                                                                      \
            _Pragma("unroll")                                                  \
            for (int mt = 0; mt < 4; ++mt)                                     \
                acc[mt][i] = __builtin_amdgcn_mfma_f32_16x16x32_f16(           \
                    af0[mt], bb0[i], acc[mt][i], 0, 0, 0);                     \
            _Pragma("unroll")                                                  \
            for (int mt = 0; mt < 4; ++mt)                                     \
                acc[mt][i] = __builtin_amdgcn_mfma_f32_16x16x32_f16(           \
                    af1[mt], bb1[i], acc[mt][i], 0, 0, 0);                     \
        }
        SEL_FMA(0) SEL_FMA(1) SEL_FMA(2) SEL_FMA(3)
        if (wv < 2) SEL_FMA(4)
#undef SEL_FMA
        __syncthreads();   // drains prefetch; all waves done reading buf[cur]
    }

    // ---- epilogue: plain stores, static branches ----
    float* shp = sh_part + (size_t)kb * ((size_t)C * 256);
    float* srp = sres_part + (size_t)kb * ((size_t)C * 32);
#pragma unroll
    for (int i = 0; i < 4; ++i) {
        int n = (wv + 4 * i) * 16 + ln;                  // always < 256
#pragma unroll
        for (int mt = 0; mt < 4; ++mt)
#pragma unroll
            for (int r = 0; r < 4; ++r) {
                int m = tok0 + mt * 16 + q * 4 + r;
                shp[(size_t)m * 256 + n] = acc[mt][i][r];
            }
    }
    if (wv < 2) {                                        // tile 4 = sres cols
        int n = wv * 16 + ln;                            // 0..31
#pragma unroll
        for (int mt = 0; mt < 4; ++mt)
#pragma unroll
            for (int r = 0; r < 4; ++r) {
                int m = tok0 + mt * 16 + q * 4 + r;
                srp[(size_t)m * 32 + n] = acc[mt][4][r];
            }
    }
}

// ---------------------------------------------------------------------------
// Fused selection tail v2 (unchanged from r11 -- measured good): vectorized
// split-K reduce (float4) + vectorized weighted sum (half4/float4).
// ---------------------------------------------------------------------------
__global__ __launch_bounds__(256) void tail_kernel(
    const float* __restrict__ sh_part, const float* __restrict__ sres_part,
    const _Float16* __restrict__ stacked,
    const float* __restrict__ sb1, const float* __restrict__ ssb,
    const float* __restrict__ sw2, const float* __restrict__ sb2,
    const float* __restrict__ swg, const float* __restrict__ sbg,
    const float* __restrict__ swf, const float* __restrict__ sbf,
    const float* __restrict__ sgam, const float* __restrict__ sbet,
    float* __restrict__ out, int tok_base, int C)
{
    __shared__ float sw2s[256 * 32];                    // 32 KB
    __shared__ float swgs[1024], swfs[1024];            // 8 KB
    __shared__ float shv[8][260];                       // 8 tokens x 256 (16B-aligned rows)
    __shared__ float wls[8][33];
    const int t = threadIdx.x;
    const size_t shS = (size_t)C * 256;
    const size_t srS = (size_t)C * 32;
    for (int i = 0; i < 32; ++i) sw2s[t + i * 256] = sw2[t + i * 256];
    for (int i = 0; i < 4; ++i) {
        swgs[t + i * 256] = swg[t + i * 256];
        swfs[t + i * 256] = swf[t + i * 256];
    }
    // reduce split-K partials + bias, elu (float4-vectorized; same add order)
#pragma unroll
    for (int i = 0; i < 2; ++i) {
        int slot = t + i * 256;                         // 0..511
        int gg = slot >> 6;                             // token 0..7
        int c4 = (slot & 63) * 4;                       // col 0..252
        size_t o = (size_t)(blockIdx.x * 8 + gg) * 256 + c4;
        float4v z = *(const float4v*)&sb1[c4];
        z += *(const float4v*)&sh_part[o];
        z += *(const float4v*)&sh_part[shS + o];
        z += *(const float4v*)&sh_part[2 * shS + o];
        z += *(const float4v*)&sh_part[3 * shS + o];
        float4v e;
#pragma unroll
        for (int j = 0; j < 4; ++j)
            e[j] = z[j] > 0.f ? z[j] : (__expf(z[j]) - 1.f);
        *(float4v*)&shv[gg][c4] = e;
    }
    __syncthreads();
    const int g = t >> 5;                               // token group 0..7
    const int j = t & 31;                               // feature index
    const int token = blockIdx.x * 8 + g;               // chunk-local
    // fc2: 256 -> 32
    float p = sb2[j];
    for (int k = 0; k < 256; ++k) p += shv[g][k] * sw2s[k * 32 + j];
    // GLU via width-32 shuffles
    float gacc = sbg[j], uacc = sbf[j];
#pragma unroll 8
    for (int i = 0; i < 32; ++i) {
        float tv = __shfl(p, i, 32);
        gacc += tv * swgs[i * 32 + j];
        uacc += tv * swfs[i * 32 + j];
    }
    float sig = 1.f / (1.f + __expf(-gacc));
    size_t o2 = (size_t)token * 32 + j;
    float sresv = ssb[j] + sres_part[o2] + sres_part[srS + o2]
                + sres_part[2 * srS + o2] + sres_part[3 * srS + o2];
    float sv = sresv + sig * uacc;
    // LayerNorm over 32 lanes
    float s1 = sv, s2 = sv * sv;
    for (int off = 16; off; off >>= 1) {
        s1 += __shfl_xor(s1, off, 32);
        s2 += __shfl_xor(s2, off, 32);
    }
    float mean = s1 * (1.f / 32.f);
    float var = s2 * (1.f / 32.f) - mean * mean;
    float v = (sv - mean) * rsqrtf(var + 1e-5f) * sgam[j] + sbet[j];
    // softmax over 32 lanes
    float mx = v;
    for (int off = 16; off; off >>= 1) mx = fmaxf(mx, __shfl_xor(mx, off, 32));
    float e = __expf(v - mx);
    float ssum = e;
    for (int off = 16; off; off >>= 1) ssum += __shfl_xor(ssum, off, 32);
    wls[g][j] = e / ssum;
    __syncthreads();
    // weighted sum: thread -> 4 consecutive cols of 2 tokens (vectorized)
    {
        const int tg = t >> 6;                          // 0..3
        const int c4 = (t & 63) * 4;                    // col 0..252
#pragma unroll
        for (int tt = 0; tt < 2; ++tt) {
            int tk = tg * 2 + tt;
            const _Float16* sp = stacked + (size_t)(blockIdx.x * 8 + tk) * FH;
            float a0 = 0.f, a1 = 0.f, a2 = 0.f, a3 = 0.f;
#pragma unroll
            for (int f = 0; f < 32; ++f) {
                half4v vv = *(const half4v*)&sp[f * 256 + c4];
                float w = wls[tk][f];
                a0 += (float)vv[0] * w;
                a1 += (float)vv[1] * w;
                a2 += (float)vv[2] * w;
                a3 += (float)vv[3] * w;
            }
            float4v ov; ov[0] = a0; ov[1] = a1; ov[2] = a2; ov[3] = a3;
            *(float4v*)&out[(size_t)(tok_base + blockIdx.x * 8 + tk) * 256 + c4] = ov;
        }
    }
}

// ---------------------------------------------------------------------------
extern "C" void kernel_launch(void* const* d_in, const int* in_sizes, int n_in,
                              void* d_out, int out_size, void* d_ws, size_t ws_size,
                              hipStream_t stream)
{
    (void)in_sizes; (void)n_in; (void)out_size;
    const float* x    = (const float*)d_in[0];
    const float* w1   = (const float*)d_in[1];
    const float* b1   = (const float*)d_in[2];
    const float* w2   = (const float*)d_in[3];
    const float* b2   = (const float*)d_in[4];
    const float* wg   = (const float*)d_in[5];
    const float* bg   = (const float*)d_in[6];
    const float* wf   = (const float*)d_in[7];
    const float* bfp  = (const float*)d_in[8];
    const float* gamma= (const float*)d_in[9];
    const float* beta = (const float*)d_in[10];
    const float* wsk  = (const float*)d_in[11];
    const float* bsk  = (const float*)d_in[12];
    const float* sw1  = (const float*)d_in[13];
    const float* sb1  = (const float*)d_in[14];
    const float* sw2  = (const float*)d_in[15];
    const float* sb2  = (const float*)d_in[16];
    const float* swg  = (const float*)d_in[17];
    const float* sbg  = (const float*)d_in[18];
    const float* swf  = (const float*)d_in[19];
    const float* sbf  = (const float*)d_in[20];
    const float* sgam = (const float*)d_in[21];
    const float* sbet = (const float*)d_in[22];
    const float* ssw  = (const float*)d_in[23];
    const float* ssb  = (const float*)d_in[24];

    // ---- workspace layout, chunk size adaptive to ws_size ----
    // per-token: stacked 16384B + sh_part 4*1024B + sres_part 4*128B = 20992B
    const size_t fixedB = 12582912 + 4718592;            // wt (12 MiB) + wcat (4.5 MiB)
    int C = BT;                                          // tokens per chunk
    while (C > 512) {
        size_t need = fixedB + (size_t)C * 20992;
        if (need <= ws_size) break;
        C >>= 1;
    }
    const int nChunks = BT / C;

    char* ws = (char*)d_ws;
    _Float16* wt      = (_Float16*)ws;                                   // 3 x 2M fp16
    _Float16* wcat    = (_Float16*)(ws + 12582912);                      // 288 x 8192 fp16
    char* p = ws + fixedB;
    _Float16* stacked = (_Float16*)p;            p += (size_t)C * FH * 2;
    float* sh_part    = (float*)p;               p += (size_t)C * 256 * 4 * SPLITK;
    float* sres_part  = (float*)p;
    float* out        = (float*)d_out;

    hipLaunchKernelGGL(transpose_w_kernel, dim3(1536), dim3(256), 0, stream, w2, wg, wf, wt);
    hipLaunchKernelGGL(transpose_s_kernel, dim3(640), dim3(256), 0, stream, sw1, ssw, wcat);
    for (int c = 0; c < nChunks; ++c) {
        int tb = c * C;
        hipLaunchKernelGGL(grn_kernel, dim3((C / 64) * 32), dim3(512), 0, stream,
                           x, w1, b1, b2, bg, bfp, gamma, beta, wsk, bsk,
                           wt, wt + 2097152, wt + 2 * 2097152, stacked, tb);
        hipLaunchKernelGGL(sel_gemm_kernel, dim3((C / 64) * SPLITK), dim3(256), 0, stream,
                           stacked, wcat, sh_part, sres_part, C);
        hipLaunchKernelGGL(tail_kernel, dim3(C / 8), dim3(256), 0, stream,
                           sh_part, sres_part, stacked, sb1, ssb, sw2, sb2, swg, sbg, swf, sbf,
                           sgam, sbet, out, tb, C);
    }
}

// Round 13
// 700.090 us; speedup vs baseline: 1.1722x; 1.0236x over previous
//
#include <hip/hip_runtime.h>
#include <hip/hip_bf16.h>
#include <hip/hip_fp16.h>

#define BT 16384
#define F 32
#define H 256
#define FH 8192
#define SPLITK 4

typedef _Float16 half8 __attribute__((ext_vector_type(8)));
typedef _Float16 half4v __attribute__((ext_vector_type(4)));
typedef float float4v __attribute__((ext_vector_type(4)));

#define GLD_LDS(gsrc, ldst) \
    __builtin_amdgcn_global_load_lds( \
        (const __attribute__((address_space(1))) void*)(gsrc), \
        (__attribute__((address_space(3))) void*)(ldst), 16, 0, 0)

// Pipelined-barrier macros (T3/T4): counted vmcnt keeps the prefetch in
// flight ACROSS the barrier; sched_barrier(0) pins ordering (rule #18).
#define WAITVM2_BAR() do { \
    __builtin_amdgcn_sched_barrier(0); \
    asm volatile("s_waitcnt vmcnt(2)" ::: "memory"); \
    __builtin_amdgcn_s_barrier(); \
    __builtin_amdgcn_sched_barrier(0); } while (0)
#define WAITVM0_BAR() do { \
    __builtin_amdgcn_sched_barrier(0); \
    asm volatile("s_waitcnt vmcnt(0)" ::: "memory"); \
    __builtin_amdgcn_s_barrier(); \
    __builtin_amdgcn_sched_barrier(0); } while (0)
#define END_BAR() do { \
    __builtin_amdgcn_sched_barrier(0); \
    __builtin_amdgcn_s_barrier(); \
    __builtin_amdgcn_sched_barrier(0); } while (0)
#define LGKM_BAR() do { \
    __builtin_amdgcn_sched_barrier(0); \
    asm volatile("s_waitcnt lgkmcnt(0)" ::: "memory"); \
    __builtin_amdgcn_s_barrier(); \
    __builtin_amdgcn_sched_barrier(0); } while (0)

// ---------------------------------------------------------------------------
// Prep: transpose w2/wg/wf (F,H_contr,H_out) fp32 -> [f][n_out][h_contr] fp16
// ---------------------------------------------------------------------------
__global__ __launch_bounds__(256) void transpose_w_kernel(
    const float* __restrict__ w2, const float* __restrict__ wg,
    const float* __restrict__ wf, _Float16* __restrict__ wt)
{
    __shared__ float tile[64][65];
    int bid = blockIdx.x;
    int tens = bid >> 9, rem = bid & 511;
    int f = rem >> 4, tl = rem & 15;
    int hb = (tl >> 2) * 64, nb = (tl & 3) * 64;
    const float* src = (tens == 0 ? w2 : (tens == 1 ? wg : wf)) + f * 65536;
    _Float16* dst = wt + (size_t)tens * 2097152 + f * 65536;
    int lane = threadIdx.x & 63, w = threadIdx.x >> 6;
    for (int i = 0; i < 16; ++i) {
        int r = i * 4 + w;
        tile[r][lane] = src[(hb + r) * 256 + nb + lane];
    }
    __syncthreads();
    for (int i = 0; i < 16; ++i) {
        int c = i * 4 + w;
        dst[(nb + c) * 256 + hb + lane] = (_Float16)tile[lane][c];
    }
}

// ---------------------------------------------------------------------------
// Prep: Wcat[n][k] fp16, n<256 from sw1 (8192,256), n in [256,288) from ssw
// ---------------------------------------------------------------------------
__global__ __launch_bounds__(256) void transpose_s_kernel(
    const float* __restrict__ sw1, const float* __restrict__ ssw,
    _Float16* __restrict__ wcat)
{
    __shared__ float tile[64][65];
    int bid = blockIdx.x;
    int lane = threadIdx.x & 63, w = threadIdx.x >> 6;
    if (bid < 512) {
        int k0 = (bid >> 2) * 64, n0 = (bid & 3) * 64;
        for (int i = 0; i < 16; ++i) {
            int r = i * 4 + w;
            tile[r][lane] = sw1[(size_t)(k0 + r) * 256 + n0 + lane];
        }
        __syncthreads();
        for (int i = 0; i < 16; ++i) {
            int c = i * 4 + w;
            wcat[(size_t)(n0 + c) * FH + k0 + lane] = (_Float16)tile[lane][c];
        }
    } else {
        int k0 = (bid - 512) * 64;
        int t = threadIdx.x;
        for (int i = 0; i < 8; ++i) {
            int idx = t + i * 256;
            int r = idx >> 5, cc = idx & 31;
            tile[r][cc] = ssw[(size_t)(k0 + r) * 32 + cc];
        }
        __syncthreads();
        for (int i = 0; i < 8; ++i) {
            int idx = t + i * 256;
            int c = idx >> 6, rr = idx & 63;
            wcat[(size_t)(256 + c) * FH + k0 + rr] = (_Float16)tile[rr][c];
        }
    }
}

// ---------------------------------------------------------------------------
// Fused per-feature GRN v7: v5 (proven) + depth-3 Bs ring, ONE barrier/step.
// LDS = As 32KB + 3 x 16KB ring = 80KB -> still 2 blocks/CU (160/80), so no
// occupancy cost. Step: {vmcnt(2); s_barrier; stage(s+2)->buf[(s+2)%3];
// MFMA(s) from buf[s%3]}. Race-free: stage(s+2) is issued AFTER barrier_s;
// its target buf[(s+2)%3]=buf[(s-1)%3] was last read at step s-1, and every
// wave at barrier_s completed its step-(s-1) ds_reads (lgkm-ordered before
// its MFMAs). vmcnt invariant: at each wait the only newer vm-ops are
// stage(s+1)'s 2 instrs -> vmcnt(2) drains exactly stage(s); last step
// vmcnt(0). Barriers/block: 48 -> 26; prefetch depth ~2 steps.
// (r6's ring failure was capacity -- 8KB stride for 16KB tiles; fixed here.)
// ---------------------------------------------------------------------------
__global__ __launch_bounds__(512, 4) void grn_kernel(
    const float* __restrict__ x, const float* __restrict__ w1, const float* __restrict__ b1,
    const float* __restrict__ b2, const float* __restrict__ bg, const float* __restrict__ bfv_,
    const float* __restrict__ gamma, const float* __restrict__ beta,
    const float* __restrict__ wsk, const float* __restrict__ bsk,
    const _Float16* __restrict__ w2t, const _Float16* __restrict__ wgt,
    const _Float16* __restrict__ wft, _Float16* __restrict__ stacked, int tok_base)
{
    __shared__ __align__(16) char smem[81920];
    _Float16* As = (_Float16*)smem;                  // 64 x 256 fp16 swizzled (32KB)
    _Float16* Bs = (_Float16*)(smem + 32768);        // 3 x (256x32) fp16 ring (48KB)
    float* red = (float*)smem;                       // alias As (post-MFMA): 512 f32
    float* mv  = (float*)(smem + 2048);              // alias As: 128 f32

    // XCD-clustered decode (T1): each XCD owns features [4*xcd, 4*xcd+4)
    const int bid = blockIdx.x;
    const int xcd = bid & 7;
    const int slot = bid >> 3;
    const int f = xcd * 4 + (slot & 3);
    const int tok0 = (slot >> 2) * 64;               // chunk-local
    const int t = threadIdx.x;
    const int wv = t >> 6;
    const int ln = t & 15;
    const int q  = (t >> 4) & 3;
    const int wm = wv >> 2;                          // m-half 0/1
    const int wn = wv & 3;                           // n-quarter 0..3
    const int r0 = wm * 32 + ln;                     // A-frag row, mt=0
    const int r1 = r0 + 16;                          // A-frag row, mt=1

    const _Float16* w2f = w2t + (size_t)f * 65536;
    const _Float16* wgf = wgt + (size_t)f * 65536;
    const _Float16* wff = wft + (size_t)f * 65536;

#define GRN_STAGE(buf, Bsrc, kc) do {                                          \
        const _Float16* _bp = (Bsrc);                                          \
        _Pragma("unroll")                                                      \
        for (int _i = 0; _i < 2; ++_i) {                                       \
            int _s = t + _i * 512;                                             \
            int _row = _s >> 2;                                                \
            int _c = (_s & 3) ^ ((_row >> 1) & 3);                             \
            GLD_LDS(_bp + _row * 256 + (kc) * 32 + _c * 8,                     \
                    Bs + (buf) * 8192 + _s * 8);                               \
        } } while (0)

#define GRN_MFMA(ACC, s) do {                                                  \
        const _Float16* _B = Bs + ((s) % 3) * 8192;                            \
        const int _kc = (s) & 7;                                               \
        half8 _a0 = *(const half8*)&As[r0 * 256 + (((_kc * 4 + q) ^ (r0 & 7)) << 3)]; \
        half8 _a1 = *(const half8*)&As[r1 * 256 + (((_kc * 4 + q) ^ (r1 & 7)) << 3)]; \
        _Pragma("unroll")                                                      \
        for (int _nt = 0; _nt < 4; ++_nt) {                                    \
            int _rb = wn * 64 + _nt * 16 + ln;                                 \
            int _cp = q ^ ((_rb >> 1) & 3);                                    \
            half8 _b8 = *(const half8*)&_B[_rb * 32 + _cp * 8];                \
            ACC[0][_nt] = __builtin_amdgcn_mfma_f32_16x16x32_f16(              \
                _a0, _b8, ACC[0][_nt], 0, 0, 0);                               \
            ACC[1][_nt] = __builtin_amdgcn_mfma_f32_16x16x32_f16(              \
                _a1, _b8, ACC[1][_nt], 0, 0, 0);                               \
        } } while (0)

    // b2 preloaded (retired by compiler wait before the h2 epilogue)
    float b2v[4];
#pragma unroll
    for (int nt = 0; nt < 4; ++nt) b2v[nt] = b2[f * H + wn * 64 + nt * 16 + ln];

    GRN_STAGE(0, w2f, 0);                            // step-0 tile -> buf0

    // A = elu(x * w1 + b1) -> As (swizzled). x reads are wave-uniform s_loads.
    {
        const int colE = t & 255;
        const int rgE = __builtin_amdgcn_readfirstlane(t >> 8) * 32;
        const float w1v = w1[f * H + colE];
        const float b1v = b1[f * H + colE];
        const int chE = colE >> 3, elE = colE & 7;
#pragma unroll 8
        for (int i = 0; i < 32; ++i) {
            int row = rgE + i;
            float xv = x[(size_t)(tok_base + tok0 + row) * F + f];
            float z = fmaf(xv, w1v, b1v);
            float e = z > 0.f ? z : (__expf(z) - 1.f);
            As[row * 256 + ((chE ^ (row & 7)) << 3) + elE] = (_Float16)e;
        }
    }
    GRN_STAGE(1, w2f, 1);                            // step-1 tile -> buf1
    LGKM_BAR();                                      // As visible; stages in flight

    float4v acc1[2][4];
#pragma unroll
    for (int mt = 0; mt < 2; ++mt)
#pragma unroll
        for (int nt = 0; nt < 4; ++nt)
#pragma unroll
            for (int r = 0; r < 4; ++r) acc1[mt][nt][r] = 0.f;

    // ---- steps 0..7: h2 = A @ w2 ----
#pragma unroll
    for (int s = 0; s < 8; ++s) {
        WAITVM2_BAR();                               // buf[s%3] ready, all waves
        if (s < 6) GRN_STAGE((s + 2) % 3, w2f, s + 2);
        else       GRN_STAGE((s + 2) % 3, wgf, s - 6);   // chain into wg
        GRN_MFMA(acc1, s);
    }
    END_BAR();                                       // step-7 As-reads done

    // h2 + b2 -> As (swizzled fp16). No vm-ops (b2 preloaded): the wg
    // prefetches stay in flight; lgkm-only barrier.
    {
#pragma unroll
        for (int mt = 0; mt < 2; ++mt)
#pragma unroll
            for (int nt = 0; nt < 4; ++nt) {
                int n = wn * 64 + nt * 16 + ln;
#pragma unroll
                for (int r = 0; r < 4; ++r) {
                    int row = wm * 32 + mt * 16 + q * 4 + r;
                    As[row * 256 + (((n >> 3) ^ (row & 7)) << 3) + (n & 7)] =
                        (_Float16)(acc1[mt][nt][r] + b2v[nt]);
                }
            }
    }
    LGKM_BAR();

    float4v accG[2][4], accF[2][4];
#pragma unroll
    for (int mt = 0; mt < 2; ++mt)
#pragma unroll
        for (int nt = 0; nt < 4; ++nt)
#pragma unroll
            for (int r = 0; r < 4; ++r) { accG[mt][nt][r] = 0.f; accF[mt][nt][r] = 0.f; }

    // ---- steps 8..15: Cg = h2 @ wg ----
#pragma unroll
    for (int s8 = 0; s8 < 8; ++s8) {
        const int s = s8 + 8;
        WAITVM2_BAR();
        if (s8 < 6) GRN_STAGE((s + 2) % 3, wgf, s8 + 2);
        else        GRN_STAGE((s + 2) % 3, wff, s8 - 6); // chain into wf
        GRN_MFMA(accG, s);
    }
    // ---- steps 16..23: Cf = h2 @ wf ----
#pragma unroll
    for (int s8 = 0; s8 < 8; ++s8) {
        const int s = s8 + 16;
        if (s8 < 7) { WAITVM2_BAR(); } else { WAITVM0_BAR(); }
        if (s8 < 6) GRN_STAGE((s + 2) % 3, wff, s8 + 2);
        GRN_MFMA(accF, s);
    }
    END_BAR();                                       // step-23 As-reads done (red aliases As)
#undef GRN_STAGE
#undef GRN_MFMA

    // ---- GLU + residual, in registers (y overwrites accG) ----
    float xr[2][4];
#pragma unroll
    for (int mt = 0; mt < 2; ++mt)
#pragma unroll
        for (int r = 0; r < 4; ++r)
            xr[mt][r] = x[(size_t)(tok_base + tok0 + wm * 32 + mt * 16 + q * 4 + r) * F + f];
#pragma unroll
    for (int nt = 0; nt < 4; ++nt) {
        int nn = f * H + wn * 64 + nt * 16 + ln;
        float bgv = bg[nn], bfv = bfv_[nn], wsv = wsk[nn], bsv = bsk[nn];
#pragma unroll
        for (int mt = 0; mt < 2; ++mt)
#pragma unroll
            for (int r = 0; r < 4; ++r) {
                float cg = accG[mt][nt][r] + bgv;
                float cf = accF[mt][nt][r] + bfv;
                float sig = 1.f / (1.f + __expf(-cg));
                accG[mt][nt][r] = sig * cf + xr[mt][r] * wsv + bsv;
            }
    }

    // ---- LN sums fused from registers ----
#pragma unroll
    for (int mt = 0; mt < 2; ++mt)
#pragma unroll
        for (int r = 0; r < 4; ++r) {
            float v0 = accG[mt][0][r], v1 = accG[mt][1][r];
            float v2 = accG[mt][2][r], v3 = accG[mt][3][r];
            float s1 = (v0 + v1) + (v2 + v3);
            float s2 = (v0 * v0 + v1 * v1) + (v2 * v2 + v3 * v3);
#pragma unroll
            for (int m = 1; m <= 8; m <<= 1) {
                s1 += __shfl_xor(s1, m, 64);
                s2 += __shfl_xor(s2, m, 64);
            }
            if (ln == 0) {
                int row = wm * 32 + mt * 16 + q * 4 + r;
                red[row * 4 + wn] = s1;
                red[256 + row * 4 + wn] = s2;
            }
        }
    __syncthreads();
    if (t < 64) {
        float a = (red[t * 4] + red[t * 4 + 1]) + (red[t * 4 + 2] + red[t * 4 + 3]);
        float b = (red[256 + t * 4] + red[256 + t * 4 + 1])
                + (red[256 + t * 4 + 2] + red[256 + t * 4 + 3]);
        float mean = a * (1.f / 256.f);
        float var = b * (1.f / 256.f) - mean * mean;
        mv[t] = mean;
        mv[64 + t] = rsqrtf(var + 1e-5f);
    }
    __syncthreads();

    // ---- normalize + scale from registers, store fp16 ----
    float mr[2][4], rr[2][4];
#pragma unroll
    for (int mt = 0; mt < 2; ++mt)
#pragma unroll
        for (int r = 0; r < 4; ++r) {
            int row = wm * 32 + mt * 16 + q * 4 + r;
            mr[mt][r] = mv[row];
            rr[mt][r] = mv[64 + row];
        }
#pragma unroll
    for (int nt = 0; nt < 4; ++nt) {
        int n = wn * 64 + nt * 16 + ln;
        float gv = gamma[f * H + n], bvv = beta[f * H + n];
#pragma unroll
        for (int mt = 0; mt < 2; ++mt)
#pragma unroll
            for (int r = 0; r < 4; ++r) {
                int row = wm * 32 + mt * 16 + q * 4 + r;
                float vv = (accG[mt][nt][r] - mr[mt][r]) * rr[mt][r] * gv + bvv;
                stacked[(size_t)(tok0 + row) * FH + f * H + n] = (_Float16)vv;
            }
    }
}

// ---------------------------------------------------------------------------
// Selection GEMM v4 (unchanged): XCD-clustered decode, A double-buffered via
// global_load_lds + XOR swizzle, B straight to registers, static indexing.
// ---------------------------------------------------------------------------
__global__ __launch_bounds__(256, 3) void sel_gemm_kernel(
    const _Float16* __restrict__ stacked, const _Float16* __restrict__ wcat,
    float* __restrict__ sh_part, float* __restrict__ sres_part, int C)
{
    __shared__ __align__(16) _Float16 As2[2][64 * 64];   // 2 x 8 KB
    const int t = threadIdx.x;
    const int wv = t >> 6;
    const int ln = t & 15, q = (t & 63) >> 4;
    const int bid = blockIdx.x;
    const int xcd = bid & 7;
    const int slot = bid >> 3;
    const int kb = xcd >> 1;                             // k-slice 0..3
    const int tok0 = (slot * 2 + (xcd & 1)) * 64;        // chunk-local

    const int s1 = t + 256;
    const int row0 = t >> 3,  c0 = ((t & 7) ^ (row0 & 7)) * 8;
    const int row1 = s1 >> 3, c1 = ((s1 & 7) ^ (row1 & 7)) * 8;
    const _Float16* a0src = stacked + (size_t)(tok0 + row0) * FH + kb * 2048 + c0;
    const _Float16* a1src = stacked + (size_t)(tok0 + row1) * FH + kb * 2048 + c1;

    float4v acc[4][5];
#pragma unroll
    for (int mt = 0; mt < 4; ++mt)
#pragma unroll
        for (int i = 0; i < 5; ++i)
#pragma unroll
            for (int r = 0; r < 4; ++r) acc[mt][i][r] = 0.f;

    GLD_LDS(a0src, &As2[0][t * 8]);
    GLD_LDS(a1src, &As2[0][s1 * 8]);
    __syncthreads();

    for (int kc = 0; kc < 32; ++kc) {
        const int cur = kc & 1;
        // ---- B fragments for this K-step: global->reg, issued FIRST ----
        half8 bb0[5], bb1[5];
#define SEL_LOAD(i)                                                            \
        {                                                                      \
            const _Float16* bp = wcat                                          \
                + (size_t)((wv + 4 * (i)) * 16 + ln) * FH                      \
                + kb * 2048 + kc * 64 + q * 8;                                 \
            bb0[i] = *(const half8*)bp;                                        \
            bb1[i] = *(const half8*)(bp + 32);                                 \
        }
        SEL_LOAD(0) SEL_LOAD(1) SEL_LOAD(2) SEL_LOAD(3)
        if (wv < 2) SEL_LOAD(4)
#undef SEL_LOAD
        // ---- prefetch next A tile into the other buffer ----
        if (kc < 31) {
            GLD_LDS(a0src + (kc + 1) * 64, &As2[cur ^ 1][t * 8]);
            GLD_LDS(a1src + (kc + 1) * 64, &As2[cur ^ 1][s1 * 8]);
        }
        // ---- A fragments from LDS (swizzled, conflict-free) ----
        const _Float16* As = As2[cur];
        half8 af0[4], af1[4];
#pragma unroll
        for (int mt = 0; mt < 4; ++mt) {
            int row = mt * 16 + ln;
            af0[mt] = *(const half8*)&As[row * 64 + ((q ^ (row & 7)) * 8)];
            af1[mt] = *(const half8*)&As[row * 64 + (((4 + q) ^ (row & 7)) * 8)];
        }
        // ---- MFMA, fully static indexing ----
#define SEL_FMA(i)                                                            \
        {                                                                      \
            _Pragma("unroll")                                                  \
            for (int mt = 0; mt < 4; ++mt)                                     \
                acc[mt][i] = __builtin_amdgcn_mfma_f32_16x16x32_f16(           \
                    af0[mt], bb0[i], acc[mt][i], 0, 0, 0);                     \
            _Pragma("unroll")                                                  \
            for (int mt = 0; mt < 4; ++mt)                                     \
                acc[mt][i] = __builtin_amdgcn_mfma_f32_16x16x32_f16(           \
                    af1[mt], bb1[i], acc[mt][i], 0, 0, 0);                     \
        }
        SEL_FMA(0) SEL_FMA(1) SEL_FMA(2) SEL_FMA(3)
        if (wv < 2) SEL_FMA(4)
#undef SEL_FMA
        __syncthreads();   // drains prefetch; all waves done reading buf[cur]
    }

    // ---- epilogue: plain stores, static branches ----
    float* shp = sh_part + (size_t)kb * ((size_t)C * 256);
    float* srp = sres_part + (size_t)kb * ((size_t)C * 32);
#pragma unroll
    for (int i = 0; i < 4; ++i) {
        int n = (wv + 4 * i) * 16 + ln;                  // always < 256
#pragma unroll
        for (int mt = 0; mt < 4; ++mt)
#pragma unroll
            for (int r = 0; r < 4; ++r) {
                int m = tok0 + mt * 16 + q * 4 + r;
                shp[(size_t)m * 256 + n] = acc[mt][i][r];
            }
    }
    if (wv < 2) {                                        // tile 4 = sres cols
        int n = wv * 16 + ln;                            // 0..31
#pragma unroll
        for (int mt = 0; mt < 4; ++mt)
#pragma unroll
            for (int r = 0; r < 4; ++r) {
                int m = tok0 + mt * 16 + q * 4 + r;
                srp[(size_t)m * 32 + n] = acc[mt][4][r];
            }
    }
}

// ---------------------------------------------------------------------------
// Fused selection tail v2 (unchanged -- measured good): vectorized split-K
// reduce (float4) + vectorized weighted sum (half4/float4).
// ---------------------------------------------------------------------------
__global__ __launch_bounds__(256) void tail_kernel(
    const float* __restrict__ sh_part, const float* __restrict__ sres_part,
    const _Float16* __restrict__ stacked,
    const float* __restrict__ sb1, const float* __restrict__ ssb,
    const float* __restrict__ sw2, const float* __restrict__ sb2,
    const float* __restrict__ swg, const float* __restrict__ sbg,
    const float* __restrict__ swf, const float* __restrict__ sbf,
    const float* __restrict__ sgam, const float* __restrict__ sbet,
    float* __restrict__ out, int tok_base, int C)
{
    __shared__ float sw2s[256 * 32];                    // 32 KB
    __shared__ float swgs[1024], swfs[1024];            // 8 KB
    __shared__ float shv[8][260];                       // 8 tokens x 256 (16B-aligned rows)
    __shared__ float wls[8][33];
    const int t = threadIdx.x;
    const size_t shS = (size_t)C * 256;
    const size_t srS = (size_t)C * 32;
    for (int i = 0; i < 32; ++i) sw2s[t + i * 256] = sw2[t + i * 256];
    for (int i = 0; i < 4; ++i) {
        swgs[t + i * 256] = swg[t + i * 256];
        swfs[t + i * 256] = swf[t + i * 256];
    }
    // reduce split-K partials + bias, elu (float4-vectorized; same add order)
#pragma unroll
    for (int i = 0; i < 2; ++i) {
        int slot = t + i * 256;                         // 0..511
        int gg = slot >> 6;                             // token 0..7
        int c4 = (slot & 63) * 4;                       // col 0..252
        size_t o = (size_t)(blockIdx.x * 8 + gg) * 256 + c4;
        float4v z = *(const float4v*)&sb1[c4];
        z += *(const float4v*)&sh_part[o];
        z += *(const float4v*)&sh_part[shS + o];
        z += *(const float4v*)&sh_part[2 * shS + o];
        z += *(const float4v*)&sh_part[3 * shS + o];
        float4v e;
#pragma unroll
        for (int j = 0; j < 4; ++j)
            e[j] = z[j] > 0.f ? z[j] : (__expf(z[j]) - 1.f);
        *(float4v*)&shv[gg][c4] = e;
    }
    __syncthreads();
    const int g = t >> 5;                               // token group 0..7
    const int j = t & 31;                               // feature index
    const int token = blockIdx.x * 8 + g;               // chunk-local
    // fc2: 256 -> 32
    float p = sb2[j];
    for (int k = 0; k < 256; ++k) p += shv[g][k] * sw2s[k * 32 + j];
    // GLU via width-32 shuffles
    float gacc = sbg[j], uacc = sbf[j];
#pragma unroll 8
    for (int i = 0; i < 32; ++i) {
        float tv = __shfl(p, i, 32);
        gacc += tv * swgs[i * 32 + j];
        uacc += tv * swfs[i * 32 + j];
    }
    float sig = 1.f / (1.f + __expf(-gacc));
    size_t o2 = (size_t)token * 32 + j;
    float sresv = ssb[j] + sres_part[o2] + sres_part[srS + o2]
                + sres_part[2 * srS + o2] + sres_part[3 * srS + o2];
    float sv = sresv + sig * uacc;
    // LayerNorm over 32 lanes
    float s1 = sv, s2 = sv * sv;
    for (int off = 16; off; off >>= 1) {
        s1 += __shfl_xor(s1, off, 32);
        s2 += __shfl_xor(s2, off, 32);
    }
    float mean = s1 * (1.f / 32.f);
    float var = s2 * (1.f / 32.f) - mean * mean;
    float v = (sv - mean) * rsqrtf(var + 1e-5f) * sgam[j] + sbet[j];
    // softmax over 32 lanes
    float mx = v;
    for (int off = 16; off; off >>= 1) mx = fmaxf(mx, __shfl_xor(mx, off, 32));
    float e = __expf(v - mx);
    float ssum = e;
    for (int off = 16; off; off >>= 1) ssum += __shfl_xor(ssum, off, 32);
    wls[g][j] = e / ssum;
    __syncthreads();
    // weighted sum: thread -> 4 consecutive cols of 2 tokens (vectorized)
    {
        const int tg = t >> 6;                          // 0..3
        const int c4 = (t & 63) * 4;                    // col 0..252
#pragma unroll
        for (int tt = 0; tt < 2; ++tt) {
            int tk = tg * 2 + tt;
            const _Float16* sp = stacked + (size_t)(blockIdx.x * 8 + tk) * FH;
            float a0 = 0.f, a1 = 0.f, a2 = 0.f, a3 = 0.f;
#pragma unroll
            for (int f = 0; f < 32; ++f) {
                half4v vv = *(const half4v*)&sp[f * 256 + c4];
                float w = wls[tk][f];
                a0 += (float)vv[0] * w;
                a1 += (float)vv[1] * w;
                a2 += (float)vv[2] * w;
                a3 += (float)vv[3] * w;
            }
            float4v ov; ov[0] = a0; ov[1] = a1; ov[2] = a2; ov[3] = a3;
            *(float4v*)&out[(size_t)(tok_base + blockIdx.x * 8 + tk) * 256 + c4] = ov;
        }
    }
}

// ---------------------------------------------------------------------------
extern "C" void kernel_launch(void* const* d_in, const int* in_sizes, int n_in,
                              void* d_out, int out_size, void* d_ws, size_t ws_size,
                              hipStream_t stream)
{
    (void)in_sizes; (void)n_in; (void)out_size;
    const float* x    = (const float*)d_in[0];
    const float* w1   = (const float*)d_in[1];
    const float* b1   = (const float*)d_in[2];
    const float* w2   = (const float*)d_in[3];
    const float* b2   = (const float*)d_in[4];
    const float* wg   = (const float*)d_in[5];
    const float* bg   = (const float*)d_in[6];
    const float* wf   = (const float*)d_in[7];
    const float* bfp  = (const float*)d_in[8];
    const float* gamma= (const float*)d_in[9];
    const float* beta = (const float*)d_in[10];
    const float* wsk  = (const float*)d_in[11];
    const float* bsk  = (const float*)d_in[12];
    const float* sw1  = (const float*)d_in[13];
    const float* sb1  = (const float*)d_in[14];
    const float* sw2  = (const float*)d_in[15];
    const float* sb2  = (const float*)d_in[16];
    const float* swg  = (const float*)d_in[17];
    const float* sbg  = (const float*)d_in[18];
    const float* swf  = (const float*)d_in[19];
    const float* sbf  = (const float*)d_in[20];
    const float* sgam = (const float*)d_in[21];
    const float* sbet = (const float*)d_in[22];
    const float* ssw  = (const float*)d_in[23];
    const float* ssb  = (const float*)d_in[24];

    // ---- workspace layout, chunk size adaptive to ws_size ----
    // per-token: stacked 16384B + sh_part 4*1024B + sres_part 4*128B = 20992B
    const size_t fixedB = 12582912 + 4718592;            // wt (12 MiB) + wcat (4.5 MiB)
    int C = BT;                                          // tokens per chunk
    while (C > 512) {
        size_t need = fixedB + (size_t)C * 20992;
        if (need <= ws_size) break;
        C >>= 1;
    }
    const int nChunks = BT / C;

    char* ws = (char*)d_ws;
    _Float16* wt      = (_Float16*)ws;                                   // 3 x 2M fp16
    _Float16* wcat    = (_Float16*)(ws + 12582912);                      // 288 x 8192 fp16
    char* p = ws + fixedB;
    _Float16* stacked = (_Float16*)p;            p += (size_t)C * FH * 2;
    float* sh_part    = (float*)p;               p += (size_t)C * 256 * 4 * SPLITK;
    float* sres_part  = (float*)p;
    float* out        = (float*)d_out;

    hipLaunchKernelGGL(transpose_w_kernel, dim3(1536), dim3(256), 0, stream, w2, wg, wf, wt);
    hipLaunchKernelGGL(transpose_s_kernel, dim3(640), dim3(256), 0, stream, sw1, ssw, wcat);
    for (int c = 0; c < nChunks; ++c) {
        int tb = c * C;
        hipLaunchKernelGGL(grn_kernel, dim3((C / 64) * 32), dim3(512), 0, stream,
                           x, w1, b1, b2, bg, bfp, gamma, beta, wsk, bsk,
                           wt, wt + 2097152, wt + 2 * 2097152, stacked, tb);
        hipLaunchKernelGGL(sel_gemm_kernel, dim3((C / 64) * SPLITK), dim3(256), 0, stream,
                           stacked, wcat, sh_part, sres_part, C);
        hipLaunchKernelGGL(tail_kernel, dim3(C / 8), dim3(256), 0, stream,
                           sh_part, sres_part, stacked, sb1, ssb, sw2, sb2, swg, sbg, swf, sbf,
                           sgam, sbet, out, tb, C);
    }
}

// Round 14
// 694.097 us; speedup vs baseline: 1.1823x; 1.0086x over previous
//
#include <hip/hip_runtime.h>
#include <hip/hip_bf16.h>
#include <hip/hip_fp16.h>

#define BT 16384
#define F 32
#define H 256
#define FH 8192
#define SPLITK 4

typedef _Float16 half8 __attribute__((ext_vector_type(8)));
typedef _Float16 half4v __attribute__((ext_vector_type(4)));
typedef float float4v __attribute__((ext_vector_type(4)));

#define GLD_LDS(gsrc, ldst) \
    __builtin_amdgcn_global_load_lds( \
        (const __attribute__((address_space(1))) void*)(gsrc), \
        (__attribute__((address_space(3))) void*)(ldst), 16, 0, 0)

// Pipelined-barrier macros (T3/T4): counted vmcnt keeps the prefetch in
// flight ACROSS the barrier; sched_barrier(0) pins ordering (rule #18).
#define WAITVM2_BAR() do { \
    __builtin_amdgcn_sched_barrier(0); \
    asm volatile("s_waitcnt vmcnt(2)" ::: "memory"); \
    __builtin_amdgcn_s_barrier(); \
    __builtin_amdgcn_sched_barrier(0); } while (0)
#define WAITVM0_BAR() do { \
    __builtin_amdgcn_sched_barrier(0); \
    asm volatile("s_waitcnt vmcnt(0)" ::: "memory"); \
    __builtin_amdgcn_s_barrier(); \
    __builtin_amdgcn_sched_barrier(0); } while (0)
#define END_BAR() do { \
    __builtin_amdgcn_sched_barrier(0); \
    __builtin_amdgcn_s_barrier(); \
    __builtin_amdgcn_sched_barrier(0); } while (0)
#define LGKM_BAR() do { \
    __builtin_amdgcn_sched_barrier(0); \
    asm volatile("s_waitcnt lgkmcnt(0)" ::: "memory"); \
    __builtin_amdgcn_s_barrier(); \
    __builtin_amdgcn_sched_barrier(0); } while (0)

// ---------------------------------------------------------------------------
// Prep: transpose w2/wg/wf (F,H_contr,H_out) fp32 -> [f][n_out][h_contr] fp16
// ---------------------------------------------------------------------------
__global__ __launch_bounds__(256) void transpose_w_kernel(
    const float* __restrict__ w2, const float* __restrict__ wg,
    const float* __restrict__ wf, _Float16* __restrict__ wt)
{
    __shared__ float tile[64][65];
    int bid = blockIdx.x;
    int tens = bid >> 9, rem = bid & 511;
    int f = rem >> 4, tl = rem & 15;
    int hb = (tl >> 2) * 64, nb = (tl & 3) * 64;
    const float* src = (tens == 0 ? w2 : (tens == 1 ? wg : wf)) + f * 65536;
    _Float16* dst = wt + (size_t)tens * 2097152 + f * 65536;
    int lane = threadIdx.x & 63, w = threadIdx.x >> 6;
    for (int i = 0; i < 16; ++i) {
        int r = i * 4 + w;
        tile[r][lane] = src[(hb + r) * 256 + nb + lane];
    }
    __syncthreads();
    for (int i = 0; i < 16; ++i) {
        int c = i * 4 + w;
        dst[(nb + c) * 256 + hb + lane] = (_Float16)tile[lane][c];
    }
}

// ---------------------------------------------------------------------------
// Prep: Wcat[n][k] fp16, n<256 from sw1 (8192,256), n in [256,288) from ssw
// ---------------------------------------------------------------------------
__global__ __launch_bounds__(256) void transpose_s_kernel(
    const float* __restrict__ sw1, const float* __restrict__ ssw,
    _Float16* __restrict__ wcat)
{
    __shared__ float tile[64][65];
    int bid = blockIdx.x;
    int lane = threadIdx.x & 63, w = threadIdx.x >> 6;
    if (bid < 512) {
        int k0 = (bid >> 2) * 64, n0 = (bid & 3) * 64;
        for (int i = 0; i < 16; ++i) {
            int r = i * 4 + w;
            tile[r][lane] = sw1[(size_t)(k0 + r) * 256 + n0 + lane];
        }
        __syncthreads();
        for (int i = 0; i < 16; ++i) {
            int c = i * 4 + w;
            wcat[(size_t)(n0 + c) * FH + k0 + lane] = (_Float16)tile[lane][c];
        }
    } else {
        int k0 = (bid - 512) * 64;
        int t = threadIdx.x;
        for (int i = 0; i < 8; ++i) {
            int idx = t + i * 256;
            int r = idx >> 5, cc = idx & 31;
            tile[r][cc] = ssw[(size_t)(k0 + r) * 32 + cc];
        }
        __syncthreads();
        for (int i = 0; i < 8; ++i) {
            int idx = t + i * 256;
            int c = idx >> 6, rr = idx & 63;
            wcat[(size_t)(256 + c) * FH + k0 + rr] = (_Float16)tile[rr][c];
        }
    }
}

// ---------------------------------------------------------------------------
// Fused per-feature GRN v7 (unchanged from r13 -- measured 201 us):
// XCD-clustered decode, depth-3 Bs ring, ONE barrier/step, counted vmcnt(2).
// ---------------------------------------------------------------------------
__global__ __launch_bounds__(512, 4) void grn_kernel(
    const float* __restrict__ x, const float* __restrict__ w1, const float* __restrict__ b1,
    const float* __restrict__ b2, const float* __restrict__ bg, const float* __restrict__ bfv_,
    const float* __restrict__ gamma, const float* __restrict__ beta,
    const float* __restrict__ wsk, const float* __restrict__ bsk,
    const _Float16* __restrict__ w2t, const _Float16* __restrict__ wgt,
    const _Float16* __restrict__ wft, _Float16* __restrict__ stacked, int tok_base)
{
    __shared__ __align__(16) char smem[81920];
    _Float16* As = (_Float16*)smem;                  // 64 x 256 fp16 swizzled (32KB)
    _Float16* Bs = (_Float16*)(smem + 32768);        // 3 x (256x32) fp16 ring (48KB)
    float* red = (float*)smem;                       // alias As (post-MFMA): 512 f32
    float* mv  = (float*)(smem + 2048);              // alias As: 128 f32

    // XCD-clustered decode (T1): each XCD owns features [4*xcd, 4*xcd+4)
    const int bid = blockIdx.x;
    const int xcd = bid & 7;
    const int slot = bid >> 3;
    const int f = xcd * 4 + (slot & 3);
    const int tok0 = (slot >> 2) * 64;               // chunk-local
    const int t = threadIdx.x;
    const int wv = t >> 6;
    const int ln = t & 15;
    const int q  = (t >> 4) & 3;
    const int wm = wv >> 2;                          // m-half 0/1
    const int wn = wv & 3;                           // n-quarter 0..3
    const int r0 = wm * 32 + ln;                     // A-frag row, mt=0
    const int r1 = r0 + 16;                          // A-frag row, mt=1

    const _Float16* w2f = w2t + (size_t)f * 65536;
    const _Float16* wgf = wgt + (size_t)f * 65536;
    const _Float16* wff = wft + (size_t)f * 65536;

#define GRN_STAGE(buf, Bsrc, kc) do {                                          \
        const _Float16* _bp = (Bsrc);                                          \
        _Pragma("unroll")                                                      \
        for (int _i = 0; _i < 2; ++_i) {                                       \
            int _s = t + _i * 512;                                             \
            int _row = _s >> 2;                                                \
            int _c = (_s & 3) ^ ((_row >> 1) & 3);                             \
            GLD_LDS(_bp + _row * 256 + (kc) * 32 + _c * 8,                     \
                    Bs + (buf) * 8192 + _s * 8);                               \
        } } while (0)

#define GRN_MFMA(ACC, s) do {                                                  \
        const _Float16* _B = Bs + ((s) % 3) * 8192;                            \
        const int _kc = (s) & 7;                                               \
        half8 _a0 = *(const half8*)&As[r0 * 256 + (((_kc * 4 + q) ^ (r0 & 7)) << 3)]; \
        half8 _a1 = *(const half8*)&As[r1 * 256 + (((_kc * 4 + q) ^ (r1 & 7)) << 3)]; \
        _Pragma("unroll")                                                      \
        for (int _nt = 0; _nt < 4; ++_nt) {                                    \
            int _rb = wn * 64 + _nt * 16 + ln;                                 \
            int _cp = q ^ ((_rb >> 1) & 3);                                    \
            half8 _b8 = *(const half8*)&_B[_rb * 32 + _cp * 8];                \
            ACC[0][_nt] = __builtin_amdgcn_mfma_f32_16x16x32_f16(              \
                _a0, _b8, ACC[0][_nt], 0, 0, 0);                               \
            ACC[1][_nt] = __builtin_amdgcn_mfma_f32_16x16x32_f16(              \
                _a1, _b8, ACC[1][_nt], 0, 0, 0);                               \
        } } while (0)

    // b2 preloaded (retired by compiler wait before the h2 epilogue)
    float b2v[4];
#pragma unroll
    for (int nt = 0; nt < 4; ++nt) b2v[nt] = b2[f * H + wn * 64 + nt * 16 + ln];

    GRN_STAGE(0, w2f, 0);                            // step-0 tile -> buf0

    // A = elu(x * w1 + b1) -> As (swizzled). x reads are wave-uniform s_loads.
    {
        const int colE = t & 255;
        const int rgE = __builtin_amdgcn_readfirstlane(t >> 8) * 32;
        const float w1v = w1[f * H + colE];
        const float b1v = b1[f * H + colE];
        const int chE = colE >> 3, elE = colE & 7;
#pragma unroll 8
        for (int i = 0; i < 32; ++i) {
            int row = rgE + i;
            float xv = x[(size_t)(tok_base + tok0 + row) * F + f];
            float z = fmaf(xv, w1v, b1v);
            float e = z > 0.f ? z : (__expf(z) - 1.f);
            As[row * 256 + ((chE ^ (row & 7)) << 3) + elE] = (_Float16)e;
        }
    }
    GRN_STAGE(1, w2f, 1);                            // step-1 tile -> buf1
    LGKM_BAR();                                      // As visible; stages in flight

    float4v acc1[2][4];
#pragma unroll
    for (int mt = 0; mt < 2; ++mt)
#pragma unroll
        for (int nt = 0; nt < 4; ++nt)
#pragma unroll
            for (int r = 0; r < 4; ++r) acc1[mt][nt][r] = 0.f;

    // ---- steps 0..7: h2 = A @ w2 ----
#pragma unroll
    for (int s = 0; s < 8; ++s) {
        WAITVM2_BAR();                               // buf[s%3] ready, all waves
        if (s < 6) GRN_STAGE((s + 2) % 3, w2f, s + 2);
        else       GRN_STAGE((s + 2) % 3, wgf, s - 6);   // chain into wg
        GRN_MFMA(acc1, s);
    }
    END_BAR();                                       // step-7 As-reads done

    // h2 + b2 -> As (swizzled fp16). No vm-ops (b2 preloaded): the wg
    // prefetches stay in flight; lgkm-only barrier.
    {
#pragma unroll
        for (int mt = 0; mt < 2; ++mt)
#pragma unroll
            for (int nt = 0; nt < 4; ++nt) {
                int n = wn * 64 + nt * 16 + ln;
#pragma unroll
                for (int r = 0; r < 4; ++r) {
                    int row = wm * 32 + mt * 16 + q * 4 + r;
                    As[row * 256 + (((n >> 3) ^ (row & 7)) << 3) + (n & 7)] =
                        (_Float16)(acc1[mt][nt][r] + b2v[nt]);
                }
            }
    }
    LGKM_BAR();

    float4v accG[2][4], accF[2][4];
#pragma unroll
    for (int mt = 0; mt < 2; ++mt)
#pragma unroll
        for (int nt = 0; nt < 4; ++nt)
#pragma unroll
            for (int r = 0; r < 4; ++r) { accG[mt][nt][r] = 0.f; accF[mt][nt][r] = 0.f; }

    // ---- steps 8..15: Cg = h2 @ wg ----
#pragma unroll
    for (int s8 = 0; s8 < 8; ++s8) {
        const int s = s8 + 8;
        WAITVM2_BAR();
        if (s8 < 6) GRN_STAGE((s + 2) % 3, wgf, s8 + 2);
        else        GRN_STAGE((s + 2) % 3, wff, s8 - 6); // chain into wf
        GRN_MFMA(accG, s);
    }
    // ---- steps 16..23: Cf = h2 @ wf ----
#pragma unroll
    for (int s8 = 0; s8 < 8; ++s8) {
        const int s = s8 + 16;
        if (s8 < 7) { WAITVM2_BAR(); } else { WAITVM0_BAR(); }
        if (s8 < 6) GRN_STAGE((s + 2) % 3, wff, s8 + 2);
        GRN_MFMA(accF, s);
    }
    END_BAR();                                       // step-23 As-reads done (red aliases As)
#undef GRN_STAGE
#undef GRN_MFMA

    // ---- GLU + residual, in registers (y overwrites accG) ----
    float xr[2][4];
#pragma unroll
    for (int mt = 0; mt < 2; ++mt)
#pragma unroll
        for (int r = 0; r < 4; ++r)
            xr[mt][r] = x[(size_t)(tok_base + tok0 + wm * 32 + mt * 16 + q * 4 + r) * F + f];
#pragma unroll
    for (int nt = 0; nt < 4; ++nt) {
        int nn = f * H + wn * 64 + nt * 16 + ln;
        float bgv = bg[nn], bfv = bfv_[nn], wsv = wsk[nn], bsv = bsk[nn];
#pragma unroll
        for (int mt = 0; mt < 2; ++mt)
#pragma unroll
            for (int r = 0; r < 4; ++r) {
                float cg = accG[mt][nt][r] + bgv;
                float cf = accF[mt][nt][r] + bfv;
                float sig = 1.f / (1.f + __expf(-cg));
                accG[mt][nt][r] = sig * cf + xr[mt][r] * wsv + bsv;
            }
    }

    // ---- LN sums fused from registers ----
#pragma unroll
    for (int mt = 0; mt < 2; ++mt)
#pragma unroll
        for (int r = 0; r < 4; ++r) {
            float v0 = accG[mt][0][r], v1 = accG[mt][1][r];
            float v2 = accG[mt][2][r], v3 = accG[mt][3][r];
            float s1 = (v0 + v1) + (v2 + v3);
            float s2 = (v0 * v0 + v1 * v1) + (v2 * v2 + v3 * v3);
#pragma unroll
            for (int m = 1; m <= 8; m <<= 1) {
                s1 += __shfl_xor(s1, m, 64);
                s2 += __shfl_xor(s2, m, 64);
            }
            if (ln == 0) {
                int row = wm * 32 + mt * 16 + q * 4 + r;
                red[row * 4 + wn] = s1;
                red[256 + row * 4 + wn] = s2;
            }
        }
    __syncthreads();
    if (t < 64) {
        float a = (red[t * 4] + red[t * 4 + 1]) + (red[t * 4 + 2] + red[t * 4 + 3]);
        float b = (red[256 + t * 4] + red[256 + t * 4 + 1])
                + (red[256 + t * 4 + 2] + red[256 + t * 4 + 3]);
        float mean = a * (1.f / 256.f);
        float var = b * (1.f / 256.f) - mean * mean;
        mv[t] = mean;
        mv[64 + t] = rsqrtf(var + 1e-5f);
    }
    __syncthreads();

    // ---- normalize + scale from registers, store fp16 ----
    float mr[2][4], rr[2][4];
#pragma unroll
    for (int mt = 0; mt < 2; ++mt)
#pragma unroll
        for (int r = 0; r < 4; ++r) {
            int row = wm * 32 + mt * 16 + q * 4 + r;
            mr[mt][r] = mv[row];
            rr[mt][r] = mv[64 + row];
        }
#pragma unroll
    for (int nt = 0; nt < 4; ++nt) {
        int n = wn * 64 + nt * 16 + ln;
        float gv = gamma[f * H + n], bvv = beta[f * H + n];
#pragma unroll
        for (int mt = 0; mt < 2; ++mt)
#pragma unroll
            for (int r = 0; r < 4; ++r) {
                int row = wm * 32 + mt * 16 + q * 4 + r;
                float vv = (accG[mt][nt][r] - mr[mt][r]) * rr[mt][r] * gv + bvv;
                stacked[(size_t)(tok0 + row) * FH + f * H + n] = (_Float16)vv;
            }
    }
}

// ---------------------------------------------------------------------------
// Selection GEMM v5: the grn-proven counted-vmcnt schedule ported here.
// Depth-3 As ring (3 x 8KB), ONE raw barrier + vmcnt(2) per K-step -- the old
// __syncthreads drained the HBM A-prefetch (stacked is 128MB/chunk, beyond
// L2 -> ~600-900 cyc) every step. Per-iter order: WAITVM2_BAR (each wave
// retires ITS stage(kc) before the barrier -> cross-wave LDS visibility);
// B-reg loads (issued BEFORE the new stage so the compiler's B-wait is
// vmcnt(2), keeping stage(kc+2) in flight); stage(kc+2); MFMA.
// vmcnt audit: at iter head outstanding = {stage(kc), stage(kc+1)} = 4 ops
// (B(kc-1) was retired by the pre-MFMA wait last iter) -> vmcnt(2) retires
// exactly stage(kc). Last two iters: no stage issued; counts still safe
// (vmcnt(2) degenerates to no-op once <=2 outstanding).
// ---------------------------------------------------------------------------
__global__ __launch_bounds__(256, 3) void sel_gemm_kernel(
    const _Float16* __restrict__ stacked, const _Float16* __restrict__ wcat,
    float* __restrict__ sh_part, float* __restrict__ sres_part, int C)
{
    __shared__ __align__(16) _Float16 As3[3][64 * 64];   // 3 x 8 KB ring
    const int t = threadIdx.x;
    const int wv = t >> 6;
    const int ln = t & 15, q = (t & 63) >> 4;
    const int bid = blockIdx.x;
    const int xcd = bid & 7;
    const int slot = bid >> 3;
    const int kb = xcd >> 1;                             // k-slice 0..3
    const int tok0 = (slot * 2 + (xcd & 1)) * 64;        // chunk-local

    const int s1 = t + 256;
    const int row0 = t >> 3,  c0 = ((t & 7) ^ (row0 & 7)) * 8;
    const int row1 = s1 >> 3, c1 = ((s1 & 7) ^ (row1 & 7)) * 8;
    const _Float16* a0src = stacked + (size_t)(tok0 + row0) * FH + kb * 2048 + c0;
    const _Float16* a1src = stacked + (size_t)(tok0 + row1) * FH + kb * 2048 + c1;

    float4v acc[4][5];
#pragma unroll
    for (int mt = 0; mt < 4; ++mt)
#pragma unroll
        for (int i = 0; i < 5; ++i)
#pragma unroll
            for (int r = 0; r < 4; ++r) acc[mt][i][r] = 0.f;

#define SEL_STAGE(buf, kcc) do {                                               \
        GLD_LDS(a0src + (kcc) * 64, &As3[buf][t * 8]);                         \
        GLD_LDS(a1src + (kcc) * 64, &As3[buf][s1 * 8]); } while (0)

    SEL_STAGE(0, 0);
    SEL_STAGE(1, 1);

    int cR = 0;                                          // read slot = kc % 3
    for (int kc = 0; kc < 32; ++kc) {
        WAITVM2_BAR();        // stage(kc) visible to ALL waves; stage(kc+1) in flight
        // ---- B fragments: global->reg, BEFORE the new stage ----
        half8 bb0[5], bb1[5];
#define SEL_LOAD(i)                                                            \
        {                                                                      \
            const _Float16* bp = wcat                                          \
                + (size_t)((wv + 4 * (i)) * 16 + ln) * FH                      \
                + kb * 2048 + kc * 64 + q * 8;                                 \
            bb0[i] = *(const half8*)bp;                                        \
            bb1[i] = *(const half8*)(bp + 32);                                 \
        }
        SEL_LOAD(0) SEL_LOAD(1) SEL_LOAD(2) SEL_LOAD(3)
        if (wv < 2) SEL_LOAD(4)
#undef SEL_LOAD
        // ---- stage kc+2 into ring slot (kc+2)%3 (read last at kc-1) ----
        if (kc < 30) {
            int cS = cR + 2; if (cS >= 3) cS -= 3;
            SEL_STAGE(cS, kc + 2);
        }
        // ---- A fragments from ring[kc%3] (swizzled, conflict-free) ----
        const _Float16* As = As3[cR];
        half8 af0[4], af1[4];
#pragma unroll
        for (int mt = 0; mt < 4; ++mt) {
            int row = mt * 16 + ln;
            af0[mt] = *(const half8*)&As[row * 64 + ((q ^ (row & 7)) * 8)];
            af1[mt] = *(const half8*)&As[row * 64 + (((4 + q) ^ (row & 7)) * 8)];
        }
        // ---- MFMA, fully static indexing ----
#define SEL_FMA(i)                                                            \
        {                                                                      \
            _Pragma("unroll")                                                  \
            for (int mt = 0; mt < 4; ++mt)                                     \
                acc[mt][i] = __builtin_amdgcn_mfma_f32_16x16x32_f16(           \
                    af0[mt], bb0[i], acc[mt][i], 0, 0, 0);                     \
            _Pragma("unroll")                                                  \
            for (int mt = 0; mt < 4; ++mt)                                     \
                acc[mt][i] = __builtin_amdgcn_mfma_f32_16x16x32_f16(           \
                    af1[mt], bb1[i], acc[mt][i], 0, 0, 0);                     \
        }
        SEL_FMA(0) SEL_FMA(1) SEL_FMA(2) SEL_FMA(3)
        if (wv < 2) SEL_FMA(4)
#undef SEL_FMA
        cR = cR + 1; if (cR == 3) cR = 0;
    }
#undef SEL_STAGE

    // ---- epilogue: plain stores, static branches ----
    float* shp = sh_part + (size_t)kb * ((size_t)C * 256);
    float* srp = sres_part + (size_t)kb * ((size_t)C * 32);
#pragma unroll
    for (int i = 0; i < 4; ++i) {
        int n = (wv + 4 * i) * 16 + ln;                  // always < 256
#pragma unroll
        for (int mt = 0; mt < 4; ++mt)
#pragma unroll
            for (int r = 0; r < 4; ++r) {
                int m = tok0 + mt * 16 + q * 4 + r;
                shp[(size_t)m * 256 + n] = acc[mt][i][r];
            }
    }
    if (wv < 2) {                                        // tile 4 = sres cols
        int n = wv * 16 + ln;                            // 0..31
#pragma unroll
        for (int mt = 0; mt < 4; ++mt)
#pragma unroll
            for (int r = 0; r < 4; ++r) {
                int m = tok0 + mt * 16 + q * 4 + r;
                srp[(size_t)m * 32 + n] = acc[mt][4][r];
            }
    }
}

// ---------------------------------------------------------------------------
// Fused selection tail v2 (unchanged -- measured good): vectorized split-K
// reduce (float4) + vectorized weighted sum (half4/float4).
// ---------------------------------------------------------------------------
__global__ __launch_bounds__(256) void tail_kernel(
    const float* __restrict__ sh_part, const float* __restrict__ sres_part,
    const _Float16* __restrict__ stacked,
    const float* __restrict__ sb1, const float* __restrict__ ssb,
    const float* __restrict__ sw2, const float* __restrict__ sb2,
    const float* __restrict__ swg, const float* __restrict__ sbg,
    const float* __restrict__ swf, const float* __restrict__ sbf,
    const float* __restrict__ sgam, const float* __restrict__ sbet,
    float* __restrict__ out, int tok_base, int C)
{
    __shared__ float sw2s[256 * 32];                    // 32 KB
    __shared__ float swgs[1024], swfs[1024];            // 8 KB
    __shared__ float shv[8][260];                       // 8 tokens x 256 (16B-aligned rows)
    __shared__ float wls[8][33];
    const int t = threadIdx.x;
    const size_t shS = (size_t)C * 256;
    const size_t srS = (size_t)C * 32;
    for (int i = 0; i < 32; ++i) sw2s[t + i * 256] = sw2[t + i * 256];
    for (int i = 0; i < 4; ++i) {
        swgs[t + i * 256] = swg[t + i * 256];
        swfs[t + i * 256] = swf[t + i * 256];
    }
    // reduce split-K partials + bias, elu (float4-vectorized; same add order)
#pragma unroll
    for (int i = 0; i < 2; ++i) {
        int slot = t + i * 256;                         // 0..511
        int gg = slot >> 6;                             // token 0..7
        int c4 = (slot & 63) * 4;                       // col 0..252
        size_t o = (size_t)(blockIdx.x * 8 + gg) * 256 + c4;
        float4v z = *(const float4v*)&sb1[c4];
        z += *(const float4v*)&sh_part[o];
        z += *(const float4v*)&sh_part[shS + o];
        z += *(const float4v*)&sh_part[2 * shS + o];
        z += *(const float4v*)&sh_part[3 * shS + o];
        float4v e;
#pragma unroll
        for (int j = 0; j < 4; ++j)
            e[j] = z[j] > 0.f ? z[j] : (__expf(z[j]) - 1.f);
        *(float4v*)&shv[gg][c4] = e;
    }
    __syncthreads();
    const int g = t >> 5;                               // token group 0..7
    const int j = t & 31;                               // feature index
    const int token = blockIdx.x * 8 + g;               // chunk-local
    // fc2: 256 -> 32
    float p = sb2[j];
    for (int k = 0; k < 256; ++k) p += shv[g][k] * sw2s[k * 32 + j];
    // GLU via width-32 shuffles
    float gacc = sbg[j], uacc = sbf[j];
#pragma unroll 8
    for (int i = 0; i < 32; ++i) {
        float tv = __shfl(p, i, 32);
        gacc += tv * swgs[i * 32 + j];
        uacc += tv * swfs[i * 32 + j];
    }
    float sig = 1.f / (1.f + __expf(-gacc));
    size_t o2 = (size_t)token * 32 + j;
    float sresv = ssb[j] + sres_part[o2] + sres_part[srS + o2]
                + sres_part[2 * srS + o2] + sres_part[3 * srS + o2];
    float sv = sresv + sig * uacc;
    // LayerNorm over 32 lanes
    float s1 = sv, s2 = sv * sv;
    for (int off = 16; off; off >>= 1) {
        s1 += __shfl_xor(s1, off, 32);
        s2 += __shfl_xor(s2, off, 32);
    }
    float mean = s1 * (1.f / 32.f);
    float var = s2 * (1.f / 32.f) - mean * mean;
    float v = (sv - mean) * rsqrtf(var + 1e-5f) * sgam[j] + sbet[j];
    // softmax over 32 lanes
    float mx = v;
    for (int off = 16; off; off >>= 1) mx = fmaxf(mx, __shfl_xor(mx, off, 32));
    float e = __expf(v - mx);
    float ssum = e;
    for (int off = 16; off; off >>= 1) ssum += __shfl_xor(ssum, off, 32);
    wls[g][j] = e / ssum;
    __syncthreads();
    // weighted sum: thread -> 4 consecutive cols of 2 tokens (vectorized)
    {
        const int tg = t >> 6;                          // 0..3
        const int c4 = (t & 63) * 4;                    // col 0..252
#pragma unroll
        for (int tt = 0; tt < 2; ++tt) {
            int tk = tg * 2 + tt;
            const _Float16* sp = stacked + (size_t)(blockIdx.x * 8 + tk) * FH;
            float a0 = 0.f, a1 = 0.f, a2 = 0.f, a3 = 0.f;
#pragma unroll
            for (int f = 0; f < 32; ++f) {
                half4v vv = *(const half4v*)&sp[f * 256 + c4];
                float w = wls[tk][f];
                a0 += (float)vv[0] * w;
                a1 += (float)vv[1] * w;
                a2 += (float)vv[2] * w;
                a3 += (float)vv[3] * w;
            }
            float4v ov; ov[0] = a0; ov[1] = a1; ov[2] = a2; ov[3] = a3;
            *(float4v*)&out[(size_t)(tok_base + blockIdx.x * 8 + tk) * 256 + c4] = ov;
        }
    }
}

// ---------------------------------------------------------------------------
extern "C" void kernel_launch(void* const* d_in, const int* in_sizes, int n_in,
                              void* d_out, int out_size, void* d_ws, size_t ws_size,
                              hipStream_t stream)
{
    (void)in_sizes; (void)n_in; (void)out_size;
    const float* x    = (const float*)d_in[0];
    const float* w1   = (const float*)d_in[1];
    const float* b1   = (const float*)d_in[2];
    const float* w2   = (const float*)d_in[3];
    const float* b2   = (const float*)d_in[4];
    const float* wg   = (const float*)d_in[5];
    const float* bg   = (const float*)d_in[6];
    const float* wf   = (const float*)d_in[7];
    const float* bfp  = (const float*)d_in[8];
    const float* gamma= (const float*)d_in[9];
    const float* beta = (const float*)d_in[10];
    const float* wsk  = (const float*)d_in[11];
    const float* bsk  = (const float*)d_in[12];
    const float* sw1  = (const float*)d_in[13];
    const float* sb1  = (const float*)d_in[14];
    const float* sw2  = (const float*)d_in[15];
    const float* sb2  = (const float*)d_in[16];
    const float* swg  = (const float*)d_in[17];
    const float* sbg  = (const float*)d_in[18];
    const float* swf  = (const float*)d_in[19];
    const float* sbf  = (const float*)d_in[20];
    const float* sgam = (const float*)d_in[21];
    const float* sbet = (const float*)d_in[22];
    const float* ssw  = (const float*)d_in[23];
    const float* ssb  = (const float*)d_in[24];

    // ---- workspace layout, chunk size adaptive to ws_size ----
    // per-token: stacked 16384B + sh_part 4*1024B + sres_part 4*128B = 20992B
    const size_t fixedB = 12582912 + 4718592;            // wt (12 MiB) + wcat (4.5 MiB)
    int C = BT;                                          // tokens per chunk
    while (C > 512) {
        size_t need = fixedB + (size_t)C * 20992;
        if (need <= ws_size) break;
        C >>= 1;
    }
    const int nChunks = BT / C;

    char* ws = (char*)d_ws;
    _Float16* wt      = (_Float16*)ws;                                   // 3 x 2M fp16
    _Float16* wcat    = (_Float16*)(ws + 12582912);                      // 288 x 8192 fp16
    char* p = ws + fixedB;
    _Float16* stacked = (_Float16*)p;            p += (size_t)C * FH * 2;
    float* sh_part    = (float*)p;               p += (size_t)C * 256 * 4 * SPLITK;
    float* sres_part  = (float*)p;
    float* out        = (float*)d_out;

    hipLaunchKernelGGL(transpose_w_kernel, dim3(1536), dim3(256), 0, stream, w2, wg, wf, wt);
    hipLaunchKernelGGL(transpose_s_kernel, dim3(640), dim3(256), 0, stream, sw1, ssw, wcat);
    for (int c = 0; c < nChunks; ++c) {
        int tb = c * C;
        hipLaunchKernelGGL(grn_kernel, dim3((C / 64) * 32), dim3(512), 0, stream,
                           x, w1, b1, b2, bg, bfp, gamma, beta, wsk, bsk,
                           wt, wt + 2097152, wt + 2 * 2097152, stacked, tb);
        hipLaunchKernelGGL(sel_gemm_kernel, dim3((C / 64) * SPLITK), dim3(256), 0, stream,
                           stacked, wcat, sh_part, sres_part, C);
        hipLaunchKernelGGL(tail_kernel, dim3(C / 8), dim3(256), 0, stream,
                           sh_part, sres_part, stacked, sb1, ssb, sw2, sb2, swg, sbg, swf, sbf,
                           sgam, sbet, out, tb, C);
    }
}

// Round 15
// 692.954 us; speedup vs baseline: 1.1842x; 1.0016x over previous
//
#include <hip/hip_runtime.h>
#include <hip/hip_bf16.h>
#include <hip/hip_fp16.h>

#define BT 16384
#define F 32
#define H 256
#define FH 8192
#define SPLITK 4

typedef _Float16 half8 __attribute__((ext_vector_type(8)));
typedef _Float16 half4v __attribute__((ext_vector_type(4)));
typedef float float4v __attribute__((ext_vector_type(4)));

#define GLD_LDS(gsrc, ldst) \
    __builtin_amdgcn_global_load_lds( \
        (const __attribute__((address_space(1))) void*)(gsrc), \
        (__attribute__((address_space(3))) void*)(ldst), 16, 0, 0)

// Pipelined-barrier macros (T3/T4): counted vmcnt keeps the prefetch in
// flight ACROSS the barrier; sched_barrier(0) pins ordering (rule #18).
#define WAITVM1_BAR() do { \
    __builtin_amdgcn_sched_barrier(0); \
    asm volatile("s_waitcnt vmcnt(1)" ::: "memory"); \
    __builtin_amdgcn_s_barrier(); \
    __builtin_amdgcn_sched_barrier(0); } while (0)
#define WAITVM2_BAR() do { \
    __builtin_amdgcn_sched_barrier(0); \
    asm volatile("s_waitcnt vmcnt(2)" ::: "memory"); \
    __builtin_amdgcn_s_barrier(); \
    __builtin_amdgcn_sched_barrier(0); } while (0)
#define WAITVM0_BAR() do { \
    __builtin_amdgcn_sched_barrier(0); \
    asm volatile("s_waitcnt vmcnt(0)" ::: "memory"); \
    __builtin_amdgcn_s_barrier(); \
    __builtin_amdgcn_sched_barrier(0); } while (0)
#define END_BAR() do { \
    __builtin_amdgcn_sched_barrier(0); \
    __builtin_amdgcn_s_barrier(); \
    __builtin_amdgcn_sched_barrier(0); } while (0)
#define LGKM_BAR() do { \
    __builtin_amdgcn_sched_barrier(0); \
    asm volatile("s_waitcnt lgkmcnt(0)" ::: "memory"); \
    __builtin_amdgcn_s_barrier(); \
    __builtin_amdgcn_sched_barrier(0); } while (0)

// ---------------------------------------------------------------------------
// Prep: transpose w2/wg/wf (F,H_contr,H_out) fp32 -> [f][n_out][h_contr] fp16
// ---------------------------------------------------------------------------
__global__ __launch_bounds__(256) void transpose_w_kernel(
    const float* __restrict__ w2, const float* __restrict__ wg,
    const float* __restrict__ wf, _Float16* __restrict__ wt)
{
    __shared__ float tile[64][65];
    int bid = blockIdx.x;
    int tens = bid >> 9, rem = bid & 511;
    int f = rem >> 4, tl = rem & 15;
    int hb = (tl >> 2) * 64, nb = (tl & 3) * 64;
    const float* src = (tens == 0 ? w2 : (tens == 1 ? wg : wf)) + f * 65536;
    _Float16* dst = wt + (size_t)tens * 2097152 + f * 65536;
    int lane = threadIdx.x & 63, w = threadIdx.x >> 6;
    for (int i = 0; i < 16; ++i) {
        int r = i * 4 + w;
        tile[r][lane] = src[(hb + r) * 256 + nb + lane];
    }
    __syncthreads();
    for (int i = 0; i < 16; ++i) {
        int c = i * 4 + w;
        dst[(nb + c) * 256 + hb + lane] = (_Float16)tile[lane][c];
    }
}

// ---------------------------------------------------------------------------
// Prep: Wcat[n][k] fp16, n<256 from sw1 (8192,256), n in [256,288) from ssw
// ---------------------------------------------------------------------------
__global__ __launch_bounds__(256) void transpose_s_kernel(
    const float* __restrict__ sw1, const float* __restrict__ ssw,
    _Float16* __restrict__ wcat)
{
    __shared__ float tile[64][65];
    int bid = blockIdx.x;
    int lane = threadIdx.x & 63, w = threadIdx.x >> 6;
    if (bid < 512) {
        int k0 = (bid >> 2) * 64, n0 = (bid & 3) * 64;
        for (int i = 0; i < 16; ++i) {
            int r = i * 4 + w;
            tile[r][lane] = sw1[(size_t)(k0 + r) * 256 + n0 + lane];
        }
        __syncthreads();
        for (int i = 0; i < 16; ++i) {
            int c = i * 4 + w;
            wcat[(size_t)(n0 + c) * FH + k0 + lane] = (_Float16)tile[lane][c];
        }
    } else {
        int k0 = (bid - 512) * 64;
        int t = threadIdx.x;
        for (int i = 0; i < 8; ++i) {
            int idx = t + i * 256;
            int r = idx >> 5, cc = idx & 31;
            tile[r][cc] = ssw[(size_t)(k0 + r) * 32 + cc];
        }
        __syncthreads();
        for (int i = 0; i < 8; ++i) {
            int idx = t + i * 256;
            int c = idx >> 6, rr = idx & 63;
            wcat[(size_t)(256 + c) * FH + k0 + rr] = (_Float16)tile[rr][c];
        }
    }
}

// ---------------------------------------------------------------------------
// Fused per-feature GRN v7 (unchanged from r13 -- measured 201 us):
// XCD-clustered decode, depth-3 Bs ring, ONE barrier/step, counted vmcnt(2).
// ---------------------------------------------------------------------------
__global__ __launch_bounds__(512, 4) void grn_kernel(
    const float* __restrict__ x, const float* __restrict__ w1, const float* __restrict__ b1,
    const float* __restrict__ b2, const float* __restrict__ bg, const float* __restrict__ bfv_,
    const float* __restrict__ gamma, const float* __restrict__ beta,
    const float* __restrict__ wsk, const float* __restrict__ bsk,
    const _Float16* __restrict__ w2t, const _Float16* __restrict__ wgt,
    const _Float16* __restrict__ wft, _Float16* __restrict__ stacked, int tok_base)
{
    __shared__ __align__(16) char smem[81920];
    _Float16* As = (_Float16*)smem;                  // 64 x 256 fp16 swizzled (32KB)
    _Float16* Bs = (_Float16*)(smem + 32768);        // 3 x (256x32) fp16 ring (48KB)
    float* red = (float*)smem;                       // alias As (post-MFMA): 512 f32
    float* mv  = (float*)(smem + 2048);              // alias As: 128 f32

    // XCD-clustered decode (T1): each XCD owns features [4*xcd, 4*xcd+4)
    const int bid = blockIdx.x;
    const int xcd = bid & 7;
    const int slot = bid >> 3;
    const int f = xcd * 4 + (slot & 3);
    const int tok0 = (slot >> 2) * 64;               // chunk-local
    const int t = threadIdx.x;
    const int wv = t >> 6;
    const int ln = t & 15;
    const int q  = (t >> 4) & 3;
    const int wm = wv >> 2;                          // m-half 0/1
    const int wn = wv & 3;                           // n-quarter 0..3
    const int r0 = wm * 32 + ln;                     // A-frag row, mt=0
    const int r1 = r0 + 16;                          // A-frag row, mt=1

    const _Float16* w2f = w2t + (size_t)f * 65536;
    const _Float16* wgf = wgt + (size_t)f * 65536;
    const _Float16* wff = wft + (size_t)f * 65536;

#define GRN_STAGE(buf, Bsrc, kc) do {                                          \
        const _Float16* _bp = (Bsrc);                                          \
        _Pragma("unroll")                                                      \
        for (int _i = 0; _i < 2; ++_i) {                                       \
            int _s = t + _i * 512;                                             \
            int _row = _s >> 2;                                                \
            int _c = (_s & 3) ^ ((_row >> 1) & 3);                             \
            GLD_LDS(_bp + _row * 256 + (kc) * 32 + _c * 8,                     \
                    Bs + (buf) * 8192 + _s * 8);                               \
        } } while (0)

#define GRN_MFMA(ACC, s) do {                                                  \
        const _Float16* _B = Bs + ((s) % 3) * 8192;                            \
        const int _kc = (s) & 7;                                               \
        half8 _a0 = *(const half8*)&As[r0 * 256 + (((_kc * 4 + q) ^ (r0 & 7)) << 3)]; \
        half8 _a1 = *(const half8*)&As[r1 * 256 + (((_kc * 4 + q) ^ (r1 & 7)) << 3)]; \
        _Pragma("unroll")                                                      \
        for (int _nt = 0; _nt < 4; ++_nt) {                                    \
            int _rb = wn * 64 + _nt * 16 + ln;                                 \
            int _cp = q ^ ((_rb >> 1) & 3);                                    \
            half8 _b8 = *(const half8*)&_B[_rb * 32 + _cp * 8];                \
            ACC[0][_nt] = __builtin_amdgcn_mfma_f32_16x16x32_f16(              \
                _a0, _b8, ACC[0][_nt], 0, 0, 0);                               \
            ACC[1][_nt] = __builtin_amdgcn_mfma_f32_16x16x32_f16(              \
                _a1, _b8, ACC[1][_nt], 0, 0, 0);                               \
        } } while (0)

    // b2 preloaded (retired by compiler wait before the h2 epilogue)
    float b2v[4];
#pragma unroll
    for (int nt = 0; nt < 4; ++nt) b2v[nt] = b2[f * H + wn * 64 + nt * 16 + ln];

    GRN_STAGE(0, w2f, 0);                            // step-0 tile -> buf0

    // A = elu(x * w1 + b1) -> As (swizzled). x reads are wave-uniform s_loads.
    {
        const int colE = t & 255;
        const int rgE = __builtin_amdgcn_readfirstlane(t >> 8) * 32;
        const float w1v = w1[f * H + colE];
        const float b1v = b1[f * H + colE];
        const int chE = colE >> 3, elE = colE & 7;
#pragma unroll 8
        for (int i = 0; i < 32; ++i) {
            int row = rgE + i;
            float xv = x[(size_t)(tok_base + tok0 + row) * F + f];
            float z = fmaf(xv, w1v, b1v);
            float e = z > 0.f ? z : (__expf(z) - 1.f);
            As[row * 256 + ((chE ^ (row & 7)) << 3) + elE] = (_Float16)e;
        }
    }
    GRN_STAGE(1, w2f, 1);                            // step-1 tile -> buf1
    LGKM_BAR();                                      // As visible; stages in flight

    float4v acc1[2][4];
#pragma unroll
    for (int mt = 0; mt < 2; ++mt)
#pragma unroll
        for (int nt = 0; nt < 4; ++nt)
#pragma unroll
            for (int r = 0; r < 4; ++r) acc1[mt][nt][r] = 0.f;

    // ---- steps 0..7: h2 = A @ w2 ----
#pragma unroll
    for (int s = 0; s < 8; ++s) {
        WAITVM2_BAR();                               // buf[s%3] ready, all waves
        if (s < 6) GRN_STAGE((s + 2) % 3, w2f, s + 2);
        else       GRN_STAGE((s + 2) % 3, wgf, s - 6);   // chain into wg
        GRN_MFMA(acc1, s);
    }
    END_BAR();                                       // step-7 As-reads done

    // h2 + b2 -> As (swizzled fp16). No vm-ops (b2 preloaded): the wg
    // prefetches stay in flight; lgkm-only barrier.
    {
#pragma unroll
        for (int mt = 0; mt < 2; ++mt)
#pragma unroll
            for (int nt = 0; nt < 4; ++nt) {
                int n = wn * 64 + nt * 16 + ln;
#pragma unroll
                for (int r = 0; r < 4; ++r) {
                    int row = wm * 32 + mt * 16 + q * 4 + r;
                    As[row * 256 + (((n >> 3) ^ (row & 7)) << 3) + (n & 7)] =
                        (_Float16)(acc1[mt][nt][r] + b2v[nt]);
                }
            }
    }
    LGKM_BAR();

    float4v accG[2][4], accF[2][4];
#pragma unroll
    for (int mt = 0; mt < 2; ++mt)
#pragma unroll
        for (int nt = 0; nt < 4; ++nt)
#pragma unroll
            for (int r = 0; r < 4; ++r) { accG[mt][nt][r] = 0.f; accF[mt][nt][r] = 0.f; }

    // ---- steps 8..15: Cg = h2 @ wg ----
#pragma unroll
    for (int s8 = 0; s8 < 8; ++s8) {
        const int s = s8 + 8;
        WAITVM2_BAR();
        if (s8 < 6) GRN_STAGE((s + 2) % 3, wgf, s8 + 2);
        else        GRN_STAGE((s + 2) % 3, wff, s8 - 6); // chain into wf
        GRN_MFMA(accG, s);
    }
    // ---- steps 16..23: Cf = h2 @ wf ----
#pragma unroll
    for (int s8 = 0; s8 < 8; ++s8) {
        const int s = s8 + 16;
        if (s8 < 7) { WAITVM2_BAR(); } else { WAITVM0_BAR(); }
        if (s8 < 6) GRN_STAGE((s + 2) % 3, wff, s8 + 2);
        GRN_MFMA(accF, s);
    }
    END_BAR();                                       // step-23 As-reads done (red aliases As)
#undef GRN_STAGE
#undef GRN_MFMA

    // ---- GLU + residual, in registers (y overwrites accG) ----
    float xr[2][4];
#pragma unroll
    for (int mt = 0; mt < 2; ++mt)
#pragma unroll
        for (int r = 0; r < 4; ++r)
            xr[mt][r] = x[(size_t)(tok_base + tok0 + wm * 32 + mt * 16 + q * 4 + r) * F + f];
#pragma unroll
    for (int nt = 0; nt < 4; ++nt) {
        int nn = f * H + wn * 64 + nt * 16 + ln;
        float bgv = bg[nn], bfv = bfv_[nn], wsv = wsk[nn], bsv = bsk[nn];
#pragma unroll
        for (int mt = 0; mt < 2; ++mt)
#pragma unroll
            for (int r = 0; r < 4; ++r) {
                float cg = accG[mt][nt][r] + bgv;
                float cf = accF[mt][nt][r] + bfv;
                float sig = 1.f / (1.f + __expf(-cg));
                accG[mt][nt][r] = sig * cf + xr[mt][r] * wsv + bsv;
            }
    }

    // ---- LN sums fused from registers ----
#pragma unroll
    for (int mt = 0; mt < 2; ++mt)
#pragma unroll
        for (int r = 0; r < 4; ++r) {
            float v0 = accG[mt][0][r], v1 = accG[mt][1][r];
            float v2 = accG[mt][2][r], v3 = accG[mt][3][r];
            float s1 = (v0 + v1) + (v2 + v3);
            float s2 = (v0 * v0 + v1 * v1) + (v2 * v2 + v3 * v3);
#pragma unroll
            for (int m = 1; m <= 8; m <<= 1) {
                s1 += __shfl_xor(s1, m, 64);
                s2 += __shfl_xor(s2, m, 64);
            }
            if (ln == 0) {
                int row = wm * 32 + mt * 16 + q * 4 + r;
                red[row * 4 + wn] = s1;
                red[256 + row * 4 + wn] = s2;
            }
        }
    __syncthreads();
    if (t < 64) {
        float a = (red[t * 4] + red[t * 4 + 1]) + (red[t * 4 + 2] + red[t * 4 + 3]);
        float b = (red[256 + t * 4] + red[256 + t * 4 + 1])
                + (red[256 + t * 4 + 2] + red[256 + t * 4 + 3]);
        float mean = a * (1.f / 256.f);
        float var = b * (1.f / 256.f) - mean * mean;
        mv[t] = mean;
        mv[64 + t] = rsqrtf(var + 1e-5f);
    }
    __syncthreads();

    // ---- normalize + scale from registers, store fp16 ----
    float mr[2][4], rr[2][4];
#pragma unroll
    for (int mt = 0; mt < 2; ++mt)
#pragma unroll
        for (int r = 0; r < 4; ++r) {
            int row = wm * 32 + mt * 16 + q * 4 + r;
            mr[mt][r] = mv[row];
            rr[mt][r] = mv[64 + row];
        }
#pragma unroll
    for (int nt = 0; nt < 4; ++nt) {
        int n = wn * 64 + nt * 16 + ln;
        float gv = gamma[f * H + n], bvv = beta[f * H + n];
#pragma unroll
        for (int mt = 0; mt < 2; ++mt)
#pragma unroll
            for (int r = 0; r < 4; ++r) {
                int row = wm * 32 + mt * 16 + q * 4 + r;
                float vv = (accG[mt][nt][r] - mr[mt][r]) * rr[mt][r] * gv + bvv;
                stacked[(size_t)(tok0 + row) * FH + f * H + n] = (_Float16)vv;
            }
    }
}

// ---------------------------------------------------------------------------
// Selection GEMM v6: occupancy fix. Grid is 512 blocks = 2 blocks/CU; the old
// 256-thread layout gave only 2 waves/SIMD -- too little TLP to hide the
// per-iter B L2 latency (critical path before each MFMA cluster). v6 keeps
// BM=64/BK=64 and the depth-3 ring but uses 512 threads = 8 waves (1m x 8n):
// each wave computes ALL 4 m-tiles; the 18 n-tiles split DISJOINTLY (waves
// 0-1: {wv, wv+8, 16+wv}; waves 2-7: {wv, wv+8}; tiles 16/17 are exactly the
// sres cols -> static branch). B rows disjoint per wave -> B L2 traffic
// unchanged; only LDS A-reads double (LDS BW ample). Waves/SIMD 2 -> 4.
// Staging = 1 gld_lds/thread (512 slots), so counted wait is vmcnt(1).
// ---------------------------------------------------------------------------
__global__ __launch_bounds__(512, 4) void sel_gemm_kernel(
    const _Float16* __restrict__ stacked, const _Float16* __restrict__ wcat,
    float* __restrict__ sh_part, float* __restrict__ sres_part, int C)
{
    __shared__ __align__(16) _Float16 As3[3][64 * 64];   // 3 x 8 KB ring
    const int t = threadIdx.x;
    const int wv = t >> 6;                               // 0..7
    const int ln = t & 15, q = (t >> 4) & 3;
    const int bid = blockIdx.x;
    const int xcd = bid & 7;
    const int slot = bid >> 3;
    const int kb = xcd >> 1;                             // k-slice 0..3
    const int tok0 = (slot * 2 + (xcd & 1)) * 64;        // chunk-local
    const int NT = (wv < 2) ? 3 : 2;                     // n-tiles this wave

    // staging: 512 slots (64 rows x 8 chunks), 1 per thread; inverse-swizzled
    // global source, linear LDS dest (rule #21).
    const int row0 = t >> 3;
    const int c0 = ((t & 7) ^ (row0 & 7)) * 8;
    const _Float16* a0src = stacked + (size_t)(tok0 + row0) * FH + kb * 2048 + c0;

    float4v acc[4][3];
#pragma unroll
    for (int mt = 0; mt < 4; ++mt)
#pragma unroll
        for (int i = 0; i < 3; ++i)
#pragma unroll
            for (int r = 0; r < 4; ++r) acc[mt][i][r] = 0.f;

#define SEL_STAGE(buf, kcc) GLD_LDS(a0src + (kcc) * 64, &As3[buf][t * 8])

    SEL_STAGE(0, 0);
    SEL_STAGE(1, 1);

    int cR = 0;                                          // read slot = kc % 3
    for (int kc = 0; kc < 32; ++kc) {
        WAITVM1_BAR();        // stage(kc) visible to ALL waves; stage(kc+1) in flight
        // ---- B fragments: global->reg, BEFORE the new stage ----
        half8 bb0[3], bb1[3];
#define SEL_LOAD(i, tile)                                                      \
        {                                                                      \
            const _Float16* bp = wcat                                          \
                + (size_t)((tile) * 16 + ln) * FH                              \
                + kb * 2048 + kc * 64 + q * 8;                                 \
            bb0[i] = *(const half8*)bp;                                        \
            bb1[i] = *(const half8*)(bp + 32);                                 \
        }
        SEL_LOAD(0, wv) SEL_LOAD(1, wv + 8)
        if (wv < 2) SEL_LOAD(2, 16 + wv)
#undef SEL_LOAD
        // ---- stage kc+2 into ring slot (kc+2)%3 (read last at kc-1) ----
        if (kc < 30) {
            int cS = cR + 2; if (cS >= 3) cS -= 3;
            SEL_STAGE(cS, kc + 2);
        }
        // ---- A fragments from ring[kc%3] (swizzled, conflict-free) ----
        const _Float16* As = As3[cR];
        half8 af0[4], af1[4];
#pragma unroll
        for (int mt = 0; mt < 4; ++mt) {
            int row = mt * 16 + ln;
            af0[mt] = *(const half8*)&As[row * 64 + ((q ^ (row & 7)) * 8)];
            af1[mt] = *(const half8*)&As[row * 64 + (((4 + q) ^ (row & 7)) * 8)];
        }
        // ---- MFMA, fully static indexing ----
#define SEL_FMA(i)                                                            \
        {                                                                      \
            _Pragma("unroll")                                                  \
            for (int mt = 0; mt < 4; ++mt)                                     \
                acc[mt][i] = __builtin_amdgcn_mfma_f32_16x16x32_f16(           \
                    af0[mt], bb0[i], acc[mt][i], 0, 0, 0);                     \
            _Pragma("unroll")                                                  \
            for (int mt = 0; mt < 4; ++mt)                                     \
                acc[mt][i] = __builtin_amdgcn_mfma_f32_16x16x32_f16(           \
                    af1[mt], bb1[i], acc[mt][i], 0, 0, 0);                     \
        }
        SEL_FMA(0) SEL_FMA(1)
        if (wv < 2) SEL_FMA(2)
#undef SEL_FMA
        cR = cR + 1; if (cR == 3) cR = 0;
    }
#undef SEL_STAGE

    // ---- epilogue: plain stores, static branches ----
    float* shp = sh_part + (size_t)kb * ((size_t)C * 256);
    float* srp = sres_part + (size_t)kb * ((size_t)C * 32);
#pragma unroll
    for (int i = 0; i < 2; ++i) {
        int n = (wv + 8 * i) * 16 + ln;                  // tiles 0..15 -> n < 256
#pragma unroll
        for (int mt = 0; mt < 4; ++mt)
#pragma unroll
            for (int r = 0; r < 4; ++r) {
                int m = tok0 + mt * 16 + q * 4 + r;
                shp[(size_t)m * 256 + n] = acc[mt][i][r];
            }
    }
    if (wv < 2) {                                        // tiles 16/17 = sres cols
        int n = wv * 16 + ln;                            // 0..31
#pragma unroll
        for (int mt = 0; mt < 4; ++mt)
#pragma unroll
            for (int r = 0; r < 4; ++r) {
                int m = tok0 + mt * 16 + q * 4 + r;
                srp[(size_t)m * 32 + n] = acc[mt][2][r];
            }
    }
}

// ---------------------------------------------------------------------------
// Fused selection tail v2 (unchanged -- measured good): vectorized split-K
// reduce (float4) + vectorized weighted sum (half4/float4).
// ---------------------------------------------------------------------------
__global__ __launch_bounds__(256) void tail_kernel(
    const float* __restrict__ sh_part, const float* __restrict__ sres_part,
    const _Float16* __restrict__ stacked,
    const float* __restrict__ sb1, const float* __restrict__ ssb,
    const float* __restrict__ sw2, const float* __restrict__ sb2,
    const float* __restrict__ swg, const float* __restrict__ sbg,
    const float* __restrict__ swf, const float* __restrict__ sbf,
    const float* __restrict__ sgam, const float* __restrict__ sbet,
    float* __restrict__ out, int tok_base, int C)
{
    __shared__ float sw2s[256 * 32];                    // 32 KB
    __shared__ float swgs[1024], swfs[1024];            // 8 KB
    __shared__ float shv[8][260];                       // 8 tokens x 256 (16B-aligned rows)
    __shared__ float wls[8][33];
    const int t = threadIdx.x;
    const size_t shS = (size_t)C * 256;
    const size_t srS = (size_t)C * 32;
    for (int i = 0; i < 32; ++i) sw2s[t + i * 256] = sw2[t + i * 256];
    for (int i = 0; i < 4; ++i) {
        swgs[t + i * 256] = swg[t + i * 256];
        swfs[t + i * 256] = swf[t + i * 256];
    }
    // reduce split-K partials + bias, elu (float4-vectorized; same add order)
#pragma unroll
    for (int i = 0; i < 2; ++i) {
        int slot = t + i * 256;                         // 0..511
        int gg = slot >> 6;                             // token 0..7
        int c4 = (slot & 63) * 4;                       // col 0..252
        size_t o = (size_t)(blockIdx.x * 8 + gg) * 256 + c4;
        float4v z = *(const float4v*)&sb1[c4];
        z += *(const float4v*)&sh_part[o];
        z += *(const float4v*)&sh_part[shS + o];
        z += *(const float4v*)&sh_part[2 * shS + o];
        z += *(const float4v*)&sh_part[3 * shS + o];
        float4v e;
#pragma unroll
        for (int j = 0; j < 4; ++j)
            e[j] = z[j] > 0.f ? z[j] : (__expf(z[j]) - 1.f);
        *(float4v*)&shv[gg][c4] = e;
    }
    __syncthreads();
    const int g = t >> 5;                               // token group 0..7
    const int j = t & 31;                               // feature index
    const int token = blockIdx.x * 8 + g;               // chunk-local
    // fc2: 256 -> 32
    float p = sb2[j];
    for (int k = 0; k < 256; ++k) p += shv[g][k] * sw2s[k * 32 + j];
    // GLU via width-32 shuffles
    float gacc = sbg[j], uacc = sbf[j];
#pragma unroll 8
    for (int i = 0; i < 32; ++i) {
        float tv = __shfl(p, i, 32);
        gacc += tv * swgs[i * 32 + j];
        uacc += tv * swfs[i * 32 + j];
    }
    float sig = 1.f / (1.f + __expf(-gacc));
    size_t o2 = (size_t)token * 32 + j;
    float sresv = ssb[j] + sres_part[o2] + sres_part[srS + o2]
                + sres_part[2 * srS + o2] + sres_part[3 * srS + o2];
    float sv = sresv + sig * uacc;
    // LayerNorm over 32 lanes
    float s1 = sv, s2 = sv * sv;
    for (int off = 16; off; off >>= 1) {
        s1 += __shfl_xor(s1, off, 32);
        s2 += __shfl_xor(s2, off, 32);
    }
    float mean = s1 * (1.f / 32.f);
    float var = s2 * (1.f / 32.f) - mean * mean;
    float v = (sv - mean) * rsqrtf(var + 1e-5f) * sgam[j] + sbet[j];
    // softmax over 32 lanes
    float mx = v;
    for (int off = 16; off; off >>= 1) mx = fmaxf(mx, __shfl_xor(mx, off, 32));
    float e = __expf(v - mx);
    float ssum = e;
    for (int off = 16; off; off >>= 1) ssum += __shfl_xor(ssum, off, 32);
    wls[g][j] = e / ssum;
    __syncthreads();
    // weighted sum: thread -> 4 consecutive cols of 2 tokens (vectorized)
    {
        const int tg = t >> 6;                          // 0..3
        const int c4 = (t & 63) * 4;                    // col 0..252
#pragma unroll
        for (int tt = 0; tt < 2; ++tt) {
            int tk = tg * 2 + tt;
            const _Float16* sp = stacked + (size_t)(blockIdx.x * 8 + tk) * FH;
            float a0 = 0.f, a1 = 0.f, a2 = 0.f, a3 = 0.f;
#pragma unroll
            for (int f = 0; f < 32; ++f) {
                half4v vv = *(const half4v*)&sp[f * 256 + c4];
                float w = wls[tk][f];
                a0 += (float)vv[0] * w;
                a1 += (float)vv[1] * w;
                a2 += (float)vv[2] * w;
                a3 += (float)vv[3] * w;
            }
            float4v ov; ov[0] = a0; ov[1] = a1; ov[2] = a2; ov[3] = a3;
            *(float4v*)&out[(size_t)(tok_base + blockIdx.x * 8 + tk) * 256 + c4] = ov;
        }
    }
}

// ---------------------------------------------------------------------------
extern "C" void kernel_launch(void* const* d_in, const int* in_sizes, int n_in,
                              void* d_out, int out_size, void* d_ws, size_t ws_size,
                              hipStream_t stream)
{
    (void)in_sizes; (void)n_in; (void)out_size;
    const float* x    = (const float*)d_in[0];
    const float* w1   = (const float*)d_in[1];
    const float* b1   = (const float*)d_in[2];
    const float* w2   = (const float*)d_in[3];
    const float* b2   = (const float*)d_in[4];
    const float* wg   = (const float*)d_in[5];
    const float* bg   = (const float*)d_in[6];
    const float* wf   = (const float*)d_in[7];
    const float* bfp  = (const float*)d_in[8];
    const float* gamma= (const float*)d_in[9];
    const float* beta = (const float*)d_in[10];
    const float* wsk  = (const float*)d_in[11];
    const float* bsk  = (const float*)d_in[12];
    const float* sw1  = (const float*)d_in[13];
    const float* sb1  = (const float*)d_in[14];
    const float* sw2  = (const float*)d_in[15];
    const float* sb2  = (const float*)d_in[16];
    const float* swg  = (const float*)d_in[17];
    const float* sbg  = (const float*)d_in[18];
    const float* swf  = (const float*)d_in[19];
    const float* sbf  = (const float*)d_in[20];
    const float* sgam = (const float*)d_in[21];
    const float* sbet = (const float*)d_in[22];
    const float* ssw  = (const float*)d_in[23];
    const float* ssb  = (const float*)d_in[24];

    // ---- workspace layout, chunk size adaptive to ws_size ----
    // per-token: stacked 16384B + sh_part 4*1024B + sres_part 4*128B = 20992B
    const size_t fixedB = 12582912 + 4718592;            // wt (12 MiB) + wcat (4.5 MiB)
    int C = BT;                                          // tokens per chunk
    while (C > 512) {
        size_t need = fixedB + (size_t)C * 20992;
        if (need <= ws_size) break;
        C >>= 1;
    }
    const int nChunks = BT / C;

    char* ws = (char*)d_ws;
    _Float16* wt      = (_Float16*)ws;                                   // 3 x 2M fp16
    _Float16* wcat    = (_Float16*)(ws + 12582912);                      // 288 x 8192 fp16
    char* p = ws + fixedB;
    _Float16* stacked = (_Float16*)p;            p += (size_t)C * FH * 2;
    float* sh_part    = (float*)p;               p += (size_t)C * 256 * 4 * SPLITK;
    float* sres_part  = (float*)p;
    float* out        = (float*)d_out;

    hipLaunchKernelGGL(transpose_w_kernel, dim3(1536), dim3(256), 0, stream, w2, wg, wf, wt);
    hipLaunchKernelGGL(transpose_s_kernel, dim3(640), dim3(256), 0, stream, sw1, ssw, wcat);
    for (int c = 0; c < nChunks; ++c) {
        int tb = c * C;
        hipLaunchKernelGGL(grn_kernel, dim3((C / 64) * 32), dim3(512), 0, stream,
                           x, w1, b1, b2, bg, bfp, gamma, beta, wsk, bsk,
                           wt, wt + 2097152, wt + 2 * 2097152, stacked, tb);
        hipLaunchKernelGGL(sel_gemm_kernel, dim3((C / 64) * SPLITK), dim3(512), 0, stream,
                           stacked, wcat, sh_part, sres_part, C);
        hipLaunchKernelGGL(tail_kernel, dim3(C / 8), dim3(256), 0, stream,
                           sh_part, sres_part, stacked, sb1, ssb, sw2, sb2, swg, sbg, swf, sbf,
                           sgam, sbet, out, tb, C);
    }
}